// Round 11
// baseline (289.452 us; speedup 1.0000x reference)
//
#include <hip/hip_runtime.h>
#include <hip/hip_bf16.h>
#include <math.h>

#define NEG_SLOPE 0.2f
#define CHUNK 2048      // edges per k_bin block
#define NPB2 128        // nodes per coarse bucket
#define SCAP 5120       // LDS record capacity (bucket mean ~4092, sd ~64)

__device__ __forceinline__ unsigned f2bf(float f) {
  unsigned u = __float_as_uint(f);
  return (u + 0x7fffu + ((u >> 16) & 1u)) >> 16;  // RNE
}

// ---------------------------------------------------------------------------
// K1: h = x @ W + b_W. Register-stationary: one wave per row, W columns in
// 128 VGPRs, x row via scalar loads, zero LDS.
// ---------------------------------------------------------------------------
__global__ __launch_bounds__(256) void k1_gemm(
    const float* __restrict__ x, const float* __restrict__ W,
    const float* __restrict__ bW, const float* __restrict__ att,
    unsigned int* __restrict__ hb, float* __restrict__ ai,
    float* __restrict__ aj, int Nn) {
  int t = threadIdx.x;
  int lane = t & 63;  // d
  int wid = blockIdx.x * (blockDim.x >> 6) + (t >> 6);
  int nwaves = gridDim.x * (blockDim.x >> 6);

  float Wr0[64], Wr1[64];
#pragma unroll
  for (int k = 0; k < 64; ++k) {
    Wr0[k] = W[k * 128 + lane];
    Wr1[k] = W[k * 128 + 64 + lane];
  }
  float bs0 = bW[lane], bs1 = bW[64 + lane];
  float ati0 = att[lane];
  float atj0 = att[64 + lane];
  float ati1 = att[128 + lane];
  float atj1 = att[192 + lane];

  for (int row = wid; row < Nn; row += nwaves) {
    int r = __builtin_amdgcn_readfirstlane(row);
    const float* __restrict__ xr = x + (size_t)r * 64;
    float a0a = 0.f, a0b = 0.f, a1a = 0.f, a1b = 0.f;
#pragma unroll
    for (int k = 0; k < 64; k += 2) {
      float xk0 = xr[k], xk1 = xr[k + 1];
      a0a = fmaf(xk0, Wr0[k], a0a);
      a1a = fmaf(xk0, Wr1[k], a1a);
      a0b = fmaf(xk1, Wr0[k + 1], a0b);
      a1b = fmaf(xk1, Wr1[k + 1], a1b);
    }
    float h0 = a0a + a0b + bs0;
    float h1 = a1a + a1b + bs1;
    hb[(size_t)r * 64 + lane] = f2bf(h0) | (f2bf(h1) << 16);

    float ti0 = ati0 * h0, tj0 = atj0 * h0;
    float ti1 = ati1 * h1, tj1 = atj1 * h1;
    ti0 += __shfl_xor(ti0, 32, 64);
    tj0 += __shfl_xor(tj0, 32, 64);
    ti1 += __shfl_xor(ti1, 32, 64);
    tj1 += __shfl_xor(tj1, 32, 64);
    float mi = (lane < 32) ? ti0 : ti1;
    float mj = (lane < 32) ? tj0 : tj1;
#pragma unroll
    for (int off = 16; off > 0; off >>= 1) {
      mi += __shfl_xor(mi, off, 64);
      mj += __shfl_xor(mj, off, 64);
    }
    if ((lane & 31) == 0) {
      ai[r * 2 + (lane >> 5)] = mi;
      aj[r * 2 + (lane >> 5)] = mj;
    }
  }
}

// ---------------------------------------------------------------------------
// K_bin: DUAL multi-split. CHUNK=2048, two private windows (dst-binned rec,
// src-binned rec_src), LDS-staged, sequential flush. Parallel 256-thread
// scans (verified round-6 middle win).
// ---------------------------------------------------------------------------
__global__ __launch_bounds__(256) void k_bin(
    const int* __restrict__ ei, const int* __restrict__ eattr,
    unsigned int* __restrict__ rec, int* __restrict__ cnt_tbl,
    int* __restrict__ base_tbl, unsigned int* __restrict__ rec_src,
    int* __restrict__ cnt_tbl2, int* __restrict__ base_tbl2, int Ee, int NCB) {
  __shared__ unsigned sbuf[CHUNK];   // 8 KB
  __shared__ unsigned sbuf2[CHUNK];  // 8 KB
  __shared__ int hist[512], cur[512], hist2[512], cur2[512];
  __shared__ int ssc[256];
  int t = threadIdx.x;
  for (int i = t; i < NCB; i += 256) { hist[i] = 0; hist2[i] = 0; }
  __syncthreads();
  int start = blockIdx.x * CHUNK;
  int end = min(start + CHUNK, Ee);
  int cnt = end - start;
  int cbv[CHUNK / 256], cb2v[CHUNK / 256];
  unsigned pkv[CHUNK / 256], pk2v[CHUNK / 256];
  int nk = 0;
  for (int e = start + t; e < end; e += 256, ++nk) {
    int dst = __builtin_nontemporal_load(&ei[Ee + e]);
    int src = __builtin_nontemporal_load(&ei[e]);
    int a0 = __builtin_nontemporal_load(&eattr[e * 3]);
    int a1 = __builtin_nontemporal_load(&eattr[e * 3 + 1]);
    int a2 = __builtin_nontemporal_load(&eattr[e * 3 + 2]);
    unsigned c012 = (unsigned)(a0 + 5 * a1 + 25 * a2);
    cbv[nk] = dst >> 7;
    pkv[nk] = (unsigned)src | (c012 << 16) | ((unsigned)(dst & 127) << 23);
    cb2v[nk] = src >> 7;
    pk2v[nk] = (unsigned)dst | ((unsigned)(src & 127) << 17) | (c012 << 24);
    atomicAdd(&hist[dst >> 7], 1);
    atomicAdd(&hist2[src >> 7], 1);
  }
  __syncthreads();
  // parallel exclusive scan: hist -> cur, hist2 -> cur2
  {
    int per = (NCB + 255) / 256;  // 2
    int loc[4];
    int lsum = 0;
#pragma unroll 2
    for (int j = 0; j < per; ++j) {
      int idx = t * per + j;
      int v = (idx < NCB) ? hist[idx] : 0;
      loc[j] = lsum;
      lsum += v;
    }
    ssc[t] = lsum;
    __syncthreads();
#pragma unroll
    for (int o = 1; o < 256; o <<= 1) {
      int xv = (t >= o) ? ssc[t - o] : 0;
      __syncthreads();
      ssc[t] += xv;
      __syncthreads();
    }
    int excl = ssc[t] - lsum;
#pragma unroll 2
    for (int j = 0; j < per; ++j) {
      int idx = t * per + j;
      if (idx < NCB) cur[idx] = excl + loc[j];
    }
    __syncthreads();
    lsum = 0;
#pragma unroll 2
    for (int j = 0; j < per; ++j) {
      int idx = t * per + j;
      int v = (idx < NCB) ? hist2[idx] : 0;
      loc[j] = lsum;
      lsum += v;
    }
    ssc[t] = lsum;
    __syncthreads();
#pragma unroll
    for (int o = 1; o < 256; o <<= 1) {
      int xv = (t >= o) ? ssc[t - o] : 0;
      __syncthreads();
      ssc[t] += xv;
      __syncthreads();
    }
    excl = ssc[t] - lsum;
#pragma unroll 2
    for (int j = 0; j < per; ++j) {
      int idx = t * per + j;
      if (idx < NCB) cur2[idx] = excl + loc[j];
    }
  }
  __syncthreads();
  for (int i = t; i < NCB; i += 256) {
    cnt_tbl[blockIdx.x * NCB + i] = hist[i];
    base_tbl[blockIdx.x * NCB + i] = cur[i];
    cnt_tbl2[blockIdx.x * NCB + i] = hist2[i];
    base_tbl2[blockIdx.x * NCB + i] = cur2[i];
  }
  __syncthreads();
  for (int k = 0; k < nk; ++k) {
    int pos = atomicAdd(&cur[cbv[k]], 1);
    sbuf[pos] = pkv[k];
    int pos2 = atomicAdd(&cur2[cb2v[k]], 1);
    sbuf2[pos2] = pk2v[k];
  }
  __syncthreads();
  for (int i = t; i < cnt; i += 256) {
    __builtin_nontemporal_store(sbuf[i], &rec[start + i]);
    __builtin_nontemporal_store(sbuf2[i], &rec_src[start + i]);
  }
}

// ---------------------------------------------------------------------------
// K_segoff_ab: both per-bucket segment-offset scans in ONE launch.
// Grid = 2*NCB; blocks [0,NCB) scan the dst table, [NCB,2*NCB) the src table.
// ---------------------------------------------------------------------------
__global__ __launch_bounds__(256) void k_segoff_ab(
    const int* __restrict__ cnt_tbl, int* __restrict__ segdst,
    int* __restrict__ btot, const int* __restrict__ cnt_tbl2,
    int* __restrict__ segdst2, int* __restrict__ btot2, int NCB, int NBLK) {
  __shared__ int s[256];
  int t = threadIdx.x;
  int bid = blockIdx.x;
  const int* __restrict__ ct = (bid < NCB) ? cnt_tbl : cnt_tbl2;
  int* __restrict__ sd = (bid < NCB) ? segdst : segdst2;
  int* __restrict__ bt = (bid < NCB) ? btot : btot2;
  int cb = (bid < NCB) ? bid : bid - NCB;
  int per = (NBLK + 255) / 256;
  int loc[8];
  int sum = 0;
  for (int j = 0; j < per; ++j) {
    int blk = t * per + j;
    int v = (blk < NBLK) ? ct[blk * NCB + cb] : 0;
    loc[j] = sum;
    sum += v;
  }
  s[t] = sum;
  __syncthreads();
#pragma unroll
  for (int o = 1; o < 256; o <<= 1) {
    int xv = (t >= o) ? s[t - o] : 0;
    __syncthreads();
    s[t] += xv;
    __syncthreads();
  }
  int excl = s[t] - sum;
  for (int j = 0; j < per; ++j) {
    int blk = t * per + j;
    if (blk < NBLK) sd[cb * NBLK + blk] = excl + loc[j];
  }
  if (t == 255) bt[cb] = s[255];
}

// ---------------------------------------------------------------------------
// K_segoff_b: tiny single-block exclusive scan over dst bucket totals.
// ---------------------------------------------------------------------------
__global__ __launch_bounds__(512) void k_segoff_b(
    const int* __restrict__ btot, int* __restrict__ coarse_base, int NCB, int Ee) {
  __shared__ int s[512];
  int t = threadIdx.x;
  int v = (t < NCB) ? btot[t] : 0;
  s[t] = v;
  __syncthreads();
#pragma unroll
  for (int o = 1; o < 512; o <<= 1) {
    int xv = (t >= o) ? s[t - o] : 0;
    __syncthreads();
    s[t] += xv;
    __syncthreads();
  }
  if (t < NCB) coarse_base[t] = s[t] - v;
  if (t == 0) coarse_base[NCB] = Ee;
}

// ---------------------------------------------------------------------------
// K_mid: FUSED k_sacc + k_sort (round-9 win), ROUND 11: ONE shared 20KB
// buffer. SORT half drops its staging buffer — two passes over the bucket's
// (L2-warm) global segments: pass A histograms dl directly from rec, pass B
// scatters records straight into SORTED LDS position. LDS 44KB -> ~24KB,
// 3 -> 6 blocks/CU for this latency-bound kernel.
//   blocks [0,NCB):    SACC half — rden = 1/(sum exp + 1e-16)
//   blocks [NCB,2NCB): SORT half — CSR offsets + UNNORMALIZED ea in alpha2
// ---------------------------------------------------------------------------
__global__ __launch_bounds__(256) void k_mid(
    const unsigned int* __restrict__ rec, const int* __restrict__ cnt_tbl,
    const int* __restrict__ base_tbl, const int* __restrict__ segdst,
    const int* __restrict__ coarse_base,
    const unsigned int* __restrict__ rec_src, const int* __restrict__ cnt_tbl2,
    const int* __restrict__ base_tbl2, const int* __restrict__ segdst2,
    const int* __restrict__ btot2,
    const float2* __restrict__ ai2, const float2* __restrict__ aj2,
    const float* __restrict__ att, const float* __restrict__ bemb,
    float* __restrict__ rden, unsigned int* __restrict__ eix2,
    float2* __restrict__ alpha2, int* __restrict__ off,
    int Nn, int NCB, int NBLK, int Ee) {
  __shared__ unsigned ub[SCAP];     // 20 KB — SACC staging / SORT sorted recs
  __shared__ int hist[NPB2], basex[NPB2], curx[NPB2];
  __shared__ float tbl[30];
  __shared__ float2 nodev[NPB2];    // ajs (sacc) / ais (sort)
  __shared__ float sdl[NPB2 * 2];   // sacc accumulators
  int t = threadIdx.x;
  if (t < 30) {
    int f = t / 10, rem = t % 10, c = rem >> 1, hh = rem & 1;
    float sacc = 0.f;
    for (int d = 0; d < 64; ++d)
      sacc += att[hh * 128 + 64 + d] * bemb[(f * 5 + c) * 128 + hh * 64 + d];
    tbl[t] = sacc;
  }

  if (blockIdx.x < NCB) {
    // ------------------------------ SACC half ------------------------------
    int cb = blockIdx.x;
    int node0 = cb << 7;
    if (t < NPB2 && node0 + t < Nn) nodev[t] = aj2[node0 + t];
    sdl[t] = 0.f;
    int total = btot2[cb];
    __syncthreads();
    bool fits = (total <= SCAP);

#define SACC_BODY(U, AIV)                                                      \
    {                                                                          \
      int sl = ((U) >> 17) & 127;                                              \
      int c012 = ((U) >> 24) & 127;                                            \
      int a0 = c012 % 5, a1 = (c012 / 5) % 5, a2 = c012 / 25;                  \
      float2 ajv = nodev[sl];                                                  \
      float lg0 = AIV.x + ajv.x + tbl[a0 * 2] + tbl[10 + a1 * 2] +             \
                  tbl[20 + a2 * 2];                                            \
      float lg1 = AIV.y + ajv.y + tbl[a0 * 2 + 1] + tbl[10 + a1 * 2 + 1] +     \
                  tbl[20 + a2 * 2 + 1];                                        \
      lg0 = lg0 >= 0.f ? lg0 : NEG_SLOPE * lg0;                                \
      lg1 = lg1 >= 0.f ? lg1 : NEG_SLOPE * lg1;                                \
      atomicAdd(&sdl[sl * 2], __expf(lg0));                                    \
      atomicAdd(&sdl[sl * 2 + 1], __expf(lg1));                                \
    }

    if (fits) {
      for (int blk = t; blk < NBLK; blk += 256) {
        int len = cnt_tbl2[blk * NCB + cb];
        if (!len) continue;
        int sp = blk * CHUNK + base_tbl2[blk * NCB + cb];
        int dp = segdst2[cb * NBLK + blk];
        for (int j = 0; j < len; ++j) ub[dp + j] = rec_src[sp + j];
      }
      __syncthreads();
      int i = t;
      for (; i + 7 * 256 < total; i += 8 * 256) {
        unsigned u[8];
        float2 aiv[8];
#pragma unroll
        for (int k = 0; k < 8; ++k) u[k] = ub[i + k * 256];
#pragma unroll
        for (int k = 0; k < 8; ++k) aiv[k] = ai2[u[k] & 0x1FFFF];
#pragma unroll
        for (int k = 0; k < 8; ++k) SACC_BODY(u[k], aiv[k])
      }
      for (; i < total; i += 256) {
        unsigned u = ub[i];
        float2 aiv = ai2[u & 0x1FFFF];
        SACC_BODY(u, aiv)
      }
    } else {
      for (int blk = t; blk < NBLK; blk += 256) {
        int len = cnt_tbl2[blk * NCB + cb];
        int sp = blk * CHUNK + base_tbl2[blk * NCB + cb];
        for (int j = 0; j < len; ++j) {
          unsigned u = rec_src[sp + j];
          float2 aiv = ai2[u & 0x1FFFF];
          SACC_BODY(u, aiv)
        }
      }
    }
#undef SACC_BODY
    __syncthreads();
    if (node0 + (t >> 1) < Nn)
      rden[(size_t)node0 * 2 + t] = 1.0f / (sdl[t] + 1e-16f);

  } else {
    // ------------------------------ SORT half ------------------------------
    int cb = blockIdx.x - NCB;
    int node0 = cb << 7;
    if (t < NPB2) {
      hist[t] = 0;
      if (node0 + t < Nn) nodev[t] = ai2[node0 + t];
    }
    int gbase = coarse_base[cb];
    int total = coarse_base[cb + 1] - gbase;
    __syncthreads();
    bool fits = (total <= SCAP);

    if (fits) {
      // pass A: histogram dl directly from global segments (L2-warm)
      for (int blk = t; blk < NBLK; blk += 256) {
        int len = cnt_tbl[blk * NCB + cb];
        if (!len) continue;
        int sp = blk * CHUNK + base_tbl[blk * NCB + cb];
        for (int j = 0; j < len; ++j)
          atomicAdd(&hist[(rec[sp + j] >> 23) & 127], 1);
      }
      __syncthreads();
      if (t == 0) {
        int s = 0;
        for (int i = 0; i < NPB2; ++i) { basex[i] = s; s += hist[i]; }
      }
      __syncthreads();
      if (t < NPB2) {
        curx[t] = basex[t];
        if (node0 + t < Nn) off[node0 + t] = gbase + basex[t];
      }
      if (cb == 0 && t == 0) off[Nn] = Ee;
      __syncthreads();
      // pass B: re-read segments, scatter straight into SORTED LDS position
      for (int blk = t; blk < NBLK; blk += 256) {
        int len = cnt_tbl[blk * NCB + cb];
        if (!len) continue;
        int sp = blk * CHUNK + base_tbl[blk * NCB + cb];
        for (int j = 0; j < len; ++j) {
          unsigned u = rec[sp + j];
          int pos = atomicAdd(&curx[(u >> 23) & 127], 1);
          ub[pos] = u;
        }
      }
      __syncthreads();

#define OUT_BODY(I, U, AJV)                                                    \
      {                                                                        \
        int src = (U) & 0xFFFF;                                                \
        int c012 = ((U) >> 16) & 127;                                          \
        int dl = ((U) >> 23) & 127;                                            \
        int a0 = c012 % 5, a1 = (c012 / 5) % 5, a2 = c012 / 25;                \
        float2 aiv = nodev[dl];                                                \
        float lg0 = aiv.x + AJV.x + tbl[a0 * 2] + tbl[10 + a1 * 2] +           \
                    tbl[20 + a2 * 2];                                          \
        float lg1 = aiv.y + AJV.y + tbl[a0 * 2 + 1] + tbl[10 + a1 * 2 + 1] +   \
                    tbl[20 + a2 * 2 + 1];                                      \
        lg0 = lg0 >= 0.f ? lg0 : NEG_SLOPE * lg0;                              \
        lg1 = lg1 >= 0.f ? lg1 : NEG_SLOPE * lg1;                              \
        eix2[gbase + (I)] = (unsigned)src | ((unsigned)a0 << 16) |             \
                            ((unsigned)a1 << 19) | ((unsigned)a2 << 22);       \
        alpha2[gbase + (I)] = make_float2(__expf(lg0), __expf(lg1));           \
      }

      int i = t;
      for (; i + 7 * 256 < total; i += 8 * 256) {
        unsigned u[8];
        float2 ajv[8];
#pragma unroll
        for (int k = 0; k < 8; ++k) u[k] = ub[i + k * 256];
#pragma unroll
        for (int k = 0; k < 8; ++k) ajv[k] = aj2[u[k] & 0xFFFF];
#pragma unroll
        for (int k = 0; k < 8; ++k) OUT_BODY(i + k * 256, u[k], ajv[k])
      }
      for (; i < total; i += 256) {
        unsigned u = ub[i];
        float2 ajv = aj2[u & 0xFFFF];
        OUT_BODY(i, u, ajv)
      }
#undef OUT_BODY
    } else {
      // fallback (statistically unreachable): global-read path
      for (int blk = t; blk < NBLK; blk += 256) {
        int len = cnt_tbl[blk * NCB + cb];
        int sp = blk * CHUNK + base_tbl[blk * NCB + cb];
        for (int j = 0; j < len; ++j)
          atomicAdd(&hist[(rec[sp + j] >> 23) & 127], 1);
      }
      __syncthreads();
      if (t == 0) {
        int s = 0;
        for (int i = 0; i < NPB2; ++i) { basex[i] = s; s += hist[i]; }
      }
      __syncthreads();
      if (t < NPB2) {
        curx[t] = basex[t];
        if (node0 + t < Nn) off[node0 + t] = gbase + basex[t];
      }
      if (cb == 0 && t == 0) off[Nn] = Ee;
      __syncthreads();
      for (int blk = t; blk < NBLK; blk += 256) {
        int len = cnt_tbl[blk * NCB + cb];
        int sp = blk * CHUNK + base_tbl[blk * NCB + cb];
        for (int j = 0; j < len; ++j) {
          unsigned u = rec[sp + j];
          int src = u & 0xFFFF;
          int c012 = (u >> 16) & 127;
          int dl = (u >> 23) & 127;
          int a0 = c012 % 5, a1 = (c012 / 5) % 5, a2 = c012 / 25;
          float2 aiv = nodev[dl];
          float2 ajv = aj2[src];
          float lg0 = aiv.x + ajv.x + tbl[a0 * 2] + tbl[10 + a1 * 2] +
                      tbl[20 + a2 * 2];
          float lg1 = aiv.y + ajv.y + tbl[a0 * 2 + 1] + tbl[10 + a1 * 2 + 1] +
                      tbl[20 + a2 * 2 + 1];
          lg0 = lg0 >= 0.f ? lg0 : NEG_SLOPE * lg0;
          lg1 = lg1 >= 0.f ? lg1 : NEG_SLOPE * lg1;
          int pos = gbase + atomicAdd(&curx[dl], 1);
          eix2[pos] = (unsigned)src | ((unsigned)a0 << 16) |
                      ((unsigned)a1 << 19) | ((unsigned)a2 << 22);
          alpha2[pos] = make_float2(__expf(lg0), __expf(lg1));
        }
      }
    }
  }
}

// ---------------------------------------------------------------------------
// K_norm: alpha2[e] *= rden2[src(e)]. Streaming 32 MB + L2-resident random
// rden gathers; 4 edges/thread, uint4/float4 vectorized.
// ---------------------------------------------------------------------------
__global__ __launch_bounds__(256) void k_norm(
    const unsigned int* __restrict__ eix, float2* __restrict__ alpha2,
    const float2* __restrict__ rden2, int Ee) {
  int g = blockIdx.x * 256 + threadIdx.x;
  int e = g * 4;
  if (e + 4 <= Ee) {
    uint4 u = *reinterpret_cast<const uint4*>(&eix[e]);
    float2 rd0 = rden2[u.x & 0xFFFFu];
    float2 rd1 = rden2[u.y & 0xFFFFu];
    float2 rd2 = rden2[u.z & 0xFFFFu];
    float2 rd3 = rden2[u.w & 0xFFFFu];
    float4 a01 = *reinterpret_cast<float4*>(&alpha2[e]);
    float4 a23 = *reinterpret_cast<float4*>(&alpha2[e + 2]);
    a01.x *= rd0.x; a01.y *= rd0.y; a01.z *= rd1.x; a01.w *= rd1.y;
    a23.x *= rd2.x; a23.y *= rd2.y; a23.z *= rd3.x; a23.w *= rd3.y;
    *reinterpret_cast<float4*>(&alpha2[e]) = a01;
    *reinterpret_cast<float4*>(&alpha2[e + 2]) = a23;
  } else {
    for (; e < Ee; ++e) {
      unsigned u = eix[e];
      float2 rd = rden2[u & 0xFFFFu];
      float2 a = alpha2[e];
      alpha2[e] = make_float2(a.x * rd.x, a.y * rd.y);
    }
  }
}

// ---------------------------------------------------------------------------
// K_gather: round-7 body (verified 58.1-58.3us). alpha2 holds FINAL alpha.
// One block of 4 waves per 4 nodes, scalarized uniform loads, myshift shave.
// ---------------------------------------------------------------------------
__global__ __launch_bounds__(256) void k_gather(
    const unsigned int* __restrict__ eix, const float2* __restrict__ alpha2,
    const int* __restrict__ off, const unsigned int* __restrict__ hb,
    const float* __restrict__ bemb, const float* __restrict__ bias,
    float* __restrict__ out, int Nn) {
  __shared__ float bembs[15 * 128];  // [f*5+c][128]
  __shared__ float wsm[4][32];
  int t = threadIdx.x;
  for (int i = t; i < 15 * 128; i += 256) bembs[i] = bemb[i];
  __syncthreads();
  int wave = t >> 6, lane = t & 63;
  int n = blockIdx.x * 4 + wave;
  if (n >= Nn) return;
  int p0 = __builtin_amdgcn_readfirstlane(off[n]);
  int p1 = __builtin_amdgcn_readfirstlane(off[n + 1]);
  int myf = lane / 5;                 // 0..2 for lanes 0..14
  int myc = lane % 5;
  bool active = lane < 15;
  int myshift = 16 + 3 * myf;         // {16,19,22}: a0/a1/a2 bit positions
  int mycEff = active ? myc : 8;      // sel in 0..7 -> 8 never matches
  float w0 = 0.f, w1 = 0.f;
  float acc0 = 0.f, acc1 = 0.f;

#define EDGE_BODY(U, HV, AL)                                                   \
  {                                                                            \
    acc0 = fmaf((AL).x, __uint_as_float((HV) << 16), acc0);                    \
    acc1 = fmaf((AL).y, __uint_as_float((HV) & 0xffff0000u), acc1);            \
    int sel = (int)(((U) >> myshift) & 7u);                                    \
    float m = (sel == mycEff) ? 1.0f : 0.0f;                                   \
    w0 = fmaf(m, (AL).x, w0);                                                  \
    w1 = fmaf(m, (AL).y, w1);                                                  \
  }

  int p = p0;
  for (; p + 8 <= p1; p += 8) {
    unsigned u[8], hv[8];
    float2 al[8];
#pragma unroll
    for (int k = 0; k < 8; ++k) u[k] = eix[p + k];       // uniform -> s_load
#pragma unroll
    for (int k = 0; k < 8; ++k) al[k] = alpha2[p + k];   // uniform -> s_load
#pragma unroll
    for (int k = 0; k < 8; ++k) {
      const unsigned* __restrict__ hrow = hb + ((size_t)(u[k] & 0xFFFFu) << 6);
      hv[k] = hrow[lane];                                // s[base] + v_laneoff
    }
#pragma unroll
    for (int k = 0; k < 8; ++k) EDGE_BODY(u[k], hv[k], al[k])
  }
  for (; p < p1; ++p) {
    unsigned ue = eix[p];
    float2 ale = alpha2[p];
    const unsigned* __restrict__ hrow = hb + ((size_t)(ue & 0xFFFFu) << 6);
    unsigned hve = hrow[lane];
    EDGE_BODY(ue, hve, ale)
  }
#undef EDGE_BODY

  if (active) {
    wsm[wave][lane * 2] = w0;      // same-wave LDS ops are in-order
    wsm[wave][lane * 2 + 1] = w1;
  }
#pragma unroll
  for (int k = 0; k < 15; ++k) {
    acc0 += wsm[wave][k * 2] * bembs[k * 128 + lane];
    acc1 += wsm[wave][k * 2 + 1] * bembs[k * 128 + 64 + lane];
  }
  out[(size_t)n * 64 + lane] = 0.5f * (acc0 + acc1) + bias[lane];
}

extern "C" void kernel_launch(void* const* d_in, const int* in_sizes, int n_in,
                              void* d_out, int out_size, void* d_ws, size_t ws_size,
                              hipStream_t stream) {
  const float* x    = (const float*)d_in[0];
  const int*   ei   = (const int*)d_in[1];
  const int*   eatt = (const int*)d_in[2];
  const float* W    = (const float*)d_in[3];
  const float* bW   = (const float*)d_in[4];
  const float* att  = (const float*)d_in[5];
  const float* bias = (const float*)d_in[6];
  const float* bemb = (const float*)d_in[7];
  int Nn = in_sizes[0] / 64;
  int Ee = in_sizes[1] / 2;
  int NCB = (Nn + NPB2 - 1) / NPB2;            // 391 coarse buckets (128 nodes)
  int NBLK = (Ee + CHUNK - 1) / CHUNK;         // 782 bin blocks

  char* ws = (char*)d_ws;
  ws = (char*)(((uintptr_t)ws + 15) & ~(uintptr_t)15);
  float* aj = (float*)ws;                 ws += (size_t)Nn * 2 * 4;
  float* rden = (float*)ws;               ws += (size_t)Nn * 2 * 4;
  float* ai = (float*)ws;                 ws += (size_t)Nn * 2 * 4;
  unsigned int* hb = (unsigned int*)ws;   ws += (size_t)Nn * 64 * 4;
  unsigned int* rec = (unsigned int*)ws;  ws += (size_t)NBLK * CHUNK * 4;
  unsigned int* rec_src = (unsigned int*)ws; ws += (size_t)NBLK * CHUNK * 4;
  unsigned int* eix2 = (unsigned int*)ws; ws += (size_t)Ee * 4;
  float2* alpha2 = (float2*)ws;           ws += (size_t)Ee * 8;
  int* off = (int*)ws;                    ws += (size_t)(Nn + 1) * 4;
  int* cnt_tbl = (int*)ws;                ws += (size_t)NBLK * NCB * 4;
  int* base_tbl = (int*)ws;               ws += (size_t)NBLK * NCB * 4;
  int* cnt_tbl2 = (int*)ws;               ws += (size_t)NBLK * NCB * 4;
  int* base_tbl2 = (int*)ws;              ws += (size_t)NBLK * NCB * 4;
  int* segdst = (int*)ws;                 ws += (size_t)NCB * NBLK * 4;
  int* segdst2 = (int*)ws;                ws += (size_t)NCB * NBLK * 4;
  int* coarse_base = (int*)ws;            ws += (size_t)(NCB + 1) * 4;
  int* btot = (int*)ws;                   ws += (size_t)NCB * 4;
  int* btot2 = (int*)ws;                  ws += (size_t)NCB * 4;

  k1_gemm<<<1024, 256, 0, stream>>>(x, W, bW, att, hb, ai, aj, Nn);
  k_bin<<<NBLK, 256, 0, stream>>>(ei, eatt, rec, cnt_tbl, base_tbl, rec_src,
                                  cnt_tbl2, base_tbl2, Ee, NCB);
  k_segoff_ab<<<2 * NCB, 256, 0, stream>>>(cnt_tbl, segdst, btot, cnt_tbl2,
                                           segdst2, btot2, NCB, NBLK);
  k_segoff_b<<<1, 512, 0, stream>>>(btot, coarse_base, NCB, Ee);
  k_mid<<<2 * NCB, 256, 0, stream>>>(rec, cnt_tbl, base_tbl, segdst,
                                     coarse_base, rec_src, cnt_tbl2, base_tbl2,
                                     segdst2, btot2, (const float2*)ai,
                                     (const float2*)aj, att, bemb, rden, eix2,
                                     alpha2, off, Nn, NCB, NBLK, Ee);
  k_norm<<<(Ee / 4 + 255) / 256, 256, 0, stream>>>(eix2, alpha2,
                                                   (const float2*)rden, Ee);
  k_gather<<<(Nn + 3) / 4, 256, 0, stream>>>(eix2, alpha2, off, hb, bemb, bias,
                                             (float*)d_out, Nn);
}

// Round 12
// 274.407 us; speedup vs baseline: 1.0548x; 1.0548x over previous
//
#include <hip/hip_runtime.h>
#include <hip/hip_bf16.h>
#include <math.h>

#define NEG_SLOPE 0.2f
#define CHUNK 2048      // edges per k_bin block
#define NPB2 128        // nodes per coarse bucket
#define SCAP 5120       // LDS record capacity (bucket mean ~4092, sd ~64)

__device__ __forceinline__ unsigned f2bf(float f) {
  unsigned u = __float_as_uint(f);
  return (u + 0x7fffu + ((u >> 16) & 1u)) >> 16;  // RNE
}

// ---------------------------------------------------------------------------
// K1: h = x @ W + b_W. Register-stationary: one wave per row, W columns in
// 128 VGPRs, x row via scalar loads, zero LDS. ROUND 12: aj written into the
// combined ajrd float4 table (aj0,aj1,rden0,rden1) — rden filled by k_mid.
// ---------------------------------------------------------------------------
__global__ __launch_bounds__(256) void k1_gemm(
    const float* __restrict__ x, const float* __restrict__ W,
    const float* __restrict__ bW, const float* __restrict__ att,
    unsigned int* __restrict__ hb, float* __restrict__ ai,
    float* __restrict__ ajrd, int Nn) {
  int t = threadIdx.x;
  int lane = t & 63;  // d
  int wid = blockIdx.x * (blockDim.x >> 6) + (t >> 6);
  int nwaves = gridDim.x * (blockDim.x >> 6);

  float Wr0[64], Wr1[64];
#pragma unroll
  for (int k = 0; k < 64; ++k) {
    Wr0[k] = W[k * 128 + lane];
    Wr1[k] = W[k * 128 + 64 + lane];
  }
  float bs0 = bW[lane], bs1 = bW[64 + lane];
  float ati0 = att[lane];
  float atj0 = att[64 + lane];
  float ati1 = att[128 + lane];
  float atj1 = att[192 + lane];

  for (int row = wid; row < Nn; row += nwaves) {
    int r = __builtin_amdgcn_readfirstlane(row);
    const float* __restrict__ xr = x + (size_t)r * 64;
    float a0a = 0.f, a0b = 0.f, a1a = 0.f, a1b = 0.f;
#pragma unroll
    for (int k = 0; k < 64; k += 2) {
      float xk0 = xr[k], xk1 = xr[k + 1];
      a0a = fmaf(xk0, Wr0[k], a0a);
      a1a = fmaf(xk0, Wr1[k], a1a);
      a0b = fmaf(xk1, Wr0[k + 1], a0b);
      a1b = fmaf(xk1, Wr1[k + 1], a1b);
    }
    float h0 = a0a + a0b + bs0;
    float h1 = a1a + a1b + bs1;
    hb[(size_t)r * 64 + lane] = f2bf(h0) | (f2bf(h1) << 16);

    float ti0 = ati0 * h0, tj0 = atj0 * h0;
    float ti1 = ati1 * h1, tj1 = atj1 * h1;
    ti0 += __shfl_xor(ti0, 32, 64);
    tj0 += __shfl_xor(tj0, 32, 64);
    ti1 += __shfl_xor(ti1, 32, 64);
    tj1 += __shfl_xor(tj1, 32, 64);
    float mi = (lane < 32) ? ti0 : ti1;
    float mj = (lane < 32) ? tj0 : tj1;
#pragma unroll
    for (int off = 16; off > 0; off >>= 1) {
      mi += __shfl_xor(mi, off, 64);
      mj += __shfl_xor(mj, off, 64);
    }
    if ((lane & 31) == 0) {
      ai[r * 2 + (lane >> 5)] = mi;
      ajrd[(size_t)r * 4 + (lane >> 5)] = mj;
    }
  }
}

// ---------------------------------------------------------------------------
// K_bin: DUAL multi-split. CHUNK=2048, two private windows (dst-binned rec,
// src-binned rec_src), LDS-staged, sequential flush. Parallel 256-thread
// scans (verified round-6 middle win).
// ---------------------------------------------------------------------------
__global__ __launch_bounds__(256) void k_bin(
    const int* __restrict__ ei, const int* __restrict__ eattr,
    unsigned int* __restrict__ rec, int* __restrict__ cnt_tbl,
    int* __restrict__ base_tbl, unsigned int* __restrict__ rec_src,
    int* __restrict__ cnt_tbl2, int* __restrict__ base_tbl2, int Ee, int NCB) {
  __shared__ unsigned sbuf[CHUNK];   // 8 KB
  __shared__ unsigned sbuf2[CHUNK];  // 8 KB
  __shared__ int hist[512], cur[512], hist2[512], cur2[512];
  __shared__ int ssc[256];
  int t = threadIdx.x;
  for (int i = t; i < NCB; i += 256) { hist[i] = 0; hist2[i] = 0; }
  __syncthreads();
  int start = blockIdx.x * CHUNK;
  int end = min(start + CHUNK, Ee);
  int cnt = end - start;
  int cbv[CHUNK / 256], cb2v[CHUNK / 256];
  unsigned pkv[CHUNK / 256], pk2v[CHUNK / 256];
  int nk = 0;
  for (int e = start + t; e < end; e += 256, ++nk) {
    int dst = __builtin_nontemporal_load(&ei[Ee + e]);
    int src = __builtin_nontemporal_load(&ei[e]);
    int a0 = __builtin_nontemporal_load(&eattr[e * 3]);
    int a1 = __builtin_nontemporal_load(&eattr[e * 3 + 1]);
    int a2 = __builtin_nontemporal_load(&eattr[e * 3 + 2]);
    unsigned c012 = (unsigned)(a0 + 5 * a1 + 25 * a2);
    cbv[nk] = dst >> 7;
    pkv[nk] = (unsigned)src | (c012 << 16) | ((unsigned)(dst & 127) << 23);
    cb2v[nk] = src >> 7;
    pk2v[nk] = (unsigned)dst | ((unsigned)(src & 127) << 17) | (c012 << 24);
    atomicAdd(&hist[dst >> 7], 1);
    atomicAdd(&hist2[src >> 7], 1);
  }
  __syncthreads();
  // parallel exclusive scan: hist -> cur, hist2 -> cur2
  {
    int per = (NCB + 255) / 256;  // 2
    int loc[4];
    int lsum = 0;
#pragma unroll 2
    for (int j = 0; j < per; ++j) {
      int idx = t * per + j;
      int v = (idx < NCB) ? hist[idx] : 0;
      loc[j] = lsum;
      lsum += v;
    }
    ssc[t] = lsum;
    __syncthreads();
#pragma unroll
    for (int o = 1; o < 256; o <<= 1) {
      int xv = (t >= o) ? ssc[t - o] : 0;
      __syncthreads();
      ssc[t] += xv;
      __syncthreads();
    }
    int excl = ssc[t] - lsum;
#pragma unroll 2
    for (int j = 0; j < per; ++j) {
      int idx = t * per + j;
      if (idx < NCB) cur[idx] = excl + loc[j];
    }
    __syncthreads();
    lsum = 0;
#pragma unroll 2
    for (int j = 0; j < per; ++j) {
      int idx = t * per + j;
      int v = (idx < NCB) ? hist2[idx] : 0;
      loc[j] = lsum;
      lsum += v;
    }
    ssc[t] = lsum;
    __syncthreads();
#pragma unroll
    for (int o = 1; o < 256; o <<= 1) {
      int xv = (t >= o) ? ssc[t - o] : 0;
      __syncthreads();
      ssc[t] += xv;
      __syncthreads();
    }
    excl = ssc[t] - lsum;
#pragma unroll 2
    for (int j = 0; j < per; ++j) {
      int idx = t * per + j;
      if (idx < NCB) cur2[idx] = excl + loc[j];
    }
  }
  __syncthreads();
  for (int i = t; i < NCB; i += 256) {
    cnt_tbl[blockIdx.x * NCB + i] = hist[i];
    base_tbl[blockIdx.x * NCB + i] = cur[i];
    cnt_tbl2[blockIdx.x * NCB + i] = hist2[i];
    base_tbl2[blockIdx.x * NCB + i] = cur2[i];
  }
  __syncthreads();
  for (int k = 0; k < nk; ++k) {
    int pos = atomicAdd(&cur[cbv[k]], 1);
    sbuf[pos] = pkv[k];
    int pos2 = atomicAdd(&cur2[cb2v[k]], 1);
    sbuf2[pos2] = pk2v[k];
  }
  __syncthreads();
  for (int i = t; i < cnt; i += 256) {
    __builtin_nontemporal_store(sbuf[i], &rec[start + i]);
    __builtin_nontemporal_store(sbuf2[i], &rec_src[start + i]);
  }
}

// ---------------------------------------------------------------------------
// K_segoff_ab: both per-bucket segment-offset scans in ONE launch.
// ---------------------------------------------------------------------------
__global__ __launch_bounds__(256) void k_segoff_ab(
    const int* __restrict__ cnt_tbl, int* __restrict__ segdst,
    int* __restrict__ btot, const int* __restrict__ cnt_tbl2,
    int* __restrict__ segdst2, int* __restrict__ btot2, int NCB, int NBLK) {
  __shared__ int s[256];
  int t = threadIdx.x;
  int bid = blockIdx.x;
  const int* __restrict__ ct = (bid < NCB) ? cnt_tbl : cnt_tbl2;
  int* __restrict__ sd = (bid < NCB) ? segdst : segdst2;
  int* __restrict__ bt = (bid < NCB) ? btot : btot2;
  int cb = (bid < NCB) ? bid : bid - NCB;
  int per = (NBLK + 255) / 256;
  int loc[8];
  int sum = 0;
  for (int j = 0; j < per; ++j) {
    int blk = t * per + j;
    int v = (blk < NBLK) ? ct[blk * NCB + cb] : 0;
    loc[j] = sum;
    sum += v;
  }
  s[t] = sum;
  __syncthreads();
#pragma unroll
  for (int o = 1; o < 256; o <<= 1) {
    int xv = (t >= o) ? s[t - o] : 0;
    __syncthreads();
    s[t] += xv;
    __syncthreads();
  }
  int excl = s[t] - sum;
  for (int j = 0; j < per; ++j) {
    int blk = t * per + j;
    if (blk < NBLK) sd[cb * NBLK + blk] = excl + loc[j];
  }
  if (t == 255) bt[cb] = s[255];
}

// ---------------------------------------------------------------------------
// K_segoff_b: tiny single-block exclusive scan over dst bucket totals.
// ROUND 12: also precomputes tblg[30] (att·bemb dot products) for k_norm.
// ---------------------------------------------------------------------------
__global__ __launch_bounds__(512) void k_segoff_b(
    const int* __restrict__ btot, int* __restrict__ coarse_base,
    const float* __restrict__ att, const float* __restrict__ bemb,
    float* __restrict__ tblg, int NCB, int Ee) {
  __shared__ int s[512];
  int t = threadIdx.x;
  if (t < 30) {
    int f = t / 10, rem = t % 10, c = rem >> 1, hh = rem & 1;
    float sacc = 0.f;
    for (int d = 0; d < 64; ++d)
      sacc += att[hh * 128 + 64 + d] * bemb[(f * 5 + c) * 128 + hh * 64 + d];
    tblg[t] = sacc;
  }
  int v = (t < NCB) ? btot[t] : 0;
  s[t] = v;
  __syncthreads();
#pragma unroll
  for (int o = 1; o < 512; o <<= 1) {
    int xv = (t >= o) ? s[t - o] : 0;
    __syncthreads();
    s[t] += xv;
    __syncthreads();
  }
  if (t < NCB) coarse_base[t] = s[t] - v;
  if (t == 0) coarse_base[NCB] = Ee;
}

// ---------------------------------------------------------------------------
// K_mid: FUSED k_sacc + k_sort (round-10 structure restored: staged SORT,
// 44KB LDS — occupancy is grid-supply-limited, so LDS doesn't matter).
// ROUND 12: SORT's output phase emits only eix2 (src|a0|a1|a2) and the AI
// PARTIAL (ai[dst] per head) into alpha2 — no aj gathers, no exp. k_norm
// (fully occupied) finishes the logit. SACC writes rden into ajrd[.zw].
// ---------------------------------------------------------------------------
__global__ __launch_bounds__(256) void k_mid(
    const unsigned int* __restrict__ rec, const int* __restrict__ cnt_tbl,
    const int* __restrict__ base_tbl, const int* __restrict__ segdst,
    const int* __restrict__ coarse_base,
    const unsigned int* __restrict__ rec_src, const int* __restrict__ cnt_tbl2,
    const int* __restrict__ base_tbl2, const int* __restrict__ segdst2,
    const int* __restrict__ btot2,
    const float2* __restrict__ ai2, float* __restrict__ ajrd,
    const float* __restrict__ att, const float* __restrict__ bemb,
    unsigned int* __restrict__ eix2, float2* __restrict__ alpha2,
    int* __restrict__ off, int Nn, int NCB, int NBLK, int Ee) {
  __shared__ unsigned ubuf[SCAP];   // 20 KB
  __shared__ unsigned ubuf2[SCAP];  // 20 KB (sort half only)
  __shared__ int hist[NPB2], basex[NPB2], curx[NPB2];
  __shared__ float tbl[30];
  __shared__ float2 nodev[NPB2];    // ajs (sacc) / ais (sort)
  __shared__ float sdl[NPB2 * 2];   // sacc accumulators
  int t = threadIdx.x;
  if (t < 30) {
    int f = t / 10, rem = t % 10, c = rem >> 1, hh = rem & 1;
    float sacc = 0.f;
    for (int d = 0; d < 64; ++d)
      sacc += att[hh * 128 + 64 + d] * bemb[(f * 5 + c) * 128 + hh * 64 + d];
    tbl[t] = sacc;
  }

  if (blockIdx.x < NCB) {
    // ------------------------------ SACC half ------------------------------
    int cb = blockIdx.x;
    int node0 = cb << 7;
    if (t < NPB2 && node0 + t < Nn)
      nodev[t] = *(const float2*)(ajrd + (size_t)(node0 + t) * 4);
    sdl[t] = 0.f;
    int total = btot2[cb];
    __syncthreads();
    bool fits = (total <= SCAP);

#define SACC_BODY(U, AIV)                                                      \
    {                                                                          \
      int sl = ((U) >> 17) & 127;                                              \
      int c012 = ((U) >> 24) & 127;                                            \
      int a0 = c012 % 5, a1 = (c012 / 5) % 5, a2 = c012 / 25;                  \
      float2 ajv = nodev[sl];                                                  \
      float lg0 = AIV.x + ajv.x + tbl[a0 * 2] + tbl[10 + a1 * 2] +             \
                  tbl[20 + a2 * 2];                                            \
      float lg1 = AIV.y + ajv.y + tbl[a0 * 2 + 1] + tbl[10 + a1 * 2 + 1] +     \
                  tbl[20 + a2 * 2 + 1];                                        \
      lg0 = lg0 >= 0.f ? lg0 : NEG_SLOPE * lg0;                                \
      lg1 = lg1 >= 0.f ? lg1 : NEG_SLOPE * lg1;                                \
      atomicAdd(&sdl[sl * 2], __expf(lg0));                                    \
      atomicAdd(&sdl[sl * 2 + 1], __expf(lg1));                                \
    }

    if (fits) {
      for (int blk = t; blk < NBLK; blk += 256) {
        int len = cnt_tbl2[blk * NCB + cb];
        if (!len) continue;
        int sp = blk * CHUNK + base_tbl2[blk * NCB + cb];
        int dp = segdst2[cb * NBLK + blk];
        for (int j = 0; j < len; ++j) ubuf[dp + j] = rec_src[sp + j];
      }
      __syncthreads();
      int i = t;
      for (; i + 7 * 256 < total; i += 8 * 256) {
        unsigned u[8];
        float2 aiv[8];
#pragma unroll
        for (int k = 0; k < 8; ++k) u[k] = ubuf[i + k * 256];
#pragma unroll
        for (int k = 0; k < 8; ++k) aiv[k] = ai2[u[k] & 0x1FFFF];
#pragma unroll
        for (int k = 0; k < 8; ++k) SACC_BODY(u[k], aiv[k])
      }
      for (; i < total; i += 256) {
        unsigned u = ubuf[i];
        float2 aiv = ai2[u & 0x1FFFF];
        SACC_BODY(u, aiv)
      }
    } else {
      for (int blk = t; blk < NBLK; blk += 256) {
        int len = cnt_tbl2[blk * NCB + cb];
        int sp = blk * CHUNK + base_tbl2[blk * NCB + cb];
        for (int j = 0; j < len; ++j) {
          unsigned u = rec_src[sp + j];
          float2 aiv = ai2[u & 0x1FFFF];
          SACC_BODY(u, aiv)
        }
      }
    }
#undef SACC_BODY
    __syncthreads();
    {
      int node = node0 + (t >> 1);
      if (node < Nn)
        ajrd[(size_t)node * 4 + 2 + (t & 1)] = 1.0f / (sdl[t] + 1e-16f);
    }

  } else {
    // ------------------------------ SORT half ------------------------------
    int cb = blockIdx.x - NCB;
    int node0 = cb << 7;
    if (t < NPB2) {
      hist[t] = 0;
      if (node0 + t < Nn) nodev[t] = ai2[node0 + t];
    }
    int gbase = coarse_base[cb];
    int total = coarse_base[cb + 1] - gbase;
    __syncthreads();
    bool fits = (total <= SCAP);

    if (fits) {
      for (int blk = t; blk < NBLK; blk += 256) {
        int len = cnt_tbl[blk * NCB + cb];
        if (!len) continue;
        int sp = blk * CHUNK + base_tbl[blk * NCB + cb];
        int dp = segdst[cb * NBLK + blk];
        for (int j = 0; j < len; ++j) ubuf[dp + j] = rec[sp + j];
      }
      __syncthreads();
      for (int i = t; i < total; i += 256)
        atomicAdd(&hist[(ubuf[i] >> 23) & 127], 1);
      __syncthreads();
      if (t == 0) {
        int s = 0;
        for (int i = 0; i < NPB2; ++i) { basex[i] = s; s += hist[i]; }
      }
      __syncthreads();
      if (t < NPB2) {
        curx[t] = basex[t];
        if (node0 + t < Nn) off[node0 + t] = gbase + basex[t];
      }
      if (cb == 0 && t == 0) off[Nn] = Ee;
      __syncthreads();
      for (int i = t; i < total; i += 256) {
        unsigned u = ubuf[i];
        int pos = atomicAdd(&curx[(u >> 23) & 127], 1);
        ubuf2[pos] = u;
      }
      __syncthreads();
      // output: eix2 + AI-partials only (no gathers, no exp)
      for (int i = t; i < total; i += 256) {
        unsigned u = ubuf2[i];
        int src = u & 0xFFFF;
        int c012 = (u >> 16) & 127;
        int dl = (u >> 23) & 127;
        int a0 = c012 % 5, a1 = (c012 / 5) % 5, a2 = c012 / 25;
        eix2[gbase + i] = (unsigned)src | ((unsigned)a0 << 16) |
                          ((unsigned)a1 << 19) | ((unsigned)a2 << 22);
        alpha2[gbase + i] = nodev[dl];
      }
    } else {
      // fallback (statistically unreachable): global-read path
      for (int blk = t; blk < NBLK; blk += 256) {
        int len = cnt_tbl[blk * NCB + cb];
        int sp = blk * CHUNK + base_tbl[blk * NCB + cb];
        for (int j = 0; j < len; ++j)
          atomicAdd(&hist[(rec[sp + j] >> 23) & 127], 1);
      }
      __syncthreads();
      if (t == 0) {
        int s = 0;
        for (int i = 0; i < NPB2; ++i) { basex[i] = s; s += hist[i]; }
      }
      __syncthreads();
      if (t < NPB2) {
        curx[t] = basex[t];
        if (node0 + t < Nn) off[node0 + t] = gbase + basex[t];
      }
      if (cb == 0 && t == 0) off[Nn] = Ee;
      __syncthreads();
      for (int blk = t; blk < NBLK; blk += 256) {
        int len = cnt_tbl[blk * NCB + cb];
        int sp = blk * CHUNK + base_tbl[blk * NCB + cb];
        for (int j = 0; j < len; ++j) {
          unsigned u = rec[sp + j];
          int src = u & 0xFFFF;
          int c012 = (u >> 16) & 127;
          int dl = (u >> 23) & 127;
          int a0 = c012 % 5, a1 = (c012 / 5) % 5, a2 = c012 / 25;
          int pos = gbase + atomicAdd(&curx[dl], 1);
          eix2[pos] = (unsigned)src | ((unsigned)a0 << 16) |
                      ((unsigned)a1 << 19) | ((unsigned)a2 << 22);
          alpha2[pos] = nodev[dl];
        }
      }
    }
  }
}

// ---------------------------------------------------------------------------
// K_norm (ROUND 12): finishes the logit at FULL occupancy. Per edge:
// one float4 gather ajrd[src] = (aj0,aj1,rden0,rden1), lg = ai_part + aj +
// tbl[attrs], leaky, alpha = exp(lg) * rden. Same add order as before.
// ---------------------------------------------------------------------------
__global__ __launch_bounds__(256) void k_norm(
    const unsigned int* __restrict__ eix, float2* __restrict__ alpha2,
    const float4* __restrict__ ajrd4, const float* __restrict__ tblg, int Ee) {
  __shared__ float tbl[30];
  int t = threadIdx.x;
  if (t < 30) tbl[t] = tblg[t];
  __syncthreads();

#define NORM_BODY(U, A, F, OUT)                                                \
  {                                                                            \
    int a0 = ((U) >> 16) & 7, a1 = ((U) >> 19) & 7, a2 = ((U) >> 22) & 7;      \
    float lg0 = (A).x + (F).x + tbl[a0 * 2] + tbl[10 + a1 * 2] +               \
                tbl[20 + a2 * 2];                                              \
    float lg1 = (A).y + (F).y + tbl[a0 * 2 + 1] + tbl[10 + a1 * 2 + 1] +       \
                tbl[20 + a2 * 2 + 1];                                          \
    lg0 = lg0 >= 0.f ? lg0 : NEG_SLOPE * lg0;                                  \
    lg1 = lg1 >= 0.f ? lg1 : NEG_SLOPE * lg1;                                  \
    OUT = make_float2(__expf(lg0) * (F).z, __expf(lg1) * (F).w);               \
  }

  int g = blockIdx.x * 256 + t;
  int e = g * 4;
  if (e + 4 <= Ee) {
    uint4 u = *reinterpret_cast<const uint4*>(&eix[e]);
    float4 f0 = ajrd4[u.x & 0xFFFFu];
    float4 f1 = ajrd4[u.y & 0xFFFFu];
    float4 f2 = ajrd4[u.z & 0xFFFFu];
    float4 f3 = ajrd4[u.w & 0xFFFFu];
    float2 a0v = alpha2[e], a1v = alpha2[e + 1];
    float2 a2v = alpha2[e + 2], a3v = alpha2[e + 3];
    float2 o0, o1, o2, o3;
    NORM_BODY(u.x, a0v, f0, o0)
    NORM_BODY(u.y, a1v, f1, o1)
    NORM_BODY(u.z, a2v, f2, o2)
    NORM_BODY(u.w, a3v, f3, o3)
    alpha2[e] = o0; alpha2[e + 1] = o1;
    alpha2[e + 2] = o2; alpha2[e + 3] = o3;
  } else {
    for (; e < Ee; ++e) {
      unsigned u = eix[e];
      float4 f = ajrd4[u & 0xFFFFu];
      float2 a = alpha2[e];
      float2 o;
      NORM_BODY(u, a, f, o)
      alpha2[e] = o;
    }
  }
#undef NORM_BODY
}

// ---------------------------------------------------------------------------
// K_gather: round-7 body (verified 58.1-58.3us). alpha2 holds FINAL alpha.
// One block of 4 waves per 4 nodes, scalarized uniform loads, myshift shave.
// ---------------------------------------------------------------------------
__global__ __launch_bounds__(256) void k_gather(
    const unsigned int* __restrict__ eix, const float2* __restrict__ alpha2,
    const int* __restrict__ off, const unsigned int* __restrict__ hb,
    const float* __restrict__ bemb, const float* __restrict__ bias,
    float* __restrict__ out, int Nn) {
  __shared__ float bembs[15 * 128];  // [f*5+c][128]
  __shared__ float wsm[4][32];
  int t = threadIdx.x;
  for (int i = t; i < 15 * 128; i += 256) bembs[i] = bemb[i];
  __syncthreads();
  int wave = t >> 6, lane = t & 63;
  int n = blockIdx.x * 4 + wave;
  if (n >= Nn) return;
  int p0 = __builtin_amdgcn_readfirstlane(off[n]);
  int p1 = __builtin_amdgcn_readfirstlane(off[n + 1]);
  int myf = lane / 5;                 // 0..2 for lanes 0..14
  int myc = lane % 5;
  bool active = lane < 15;
  int myshift = 16 + 3 * myf;         // {16,19,22}: a0/a1/a2 bit positions
  int mycEff = active ? myc : 8;      // sel in 0..7 -> 8 never matches
  float w0 = 0.f, w1 = 0.f;
  float acc0 = 0.f, acc1 = 0.f;

#define EDGE_BODY(U, HV, AL)                                                   \
  {                                                                            \
    acc0 = fmaf((AL).x, __uint_as_float((HV) << 16), acc0);                    \
    acc1 = fmaf((AL).y, __uint_as_float((HV) & 0xffff0000u), acc1);            \
    int sel = (int)(((U) >> myshift) & 7u);                                    \
    float m = (sel == mycEff) ? 1.0f : 0.0f;                                   \
    w0 = fmaf(m, (AL).x, w0);                                                  \
    w1 = fmaf(m, (AL).y, w1);                                                  \
  }

  int p = p0;
  for (; p + 8 <= p1; p += 8) {
    unsigned u[8], hv[8];
    float2 al[8];
#pragma unroll
    for (int k = 0; k < 8; ++k) u[k] = eix[p + k];       // uniform -> s_load
#pragma unroll
    for (int k = 0; k < 8; ++k) al[k] = alpha2[p + k];   // uniform -> s_load
#pragma unroll
    for (int k = 0; k < 8; ++k) {
      const unsigned* __restrict__ hrow = hb + ((size_t)(u[k] & 0xFFFFu) << 6);
      hv[k] = hrow[lane];                                // s[base] + v_laneoff
    }
#pragma unroll
    for (int k = 0; k < 8; ++k) EDGE_BODY(u[k], hv[k], al[k])
  }
  for (; p < p1; ++p) {
    unsigned ue = eix[p];
    float2 ale = alpha2[p];
    const unsigned* __restrict__ hrow = hb + ((size_t)(ue & 0xFFFFu) << 6);
    unsigned hve = hrow[lane];
    EDGE_BODY(ue, hve, ale)
  }
#undef EDGE_BODY

  if (active) {
    wsm[wave][lane * 2] = w0;      // same-wave LDS ops are in-order
    wsm[wave][lane * 2 + 1] = w1;
  }
#pragma unroll
  for (int k = 0; k < 15; ++k) {
    acc0 += wsm[wave][k * 2] * bembs[k * 128 + lane];
    acc1 += wsm[wave][k * 2 + 1] * bembs[k * 128 + 64 + lane];
  }
  out[(size_t)n * 64 + lane] = 0.5f * (acc0 + acc1) + bias[lane];
}

extern "C" void kernel_launch(void* const* d_in, const int* in_sizes, int n_in,
                              void* d_out, int out_size, void* d_ws, size_t ws_size,
                              hipStream_t stream) {
  const float* x    = (const float*)d_in[0];
  const int*   ei   = (const int*)d_in[1];
  const int*   eatt = (const int*)d_in[2];
  const float* W    = (const float*)d_in[3];
  const float* bW   = (const float*)d_in[4];
  const float* att  = (const float*)d_in[5];
  const float* bias = (const float*)d_in[6];
  const float* bemb = (const float*)d_in[7];
  int Nn = in_sizes[0] / 64;
  int Ee = in_sizes[1] / 2;
  int NCB = (Nn + NPB2 - 1) / NPB2;            // 391 coarse buckets (128 nodes)
  int NBLK = (Ee + CHUNK - 1) / CHUNK;         // 782 bin blocks

  char* ws = (char*)d_ws;
  ws = (char*)(((uintptr_t)ws + 15) & ~(uintptr_t)15);
  float* ajrd = (float*)ws;               ws += (size_t)Nn * 4 * 4;  // 16B-aligned
  float* ai = (float*)ws;                 ws += (size_t)Nn * 2 * 4;
  float* tblg = (float*)ws;               ws += 32 * 4;
  unsigned int* hb = (unsigned int*)ws;   ws += (size_t)Nn * 64 * 4;
  unsigned int* rec = (unsigned int*)ws;  ws += (size_t)NBLK * CHUNK * 4;
  unsigned int* rec_src = (unsigned int*)ws; ws += (size_t)NBLK * CHUNK * 4;
  unsigned int* eix2 = (unsigned int*)ws; ws += (size_t)Ee * 4;
  float2* alpha2 = (float2*)ws;           ws += (size_t)Ee * 8;
  int* off = (int*)ws;                    ws += (size_t)(Nn + 1) * 4;
  int* cnt_tbl = (int*)ws;                ws += (size_t)NBLK * NCB * 4;
  int* base_tbl = (int*)ws;               ws += (size_t)NBLK * NCB * 4;
  int* cnt_tbl2 = (int*)ws;               ws += (size_t)NBLK * NCB * 4;
  int* base_tbl2 = (int*)ws;              ws += (size_t)NBLK * NCB * 4;
  int* segdst = (int*)ws;                 ws += (size_t)NCB * NBLK * 4;
  int* segdst2 = (int*)ws;                ws += (size_t)NCB * NBLK * 4;
  int* coarse_base = (int*)ws;            ws += (size_t)(NCB + 1) * 4;
  int* btot = (int*)ws;                   ws += (size_t)NCB * 4;
  int* btot2 = (int*)ws;                  ws += (size_t)NCB * 4;

  k1_gemm<<<1024, 256, 0, stream>>>(x, W, bW, att, hb, ai, ajrd, Nn);
  k_bin<<<NBLK, 256, 0, stream>>>(ei, eatt, rec, cnt_tbl, base_tbl, rec_src,
                                  cnt_tbl2, base_tbl2, Ee, NCB);
  k_segoff_ab<<<2 * NCB, 256, 0, stream>>>(cnt_tbl, segdst, btot, cnt_tbl2,
                                           segdst2, btot2, NCB, NBLK);
  k_segoff_b<<<1, 512, 0, stream>>>(btot, coarse_base, att, bemb, tblg, NCB, Ee);
  k_mid<<<2 * NCB, 256, 0, stream>>>(rec, cnt_tbl, base_tbl, segdst,
                                     coarse_base, rec_src, cnt_tbl2, base_tbl2,
                                     segdst2, btot2, (const float2*)ai, ajrd,
                                     att, bemb, eix2, alpha2, off,
                                     Nn, NCB, NBLK, Ee);
  k_norm<<<(Ee / 4 + 255) / 256, 256, 0, stream>>>(eix2, alpha2,
                                                   (const float4*)ajrd, tblg, Ee);
  k_gather<<<(Nn + 3) / 4, 256, 0, stream>>>(eix2, alpha2, off, hb, bemb, bias,
                                             (float*)d_out, Nn);
}

// Round 13
// 268.736 us; speedup vs baseline: 1.0771x; 1.0211x over previous
//
#include <hip/hip_runtime.h>
#include <hip/hip_bf16.h>
#include <math.h>

#define NEG_SLOPE 0.2f
#define CHUNK 2048      // edges per k_bin block
#define NPB2 128        // nodes per coarse bucket
#define SCAP 5120       // LDS record capacity (bucket mean ~4092, sd ~64)

__device__ __forceinline__ unsigned f2bf(float f) {
  unsigned u = __float_as_uint(f);
  return (u + 0x7fffu + ((u >> 16) & 1u)) >> 16;  // RNE
}

// ---------------------------------------------------------------------------
// K1: h = x @ W + b_W. Register-stationary: one wave per row, W columns in
// 128 VGPRs, x row via scalar loads, zero LDS. aj written into the combined
// ajrd float4 table (aj0,aj1,rden0,rden1) — rden filled by k_mid.
// ---------------------------------------------------------------------------
__global__ __launch_bounds__(256) void k1_gemm(
    const float* __restrict__ x, const float* __restrict__ W,
    const float* __restrict__ bW, const float* __restrict__ att,
    unsigned int* __restrict__ hb, float* __restrict__ ai,
    float* __restrict__ ajrd, int Nn) {
  int t = threadIdx.x;
  int lane = t & 63;  // d
  int wid = blockIdx.x * (blockDim.x >> 6) + (t >> 6);
  int nwaves = gridDim.x * (blockDim.x >> 6);

  float Wr0[64], Wr1[64];
#pragma unroll
  for (int k = 0; k < 64; ++k) {
    Wr0[k] = W[k * 128 + lane];
    Wr1[k] = W[k * 128 + 64 + lane];
  }
  float bs0 = bW[lane], bs1 = bW[64 + lane];
  float ati0 = att[lane];
  float atj0 = att[64 + lane];
  float ati1 = att[128 + lane];
  float atj1 = att[192 + lane];

  for (int row = wid; row < Nn; row += nwaves) {
    int r = __builtin_amdgcn_readfirstlane(row);
    const float* __restrict__ xr = x + (size_t)r * 64;
    float a0a = 0.f, a0b = 0.f, a1a = 0.f, a1b = 0.f;
#pragma unroll
    for (int k = 0; k < 64; k += 2) {
      float xk0 = xr[k], xk1 = xr[k + 1];
      a0a = fmaf(xk0, Wr0[k], a0a);
      a1a = fmaf(xk0, Wr1[k], a1a);
      a0b = fmaf(xk1, Wr0[k + 1], a0b);
      a1b = fmaf(xk1, Wr1[k + 1], a1b);
    }
    float h0 = a0a + a0b + bs0;
    float h1 = a1a + a1b + bs1;
    hb[(size_t)r * 64 + lane] = f2bf(h0) | (f2bf(h1) << 16);

    float ti0 = ati0 * h0, tj0 = atj0 * h0;
    float ti1 = ati1 * h1, tj1 = atj1 * h1;
    ti0 += __shfl_xor(ti0, 32, 64);
    tj0 += __shfl_xor(tj0, 32, 64);
    ti1 += __shfl_xor(ti1, 32, 64);
    tj1 += __shfl_xor(tj1, 32, 64);
    float mi = (lane < 32) ? ti0 : ti1;
    float mj = (lane < 32) ? tj0 : tj1;
#pragma unroll
    for (int off = 16; off > 0; off >>= 1) {
      mi += __shfl_xor(mi, off, 64);
      mj += __shfl_xor(mj, off, 64);
    }
    if ((lane & 31) == 0) {
      ai[r * 2 + (lane >> 5)] = mi;
      ajrd[(size_t)r * 4 + (lane >> 5)] = mj;
    }
  }
}

// ---------------------------------------------------------------------------
// K_bin: DUAL multi-split. CHUNK=2048, two private windows (dst-binned rec,
// src-binned rec_src), LDS-staged, sequential flush. Parallel 256-thread
// scans (verified round-6 middle win).
// ---------------------------------------------------------------------------
__global__ __launch_bounds__(256) void k_bin(
    const int* __restrict__ ei, const int* __restrict__ eattr,
    unsigned int* __restrict__ rec, int* __restrict__ cnt_tbl,
    int* __restrict__ base_tbl, unsigned int* __restrict__ rec_src,
    int* __restrict__ cnt_tbl2, int* __restrict__ base_tbl2, int Ee, int NCB) {
  __shared__ unsigned sbuf[CHUNK];   // 8 KB
  __shared__ unsigned sbuf2[CHUNK];  // 8 KB
  __shared__ int hist[512], cur[512], hist2[512], cur2[512];
  __shared__ int ssc[256];
  int t = threadIdx.x;
  for (int i = t; i < NCB; i += 256) { hist[i] = 0; hist2[i] = 0; }
  __syncthreads();
  int start = blockIdx.x * CHUNK;
  int end = min(start + CHUNK, Ee);
  int cnt = end - start;
  int cbv[CHUNK / 256], cb2v[CHUNK / 256];
  unsigned pkv[CHUNK / 256], pk2v[CHUNK / 256];
  int nk = 0;
  for (int e = start + t; e < end; e += 256, ++nk) {
    int dst = __builtin_nontemporal_load(&ei[Ee + e]);
    int src = __builtin_nontemporal_load(&ei[e]);
    int a0 = __builtin_nontemporal_load(&eattr[e * 3]);
    int a1 = __builtin_nontemporal_load(&eattr[e * 3 + 1]);
    int a2 = __builtin_nontemporal_load(&eattr[e * 3 + 2]);
    unsigned c012 = (unsigned)(a0 + 5 * a1 + 25 * a2);
    cbv[nk] = dst >> 7;
    pkv[nk] = (unsigned)src | (c012 << 16) | ((unsigned)(dst & 127) << 23);
    cb2v[nk] = src >> 7;
    pk2v[nk] = (unsigned)dst | ((unsigned)(src & 127) << 17) | (c012 << 24);
    atomicAdd(&hist[dst >> 7], 1);
    atomicAdd(&hist2[src >> 7], 1);
  }
  __syncthreads();
  // parallel exclusive scan: hist -> cur, hist2 -> cur2
  {
    int per = (NCB + 255) / 256;  // 2
    int loc[4];
    int lsum = 0;
#pragma unroll 2
    for (int j = 0; j < per; ++j) {
      int idx = t * per + j;
      int v = (idx < NCB) ? hist[idx] : 0;
      loc[j] = lsum;
      lsum += v;
    }
    ssc[t] = lsum;
    __syncthreads();
#pragma unroll
    for (int o = 1; o < 256; o <<= 1) {
      int xv = (t >= o) ? ssc[t - o] : 0;
      __syncthreads();
      ssc[t] += xv;
      __syncthreads();
    }
    int excl = ssc[t] - lsum;
#pragma unroll 2
    for (int j = 0; j < per; ++j) {
      int idx = t * per + j;
      if (idx < NCB) cur[idx] = excl + loc[j];
    }
    __syncthreads();
    lsum = 0;
#pragma unroll 2
    for (int j = 0; j < per; ++j) {
      int idx = t * per + j;
      int v = (idx < NCB) ? hist2[idx] : 0;
      loc[j] = lsum;
      lsum += v;
    }
    ssc[t] = lsum;
    __syncthreads();
#pragma unroll
    for (int o = 1; o < 256; o <<= 1) {
      int xv = (t >= o) ? ssc[t - o] : 0;
      __syncthreads();
      ssc[t] += xv;
      __syncthreads();
    }
    excl = ssc[t] - lsum;
#pragma unroll 2
    for (int j = 0; j < per; ++j) {
      int idx = t * per + j;
      if (idx < NCB) cur2[idx] = excl + loc[j];
    }
  }
  __syncthreads();
  for (int i = t; i < NCB; i += 256) {
    cnt_tbl[blockIdx.x * NCB + i] = hist[i];
    base_tbl[blockIdx.x * NCB + i] = cur[i];
    cnt_tbl2[blockIdx.x * NCB + i] = hist2[i];
    base_tbl2[blockIdx.x * NCB + i] = cur2[i];
  }
  __syncthreads();
  for (int k = 0; k < nk; ++k) {
    int pos = atomicAdd(&cur[cbv[k]], 1);
    sbuf[pos] = pkv[k];
    int pos2 = atomicAdd(&cur2[cb2v[k]], 1);
    sbuf2[pos2] = pk2v[k];
  }
  __syncthreads();
  for (int i = t; i < cnt; i += 256) {
    __builtin_nontemporal_store(sbuf[i], &rec[start + i]);
    __builtin_nontemporal_store(sbuf2[i], &rec_src[start + i]);
  }
}

// ---------------------------------------------------------------------------
// K_segoff_ab: both per-bucket segment-offset scans in ONE launch.
// ---------------------------------------------------------------------------
__global__ __launch_bounds__(256) void k_segoff_ab(
    const int* __restrict__ cnt_tbl, int* __restrict__ segdst,
    int* __restrict__ btot, const int* __restrict__ cnt_tbl2,
    int* __restrict__ segdst2, int* __restrict__ btot2, int NCB, int NBLK) {
  __shared__ int s[256];
  int t = threadIdx.x;
  int bid = blockIdx.x;
  const int* __restrict__ ct = (bid < NCB) ? cnt_tbl : cnt_tbl2;
  int* __restrict__ sd = (bid < NCB) ? segdst : segdst2;
  int* __restrict__ bt = (bid < NCB) ? btot : btot2;
  int cb = (bid < NCB) ? bid : bid - NCB;
  int per = (NBLK + 255) / 256;
  int loc[8];
  int sum = 0;
  for (int j = 0; j < per; ++j) {
    int blk = t * per + j;
    int v = (blk < NBLK) ? ct[blk * NCB + cb] : 0;
    loc[j] = sum;
    sum += v;
  }
  s[t] = sum;
  __syncthreads();
#pragma unroll
  for (int o = 1; o < 256; o <<= 1) {
    int xv = (t >= o) ? s[t - o] : 0;
    __syncthreads();
    s[t] += xv;
    __syncthreads();
  }
  int excl = s[t] - sum;
  for (int j = 0; j < per; ++j) {
    int blk = t * per + j;
    if (blk < NBLK) sd[cb * NBLK + blk] = excl + loc[j];
  }
  if (t == 255) bt[cb] = s[255];
}

// ---------------------------------------------------------------------------
// K_segoff_b: tiny single-block exclusive scan over dst bucket totals.
// Also precomputes tblg[30] (att·bemb dot products) for k_norm.
// ---------------------------------------------------------------------------
__global__ __launch_bounds__(512) void k_segoff_b(
    const int* __restrict__ btot, int* __restrict__ coarse_base,
    const float* __restrict__ att, const float* __restrict__ bemb,
    float* __restrict__ tblg, int NCB, int Ee) {
  __shared__ int s[512];
  int t = threadIdx.x;
  if (t < 30) {
    int f = t / 10, rem = t % 10, c = rem >> 1, hh = rem & 1;
    float sacc = 0.f;
    for (int d = 0; d < 64; ++d)
      sacc += att[hh * 128 + 64 + d] * bemb[(f * 5 + c) * 128 + hh * 64 + d];
    tblg[t] = sacc;
  }
  int v = (t < NCB) ? btot[t] : 0;
  s[t] = v;
  __syncthreads();
#pragma unroll
  for (int o = 1; o < 512; o <<= 1) {
    int xv = (t >= o) ? s[t - o] : 0;
    __syncthreads();
    s[t] += xv;
    __syncthreads();
  }
  if (t < NCB) coarse_base[t] = s[t] - v;
  if (t == 0) coarse_base[NCB] = Ee;
}

// ---------------------------------------------------------------------------
// K_mid: FUSED k_sacc + k_sort. ROUND 13: 512 THREADS/BLOCK — grid supply
// (782 blocks ~= 3/CU) caps block count, so add waves per block instead:
// 12 -> 24 waves/CU at unchanged 44KB LDS (still 3 blocks/CU, VGPR 68 ok).
// SORT emits eix2 + AI partials (k_norm finishes); SACC writes rden.
// ---------------------------------------------------------------------------
__global__ __launch_bounds__(512) void k_mid(
    const unsigned int* __restrict__ rec, const int* __restrict__ cnt_tbl,
    const int* __restrict__ base_tbl, const int* __restrict__ segdst,
    const int* __restrict__ coarse_base,
    const unsigned int* __restrict__ rec_src, const int* __restrict__ cnt_tbl2,
    const int* __restrict__ base_tbl2, const int* __restrict__ segdst2,
    const int* __restrict__ btot2,
    const float2* __restrict__ ai2, float* __restrict__ ajrd,
    const float* __restrict__ att, const float* __restrict__ bemb,
    unsigned int* __restrict__ eix2, float2* __restrict__ alpha2,
    int* __restrict__ off, int Nn, int NCB, int NBLK, int Ee) {
  __shared__ unsigned ubuf[SCAP];   // 20 KB
  __shared__ unsigned ubuf2[SCAP];  // 20 KB (sort half only)
  __shared__ int hist[NPB2], basex[NPB2], curx[NPB2];
  __shared__ float tbl[30];
  __shared__ float2 nodev[NPB2];    // ajs (sacc) / ais (sort)
  __shared__ float sdl[NPB2 * 2];   // sacc accumulators
  int t = threadIdx.x;
  if (t < 30) {
    int f = t / 10, rem = t % 10, c = rem >> 1, hh = rem & 1;
    float sacc = 0.f;
    for (int d = 0; d < 64; ++d)
      sacc += att[hh * 128 + 64 + d] * bemb[(f * 5 + c) * 128 + hh * 64 + d];
    tbl[t] = sacc;
  }

  if (blockIdx.x < NCB) {
    // ------------------------------ SACC half ------------------------------
    int cb = blockIdx.x;
    int node0 = cb << 7;
    if (t < NPB2 && node0 + t < Nn)
      nodev[t] = *(const float2*)(ajrd + (size_t)(node0 + t) * 4);
    if (t < NPB2 * 2) sdl[t] = 0.f;
    int total = btot2[cb];
    __syncthreads();
    bool fits = (total <= SCAP);

#define SACC_BODY(U, AIV)                                                      \
    {                                                                          \
      int sl = ((U) >> 17) & 127;                                              \
      int c012 = ((U) >> 24) & 127;                                            \
      int a0 = c012 % 5, a1 = (c012 / 5) % 5, a2 = c012 / 25;                  \
      float2 ajv = nodev[sl];                                                  \
      float lg0 = AIV.x + ajv.x + tbl[a0 * 2] + tbl[10 + a1 * 2] +             \
                  tbl[20 + a2 * 2];                                            \
      float lg1 = AIV.y + ajv.y + tbl[a0 * 2 + 1] + tbl[10 + a1 * 2 + 1] +     \
                  tbl[20 + a2 * 2 + 1];                                        \
      lg0 = lg0 >= 0.f ? lg0 : NEG_SLOPE * lg0;                                \
      lg1 = lg1 >= 0.f ? lg1 : NEG_SLOPE * lg1;                                \
      atomicAdd(&sdl[sl * 2], __expf(lg0));                                    \
      atomicAdd(&sdl[sl * 2 + 1], __expf(lg1));                                \
    }

    if (fits) {
      for (int blk = t; blk < NBLK; blk += 512) {
        int len = cnt_tbl2[blk * NCB + cb];
        if (!len) continue;
        int sp = blk * CHUNK + base_tbl2[blk * NCB + cb];
        int dp = segdst2[cb * NBLK + blk];
        for (int j = 0; j < len; ++j) ubuf[dp + j] = rec_src[sp + j];
      }
      __syncthreads();
      int i = t;
      for (; i + 7 * 512 < total; i += 8 * 512) {
        unsigned u[8];
        float2 aiv[8];
#pragma unroll
        for (int k = 0; k < 8; ++k) u[k] = ubuf[i + k * 512];
#pragma unroll
        for (int k = 0; k < 8; ++k) aiv[k] = ai2[u[k] & 0x1FFFF];
#pragma unroll
        for (int k = 0; k < 8; ++k) SACC_BODY(u[k], aiv[k])
      }
      for (; i < total; i += 512) {
        unsigned u = ubuf[i];
        float2 aiv = ai2[u & 0x1FFFF];
        SACC_BODY(u, aiv)
      }
    } else {
      for (int blk = t; blk < NBLK; blk += 512) {
        int len = cnt_tbl2[blk * NCB + cb];
        int sp = blk * CHUNK + base_tbl2[blk * NCB + cb];
        for (int j = 0; j < len; ++j) {
          unsigned u = rec_src[sp + j];
          float2 aiv = ai2[u & 0x1FFFF];
          SACC_BODY(u, aiv)
        }
      }
    }
#undef SACC_BODY
    __syncthreads();
    if (t < NPB2 * 2) {
      int node = node0 + (t >> 1);
      if (node < Nn)
        ajrd[(size_t)node * 4 + 2 + (t & 1)] = 1.0f / (sdl[t] + 1e-16f);
    }

  } else {
    // ------------------------------ SORT half ------------------------------
    int cb = blockIdx.x - NCB;
    int node0 = cb << 7;
    if (t < NPB2) {
      hist[t] = 0;
      if (node0 + t < Nn) nodev[t] = ai2[node0 + t];
    }
    int gbase = coarse_base[cb];
    int total = coarse_base[cb + 1] - gbase;
    __syncthreads();
    bool fits = (total <= SCAP);

    if (fits) {
      for (int blk = t; blk < NBLK; blk += 512) {
        int len = cnt_tbl[blk * NCB + cb];
        if (!len) continue;
        int sp = blk * CHUNK + base_tbl[blk * NCB + cb];
        int dp = segdst[cb * NBLK + blk];
        for (int j = 0; j < len; ++j) ubuf[dp + j] = rec[sp + j];
      }
      __syncthreads();
      for (int i = t; i < total; i += 512)
        atomicAdd(&hist[(ubuf[i] >> 23) & 127], 1);
      __syncthreads();
      if (t == 0) {
        int s = 0;
        for (int i = 0; i < NPB2; ++i) { basex[i] = s; s += hist[i]; }
      }
      __syncthreads();
      if (t < NPB2) {
        curx[t] = basex[t];
        if (node0 + t < Nn) off[node0 + t] = gbase + basex[t];
      }
      if (cb == 0 && t == 0) off[Nn] = Ee;
      __syncthreads();
      for (int i = t; i < total; i += 512) {
        unsigned u = ubuf[i];
        int pos = atomicAdd(&curx[(u >> 23) & 127], 1);
        ubuf2[pos] = u;
      }
      __syncthreads();
      // output: eix2 + AI-partials only (no gathers, no exp)
      for (int i = t; i < total; i += 512) {
        unsigned u = ubuf2[i];
        int src = u & 0xFFFF;
        int c012 = (u >> 16) & 127;
        int dl = (u >> 23) & 127;
        int a0 = c012 % 5, a1 = (c012 / 5) % 5, a2 = c012 / 25;
        eix2[gbase + i] = (unsigned)src | ((unsigned)a0 << 16) |
                          ((unsigned)a1 << 19) | ((unsigned)a2 << 22);
        alpha2[gbase + i] = nodev[dl];
      }
    } else {
      // fallback (statistically unreachable): global-read path
      for (int blk = t; blk < NBLK; blk += 512) {
        int len = cnt_tbl[blk * NCB + cb];
        int sp = blk * CHUNK + base_tbl[blk * NCB + cb];
        for (int j = 0; j < len; ++j)
          atomicAdd(&hist[(rec[sp + j] >> 23) & 127], 1);
      }
      __syncthreads();
      if (t == 0) {
        int s = 0;
        for (int i = 0; i < NPB2; ++i) { basex[i] = s; s += hist[i]; }
      }
      __syncthreads();
      if (t < NPB2) {
        curx[t] = basex[t];
        if (node0 + t < Nn) off[node0 + t] = gbase + basex[t];
      }
      if (cb == 0 && t == 0) off[Nn] = Ee;
      __syncthreads();
      for (int blk = t; blk < NBLK; blk += 512) {
        int len = cnt_tbl[blk * NCB + cb];
        int sp = blk * CHUNK + base_tbl[blk * NCB + cb];
        for (int j = 0; j < len; ++j) {
          unsigned u = rec[sp + j];
          int src = u & 0xFFFF;
          int c012 = (u >> 16) & 127;
          int dl = (u >> 23) & 127;
          int a0 = c012 % 5, a1 = (c012 / 5) % 5, a2 = c012 / 25;
          int pos = gbase + atomicAdd(&curx[dl], 1);
          eix2[pos] = (unsigned)src | ((unsigned)a0 << 16) |
                      ((unsigned)a1 << 19) | ((unsigned)a2 << 22);
          alpha2[pos] = nodev[dl];
        }
      }
    }
  }
}

// ---------------------------------------------------------------------------
// K_norm: finishes the logit at FULL occupancy. Per edge: one float4 gather
// ajrd[src] = (aj0,aj1,rden0,rden1), lg = ai_part + aj + tbl[attrs], leaky,
// alpha = exp(lg) * rden. Same add order as the fused version.
// ---------------------------------------------------------------------------
__global__ __launch_bounds__(256) void k_norm(
    const unsigned int* __restrict__ eix, float2* __restrict__ alpha2,
    const float4* __restrict__ ajrd4, const float* __restrict__ tblg, int Ee) {
  __shared__ float tbl[30];
  int t = threadIdx.x;
  if (t < 30) tbl[t] = tblg[t];
  __syncthreads();

#define NORM_BODY(U, A, F, OUT)                                                \
  {                                                                            \
    int a0 = ((U) >> 16) & 7, a1 = ((U) >> 19) & 7, a2 = ((U) >> 22) & 7;      \
    float lg0 = (A).x + (F).x + tbl[a0 * 2] + tbl[10 + a1 * 2] +               \
                tbl[20 + a2 * 2];                                              \
    float lg1 = (A).y + (F).y + tbl[a0 * 2 + 1] + tbl[10 + a1 * 2 + 1] +       \
                tbl[20 + a2 * 2 + 1];                                          \
    lg0 = lg0 >= 0.f ? lg0 : NEG_SLOPE * lg0;                                  \
    lg1 = lg1 >= 0.f ? lg1 : NEG_SLOPE * lg1;                                  \
    OUT = make_float2(__expf(lg0) * (F).z, __expf(lg1) * (F).w);               \
  }

  int g = blockIdx.x * 256 + t;
  int e = g * 4;
  if (e + 4 <= Ee) {
    uint4 u = *reinterpret_cast<const uint4*>(&eix[e]);
    float4 f0 = ajrd4[u.x & 0xFFFFu];
    float4 f1 = ajrd4[u.y & 0xFFFFu];
    float4 f2 = ajrd4[u.z & 0xFFFFu];
    float4 f3 = ajrd4[u.w & 0xFFFFu];
    float2 a0v = alpha2[e], a1v = alpha2[e + 1];
    float2 a2v = alpha2[e + 2], a3v = alpha2[e + 3];
    float2 o0, o1, o2, o3;
    NORM_BODY(u.x, a0v, f0, o0)
    NORM_BODY(u.y, a1v, f1, o1)
    NORM_BODY(u.z, a2v, f2, o2)
    NORM_BODY(u.w, a3v, f3, o3)
    alpha2[e] = o0; alpha2[e + 1] = o1;
    alpha2[e + 2] = o2; alpha2[e + 3] = o3;
  } else {
    for (; e < Ee; ++e) {
      unsigned u = eix[e];
      float4 f = ajrd4[u & 0xFFFFu];
      float2 a = alpha2[e];
      float2 o;
      NORM_BODY(u, a, f, o)
      alpha2[e] = o;
    }
  }
#undef NORM_BODY
}

// ---------------------------------------------------------------------------
// K_gather: round-7 body (verified 58.1-58.3us). alpha2 holds FINAL alpha.
// One block of 4 waves per 4 nodes, scalarized uniform loads, myshift shave.
// ---------------------------------------------------------------------------
__global__ __launch_bounds__(256) void k_gather(
    const unsigned int* __restrict__ eix, const float2* __restrict__ alpha2,
    const int* __restrict__ off, const unsigned int* __restrict__ hb,
    const float* __restrict__ bemb, const float* __restrict__ bias,
    float* __restrict__ out, int Nn) {
  __shared__ float bembs[15 * 128];  // [f*5+c][128]
  __shared__ float wsm[4][32];
  int t = threadIdx.x;
  for (int i = t; i < 15 * 128; i += 256) bembs[i] = bemb[i];
  __syncthreads();
  int wave = t >> 6, lane = t & 63;
  int n = blockIdx.x * 4 + wave;
  if (n >= Nn) return;
  int p0 = __builtin_amdgcn_readfirstlane(off[n]);
  int p1 = __builtin_amdgcn_readfirstlane(off[n + 1]);
  int myf = lane / 5;                 // 0..2 for lanes 0..14
  int myc = lane % 5;
  bool active = lane < 15;
  int myshift = 16 + 3 * myf;         // {16,19,22}: a0/a1/a2 bit positions
  int mycEff = active ? myc : 8;      // sel in 0..7 -> 8 never matches
  float w0 = 0.f, w1 = 0.f;
  float acc0 = 0.f, acc1 = 0.f;

#define EDGE_BODY(U, HV, AL)                                                   \
  {                                                                            \
    acc0 = fmaf((AL).x, __uint_as_float((HV) << 16), acc0);                    \
    acc1 = fmaf((AL).y, __uint_as_float((HV) & 0xffff0000u), acc1);            \
    int sel = (int)(((U) >> myshift) & 7u);                                    \
    float m = (sel == mycEff) ? 1.0f : 0.0f;                                   \
    w0 = fmaf(m, (AL).x, w0);                                                  \
    w1 = fmaf(m, (AL).y, w1);                                                  \
  }

  int p = p0;
  for (; p + 8 <= p1; p += 8) {
    unsigned u[8], hv[8];
    float2 al[8];
#pragma unroll
    for (int k = 0; k < 8; ++k) u[k] = eix[p + k];       // uniform -> s_load
#pragma unroll
    for (int k = 0; k < 8; ++k) al[k] = alpha2[p + k];   // uniform -> s_load
#pragma unroll
    for (int k = 0; k < 8; ++k) {
      const unsigned* __restrict__ hrow = hb + ((size_t)(u[k] & 0xFFFFu) << 6);
      hv[k] = hrow[lane];                                // s[base] + v_laneoff
    }
#pragma unroll
    for (int k = 0; k < 8; ++k) EDGE_BODY(u[k], hv[k], al[k])
  }
  for (; p < p1; ++p) {
    unsigned ue = eix[p];
    float2 ale = alpha2[p];
    const unsigned* __restrict__ hrow = hb + ((size_t)(ue & 0xFFFFu) << 6);
    unsigned hve = hrow[lane];
    EDGE_BODY(ue, hve, ale)
  }
#undef EDGE_BODY

  if (active) {
    wsm[wave][lane * 2] = w0;      // same-wave LDS ops are in-order
    wsm[wave][lane * 2 + 1] = w1;
  }
#pragma unroll
  for (int k = 0; k < 15; ++k) {
    acc0 += wsm[wave][k * 2] * bembs[k * 128 + lane];
    acc1 += wsm[wave][k * 2 + 1] * bembs[k * 128 + 64 + lane];
  }
  out[(size_t)n * 64 + lane] = 0.5f * (acc0 + acc1) + bias[lane];
}

extern "C" void kernel_launch(void* const* d_in, const int* in_sizes, int n_in,
                              void* d_out, int out_size, void* d_ws, size_t ws_size,
                              hipStream_t stream) {
  const float* x    = (const float*)d_in[0];
  const int*   ei   = (const int*)d_in[1];
  const int*   eatt = (const int*)d_in[2];
  const float* W    = (const float*)d_in[3];
  const float* bW   = (const float*)d_in[4];
  const float* att  = (const float*)d_in[5];
  const float* bias = (const float*)d_in[6];
  const float* bemb = (const float*)d_in[7];
  int Nn = in_sizes[0] / 64;
  int Ee = in_sizes[1] / 2;
  int NCB = (Nn + NPB2 - 1) / NPB2;            // 391 coarse buckets (128 nodes)
  int NBLK = (Ee + CHUNK - 1) / CHUNK;         // 782 bin blocks

  char* ws = (char*)d_ws;
  ws = (char*)(((uintptr_t)ws + 15) & ~(uintptr_t)15);
  float* ajrd = (float*)ws;               ws += (size_t)Nn * 4 * 4;  // 16B-aligned
  float* ai = (float*)ws;                 ws += (size_t)Nn * 2 * 4;
  float* tblg = (float*)ws;               ws += 32 * 4;
  unsigned int* hb = (unsigned int*)ws;   ws += (size_t)Nn * 64 * 4;
  unsigned int* rec = (unsigned int*)ws;  ws += (size_t)NBLK * CHUNK * 4;
  unsigned int* rec_src = (unsigned int*)ws; ws += (size_t)NBLK * CHUNK * 4;
  unsigned int* eix2 = (unsigned int*)ws; ws += (size_t)Ee * 4;
  float2* alpha2 = (float2*)ws;           ws += (size_t)Ee * 8;
  int* off = (int*)ws;                    ws += (size_t)(Nn + 1) * 4;
  int* cnt_tbl = (int*)ws;                ws += (size_t)NBLK * NCB * 4;
  int* base_tbl = (int*)ws;               ws += (size_t)NBLK * NCB * 4;
  int* cnt_tbl2 = (int*)ws;               ws += (size_t)NBLK * NCB * 4;
  int* base_tbl2 = (int*)ws;              ws += (size_t)NBLK * NCB * 4;
  int* segdst = (int*)ws;                 ws += (size_t)NCB * NBLK * 4;
  int* segdst2 = (int*)ws;                ws += (size_t)NCB * NBLK * 4;
  int* coarse_base = (int*)ws;            ws += (size_t)(NCB + 1) * 4;
  int* btot = (int*)ws;                   ws += (size_t)NCB * 4;
  int* btot2 = (int*)ws;                  ws += (size_t)NCB * 4;

  k1_gemm<<<1024, 256, 0, stream>>>(x, W, bW, att, hb, ai, ajrd, Nn);
  k_bin<<<NBLK, 256, 0, stream>>>(ei, eatt, rec, cnt_tbl, base_tbl, rec_src,
                                  cnt_tbl2, base_tbl2, Ee, NCB);
  k_segoff_ab<<<2 * NCB, 256, 0, stream>>>(cnt_tbl, segdst, btot, cnt_tbl2,
                                           segdst2, btot2, NCB, NBLK);
  k_segoff_b<<<1, 512, 0, stream>>>(btot, coarse_base, att, bemb, tblg, NCB, Ee);
  k_mid<<<2 * NCB, 512, 0, stream>>>(rec, cnt_tbl, base_tbl, segdst,
                                     coarse_base, rec_src, cnt_tbl2, base_tbl2,
                                     segdst2, btot2, (const float2*)ai, ajrd,
                                     att, bemb, eix2, alpha2, off,
                                     Nn, NCB, NBLK, Ee);
  k_norm<<<(Ee / 4 + 255) / 256, 256, 0, stream>>>(eix2, alpha2,
                                                   (const float4*)ajrd, tblg, Ee);
  k_gather<<<(Nn + 3) / 4, 256, 0, stream>>>(eix2, alpha2, off, hb, bemb, bias,
                                             (float*)d_out, Nn);
}

// Round 14
// 267.174 us; speedup vs baseline: 1.0834x; 1.0058x over previous
//
#include <hip/hip_runtime.h>
#include <hip/hip_bf16.h>
#include <math.h>

#define NEG_SLOPE 0.2f
#define CHUNK 2048      // edges per k_bin block
#define NPB2 128        // nodes per coarse bucket
#define SCAP 5120       // LDS record capacity (bucket mean ~4092, sd ~64)

__device__ __forceinline__ unsigned f2bf(float f) {
  unsigned u = __float_as_uint(f);
  return (u + 0x7fffu + ((u >> 16) & 1u)) >> 16;  // RNE
}

// ---------------------------------------------------------------------------
// K1: h = x @ W + b_W. Register-stationary: one wave per row, W columns in
// 128 VGPRs, x row via scalar loads, zero LDS. aj written into the combined
// ajrd float4 table (aj0,aj1,rden0,rden1) — rden filled by k_mid.
// ---------------------------------------------------------------------------
__global__ __launch_bounds__(256) void k1_gemm(
    const float* __restrict__ x, const float* __restrict__ W,
    const float* __restrict__ bW, const float* __restrict__ att,
    unsigned int* __restrict__ hb, float* __restrict__ ai,
    float* __restrict__ ajrd, int Nn) {
  int t = threadIdx.x;
  int lane = t & 63;  // d
  int wid = blockIdx.x * (blockDim.x >> 6) + (t >> 6);
  int nwaves = gridDim.x * (blockDim.x >> 6);

  float Wr0[64], Wr1[64];
#pragma unroll
  for (int k = 0; k < 64; ++k) {
    Wr0[k] = W[k * 128 + lane];
    Wr1[k] = W[k * 128 + 64 + lane];
  }
  float bs0 = bW[lane], bs1 = bW[64 + lane];
  float ati0 = att[lane];
  float atj0 = att[64 + lane];
  float ati1 = att[128 + lane];
  float atj1 = att[192 + lane];

  for (int row = wid; row < Nn; row += nwaves) {
    int r = __builtin_amdgcn_readfirstlane(row);
    const float* __restrict__ xr = x + (size_t)r * 64;
    float a0a = 0.f, a0b = 0.f, a1a = 0.f, a1b = 0.f;
#pragma unroll
    for (int k = 0; k < 64; k += 2) {
      float xk0 = xr[k], xk1 = xr[k + 1];
      a0a = fmaf(xk0, Wr0[k], a0a);
      a1a = fmaf(xk0, Wr1[k], a1a);
      a0b = fmaf(xk1, Wr0[k + 1], a0b);
      a1b = fmaf(xk1, Wr1[k + 1], a1b);
    }
    float h0 = a0a + a0b + bs0;
    float h1 = a1a + a1b + bs1;
    hb[(size_t)r * 64 + lane] = f2bf(h0) | (f2bf(h1) << 16);

    float ti0 = ati0 * h0, tj0 = atj0 * h0;
    float ti1 = ati1 * h1, tj1 = atj1 * h1;
    ti0 += __shfl_xor(ti0, 32, 64);
    tj0 += __shfl_xor(tj0, 32, 64);
    ti1 += __shfl_xor(ti1, 32, 64);
    tj1 += __shfl_xor(tj1, 32, 64);
    float mi = (lane < 32) ? ti0 : ti1;
    float mj = (lane < 32) ? tj0 : tj1;
#pragma unroll
    for (int off = 16; off > 0; off >>= 1) {
      mi += __shfl_xor(mi, off, 64);
      mj += __shfl_xor(mj, off, 64);
    }
    if ((lane & 31) == 0) {
      ai[r * 2 + (lane >> 5)] = mi;
      ajrd[(size_t)r * 4 + (lane >> 5)] = mj;
    }
  }
}

// ---------------------------------------------------------------------------
// K_bin: DUAL multi-split. CHUNK=2048, two private windows (dst-binned rec,
// src-binned rec_src), LDS-staged, sequential flush. Parallel 256-thread
// scans (verified round-6 middle win).
// ---------------------------------------------------------------------------
__global__ __launch_bounds__(256) void k_bin(
    const int* __restrict__ ei, const int* __restrict__ eattr,
    unsigned int* __restrict__ rec, int* __restrict__ cnt_tbl,
    int* __restrict__ base_tbl, unsigned int* __restrict__ rec_src,
    int* __restrict__ cnt_tbl2, int* __restrict__ base_tbl2, int Ee, int NCB) {
  __shared__ unsigned sbuf[CHUNK];   // 8 KB
  __shared__ unsigned sbuf2[CHUNK];  // 8 KB
  __shared__ int hist[512], cur[512], hist2[512], cur2[512];
  __shared__ int ssc[256];
  int t = threadIdx.x;
  for (int i = t; i < NCB; i += 256) { hist[i] = 0; hist2[i] = 0; }
  __syncthreads();
  int start = blockIdx.x * CHUNK;
  int end = min(start + CHUNK, Ee);
  int cnt = end - start;
  int cbv[CHUNK / 256], cb2v[CHUNK / 256];
  unsigned pkv[CHUNK / 256], pk2v[CHUNK / 256];
  int nk = 0;
  for (int e = start + t; e < end; e += 256, ++nk) {
    int dst = __builtin_nontemporal_load(&ei[Ee + e]);
    int src = __builtin_nontemporal_load(&ei[e]);
    int a0 = __builtin_nontemporal_load(&eattr[e * 3]);
    int a1 = __builtin_nontemporal_load(&eattr[e * 3 + 1]);
    int a2 = __builtin_nontemporal_load(&eattr[e * 3 + 2]);
    unsigned c012 = (unsigned)(a0 + 5 * a1 + 25 * a2);
    cbv[nk] = dst >> 7;
    pkv[nk] = (unsigned)src | (c012 << 16) | ((unsigned)(dst & 127) << 23);
    cb2v[nk] = src >> 7;
    pk2v[nk] = (unsigned)dst | ((unsigned)(src & 127) << 17) | (c012 << 24);
    atomicAdd(&hist[dst >> 7], 1);
    atomicAdd(&hist2[src >> 7], 1);
  }
  __syncthreads();
  // parallel exclusive scan: hist -> cur, hist2 -> cur2
  {
    int per = (NCB + 255) / 256;  // 2
    int loc[4];
    int lsum = 0;
#pragma unroll 2
    for (int j = 0; j < per; ++j) {
      int idx = t * per + j;
      int v = (idx < NCB) ? hist[idx] : 0;
      loc[j] = lsum;
      lsum += v;
    }
    ssc[t] = lsum;
    __syncthreads();
#pragma unroll
    for (int o = 1; o < 256; o <<= 1) {
      int xv = (t >= o) ? ssc[t - o] : 0;
      __syncthreads();
      ssc[t] += xv;
      __syncthreads();
    }
    int excl = ssc[t] - lsum;
#pragma unroll 2
    for (int j = 0; j < per; ++j) {
      int idx = t * per + j;
      if (idx < NCB) cur[idx] = excl + loc[j];
    }
    __syncthreads();
    lsum = 0;
#pragma unroll 2
    for (int j = 0; j < per; ++j) {
      int idx = t * per + j;
      int v = (idx < NCB) ? hist2[idx] : 0;
      loc[j] = lsum;
      lsum += v;
    }
    ssc[t] = lsum;
    __syncthreads();
#pragma unroll
    for (int o = 1; o < 256; o <<= 1) {
      int xv = (t >= o) ? ssc[t - o] : 0;
      __syncthreads();
      ssc[t] += xv;
      __syncthreads();
    }
    excl = ssc[t] - lsum;
#pragma unroll 2
    for (int j = 0; j < per; ++j) {
      int idx = t * per + j;
      if (idx < NCB) cur2[idx] = excl + loc[j];
    }
  }
  __syncthreads();
  for (int i = t; i < NCB; i += 256) {
    cnt_tbl[blockIdx.x * NCB + i] = hist[i];
    base_tbl[blockIdx.x * NCB + i] = cur[i];
    cnt_tbl2[blockIdx.x * NCB + i] = hist2[i];
    base_tbl2[blockIdx.x * NCB + i] = cur2[i];
  }
  __syncthreads();
  for (int k = 0; k < nk; ++k) {
    int pos = atomicAdd(&cur[cbv[k]], 1);
    sbuf[pos] = pkv[k];
    int pos2 = atomicAdd(&cur2[cb2v[k]], 1);
    sbuf2[pos2] = pk2v[k];
  }
  __syncthreads();
  for (int i = t; i < cnt; i += 256) {
    __builtin_nontemporal_store(sbuf[i], &rec[start + i]);
    __builtin_nontemporal_store(sbuf2[i], &rec_src[start + i]);
  }
}

// ---------------------------------------------------------------------------
// K_segoff_ab: both per-bucket segment-offset scans in ONE launch.
// ---------------------------------------------------------------------------
__global__ __launch_bounds__(256) void k_segoff_ab(
    const int* __restrict__ cnt_tbl, int* __restrict__ segdst,
    int* __restrict__ btot, const int* __restrict__ cnt_tbl2,
    int* __restrict__ segdst2, int* __restrict__ btot2, int NCB, int NBLK) {
  __shared__ int s[256];
  int t = threadIdx.x;
  int bid = blockIdx.x;
  const int* __restrict__ ct = (bid < NCB) ? cnt_tbl : cnt_tbl2;
  int* __restrict__ sd = (bid < NCB) ? segdst : segdst2;
  int* __restrict__ bt = (bid < NCB) ? btot : btot2;
  int cb = (bid < NCB) ? bid : bid - NCB;
  int per = (NBLK + 255) / 256;
  int loc[8];
  int sum = 0;
  for (int j = 0; j < per; ++j) {
    int blk = t * per + j;
    int v = (blk < NBLK) ? ct[blk * NCB + cb] : 0;
    loc[j] = sum;
    sum += v;
  }
  s[t] = sum;
  __syncthreads();
#pragma unroll
  for (int o = 1; o < 256; o <<= 1) {
    int xv = (t >= o) ? s[t - o] : 0;
    __syncthreads();
    s[t] += xv;
    __syncthreads();
  }
  int excl = s[t] - sum;
  for (int j = 0; j < per; ++j) {
    int blk = t * per + j;
    if (blk < NBLK) sd[cb * NBLK + blk] = excl + loc[j];
  }
  if (t == 255) bt[cb] = s[255];
}

// ---------------------------------------------------------------------------
// K_segoff_b: tiny single-block exclusive scan over dst bucket totals.
// Also precomputes tblg[30] (att·bemb dot products) for k_norm.
// ---------------------------------------------------------------------------
__global__ __launch_bounds__(512) void k_segoff_b(
    const int* __restrict__ btot, int* __restrict__ coarse_base,
    const float* __restrict__ att, const float* __restrict__ bemb,
    float* __restrict__ tblg, int NCB, int Ee) {
  __shared__ int s[512];
  int t = threadIdx.x;
  if (t < 30) {
    int f = t / 10, rem = t % 10, c = rem >> 1, hh = rem & 1;
    float sacc = 0.f;
    for (int d = 0; d < 64; ++d)
      sacc += att[hh * 128 + 64 + d] * bemb[(f * 5 + c) * 128 + hh * 64 + d];
    tblg[t] = sacc;
  }
  int v = (t < NCB) ? btot[t] : 0;
  s[t] = v;
  __syncthreads();
#pragma unroll
  for (int o = 1; o < 512; o <<= 1) {
    int xv = (t >= o) ? s[t - o] : 0;
    __syncthreads();
    s[t] += xv;
    __syncthreads();
  }
  if (t < NCB) coarse_base[t] = s[t] - v;
  if (t == 0) coarse_base[NCB] = Ee;
}

// ---------------------------------------------------------------------------
// K_mid: FUSED k_sacc + k_sort, 512 threads. ROUND 14: __launch_bounds__
// (512, 8) forces VGPR <= 64 (was 68 — just over the 64-VGPR wave-cap cliff:
// 68 -> 4 waves/SIMD cap -> 2 blocks/CU; 64 -> 8 waves/SIMD -> LDS-capped
// 3 blocks/CU = 24 waves). Serial basex scan replaced by 128-thread
// Hillis-Steele (15 waves were idling behind a 128-long serial LDS chain).
// ---------------------------------------------------------------------------
__global__ __launch_bounds__(512, 8) void k_mid(
    const unsigned int* __restrict__ rec, const int* __restrict__ cnt_tbl,
    const int* __restrict__ base_tbl, const int* __restrict__ segdst,
    const int* __restrict__ coarse_base,
    const unsigned int* __restrict__ rec_src, const int* __restrict__ cnt_tbl2,
    const int* __restrict__ base_tbl2, const int* __restrict__ segdst2,
    const int* __restrict__ btot2,
    const float2* __restrict__ ai2, float* __restrict__ ajrd,
    const float* __restrict__ att, const float* __restrict__ bemb,
    unsigned int* __restrict__ eix2, float2* __restrict__ alpha2,
    int* __restrict__ off, int Nn, int NCB, int NBLK, int Ee) {
  __shared__ unsigned ubuf[SCAP];   // 20 KB
  __shared__ unsigned ubuf2[SCAP];  // 20 KB (sort half only)
  __shared__ int hist[NPB2], basex[NPB2], curx[NPB2], scn[NPB2];
  __shared__ float tbl[30];
  __shared__ float2 nodev[NPB2];    // ajs (sacc) / ais (sort)
  __shared__ float sdl[NPB2 * 2];   // sacc accumulators
  int t = threadIdx.x;
  if (t < 30) {
    int f = t / 10, rem = t % 10, c = rem >> 1, hh = rem & 1;
    float sacc = 0.f;
    for (int d = 0; d < 64; ++d)
      sacc += att[hh * 128 + 64 + d] * bemb[(f * 5 + c) * 128 + hh * 64 + d];
    tbl[t] = sacc;
  }

  if (blockIdx.x < NCB) {
    // ------------------------------ SACC half ------------------------------
    int cb = blockIdx.x;
    int node0 = cb << 7;
    if (t < NPB2 && node0 + t < Nn)
      nodev[t] = *(const float2*)(ajrd + (size_t)(node0 + t) * 4);
    if (t < NPB2 * 2) sdl[t] = 0.f;
    int total = btot2[cb];
    __syncthreads();
    bool fits = (total <= SCAP);

#define SACC_BODY(U, AIV)                                                      \
    {                                                                          \
      int sl = ((U) >> 17) & 127;                                              \
      int c012 = ((U) >> 24) & 127;                                            \
      int a0 = c012 % 5, a1 = (c012 / 5) % 5, a2 = c012 / 25;                  \
      float2 ajv = nodev[sl];                                                  \
      float lg0 = AIV.x + ajv.x + tbl[a0 * 2] + tbl[10 + a1 * 2] +             \
                  tbl[20 + a2 * 2];                                            \
      float lg1 = AIV.y + ajv.y + tbl[a0 * 2 + 1] + tbl[10 + a1 * 2 + 1] +     \
                  tbl[20 + a2 * 2 + 1];                                        \
      lg0 = lg0 >= 0.f ? lg0 : NEG_SLOPE * lg0;                                \
      lg1 = lg1 >= 0.f ? lg1 : NEG_SLOPE * lg1;                                \
      atomicAdd(&sdl[sl * 2], __expf(lg0));                                    \
      atomicAdd(&sdl[sl * 2 + 1], __expf(lg1));                                \
    }

    if (fits) {
      for (int blk = t; blk < NBLK; blk += 512) {
        int len = cnt_tbl2[blk * NCB + cb];
        if (!len) continue;
        int sp = blk * CHUNK + base_tbl2[blk * NCB + cb];
        int dp = segdst2[cb * NBLK + blk];
        for (int j = 0; j < len; ++j) ubuf[dp + j] = rec_src[sp + j];
      }
      __syncthreads();
      int i = t;
      for (; i + 7 * 512 < total; i += 8 * 512) {
        unsigned u[8];
        float2 aiv[8];
#pragma unroll
        for (int k = 0; k < 8; ++k) u[k] = ubuf[i + k * 512];
#pragma unroll
        for (int k = 0; k < 8; ++k) aiv[k] = ai2[u[k] & 0x1FFFF];
#pragma unroll
        for (int k = 0; k < 8; ++k) SACC_BODY(u[k], aiv[k])
      }
      for (; i < total; i += 512) {
        unsigned u = ubuf[i];
        float2 aiv = ai2[u & 0x1FFFF];
        SACC_BODY(u, aiv)
      }
    } else {
      for (int blk = t; blk < NBLK; blk += 512) {
        int len = cnt_tbl2[blk * NCB + cb];
        int sp = blk * CHUNK + base_tbl2[blk * NCB + cb];
        for (int j = 0; j < len; ++j) {
          unsigned u = rec_src[sp + j];
          float2 aiv = ai2[u & 0x1FFFF];
          SACC_BODY(u, aiv)
        }
      }
    }
#undef SACC_BODY
    __syncthreads();
    if (t < NPB2 * 2) {
      int node = node0 + (t >> 1);
      if (node < Nn)
        ajrd[(size_t)node * 4 + 2 + (t & 1)] = 1.0f / (sdl[t] + 1e-16f);
    }

  } else {
    // ------------------------------ SORT half ------------------------------
    int cb = blockIdx.x - NCB;
    int node0 = cb << 7;
    if (t < NPB2) {
      hist[t] = 0;
      if (node0 + t < Nn) nodev[t] = ai2[node0 + t];
    }
    int gbase = coarse_base[cb];
    int total = coarse_base[cb + 1] - gbase;
    __syncthreads();
    bool fits = (total <= SCAP);

    if (fits) {
      for (int blk = t; blk < NBLK; blk += 512) {
        int len = cnt_tbl[blk * NCB + cb];
        if (!len) continue;
        int sp = blk * CHUNK + base_tbl[blk * NCB + cb];
        int dp = segdst[cb * NBLK + blk];
        for (int j = 0; j < len; ++j) ubuf[dp + j] = rec[sp + j];
      }
      __syncthreads();
      for (int i = t; i < total; i += 512)
        atomicAdd(&hist[(ubuf[i] >> 23) & 127], 1);
      __syncthreads();
      // parallel exclusive scan over 128 bins (Hillis-Steele)
      if (t < NPB2) scn[t] = hist[t];
      __syncthreads();
#pragma unroll
      for (int o = 1; o < NPB2; o <<= 1) {
        int v = (t < NPB2 && t >= o) ? scn[t - o] : 0;
        __syncthreads();
        if (t < NPB2) scn[t] += v;
        __syncthreads();
      }
      if (t < NPB2) {
        basex[t] = scn[t] - hist[t];
        curx[t] = scn[t] - hist[t];
        if (node0 + t < Nn) off[node0 + t] = gbase + scn[t] - hist[t];
      }
      if (cb == 0 && t == 0) off[Nn] = Ee;
      __syncthreads();
      for (int i = t; i < total; i += 512) {
        unsigned u = ubuf[i];
        int pos = atomicAdd(&curx[(u >> 23) & 127], 1);
        ubuf2[pos] = u;
      }
      __syncthreads();
      // output: eix2 + AI-partials only (no gathers, no exp)
      for (int i = t; i < total; i += 512) {
        unsigned u = ubuf2[i];
        int src = u & 0xFFFF;
        int c012 = (u >> 16) & 127;
        int dl = (u >> 23) & 127;
        int a0 = c012 % 5, a1 = (c012 / 5) % 5, a2 = c012 / 25;
        eix2[gbase + i] = (unsigned)src | ((unsigned)a0 << 16) |
                          ((unsigned)a1 << 19) | ((unsigned)a2 << 22);
        alpha2[gbase + i] = nodev[dl];
      }
    } else {
      // fallback (statistically unreachable): global-read path
      for (int blk = t; blk < NBLK; blk += 512) {
        int len = cnt_tbl[blk * NCB + cb];
        int sp = blk * CHUNK + base_tbl[blk * NCB + cb];
        for (int j = 0; j < len; ++j)
          atomicAdd(&hist[(rec[sp + j] >> 23) & 127], 1);
      }
      __syncthreads();
      if (t == 0) {
        int s = 0;
        for (int i = 0; i < NPB2; ++i) { basex[i] = s; s += hist[i]; }
      }
      __syncthreads();
      if (t < NPB2) {
        curx[t] = basex[t];
        if (node0 + t < Nn) off[node0 + t] = gbase + basex[t];
      }
      if (cb == 0 && t == 0) off[Nn] = Ee;
      __syncthreads();
      for (int blk = t; blk < NBLK; blk += 512) {
        int len = cnt_tbl[blk * NCB + cb];
        int sp = blk * CHUNK + base_tbl[blk * NCB + cb];
        for (int j = 0; j < len; ++j) {
          unsigned u = rec[sp + j];
          int src = u & 0xFFFF;
          int c012 = (u >> 16) & 127;
          int dl = (u >> 23) & 127;
          int a0 = c012 % 5, a1 = (c012 / 5) % 5, a2 = c012 / 25;
          int pos = gbase + atomicAdd(&curx[dl], 1);
          eix2[pos] = (unsigned)src | ((unsigned)a0 << 16) |
                      ((unsigned)a1 << 19) | ((unsigned)a2 << 22);
          alpha2[pos] = nodev[dl];
        }
      }
    }
  }
}

// ---------------------------------------------------------------------------
// K_norm: finishes the logit at FULL occupancy. Per edge: one float4 gather
// ajrd[src] = (aj0,aj1,rden0,rden1), lg = ai_part + aj + tbl[attrs], leaky,
// alpha = exp(lg) * rden. Same add order as the fused version.
// ---------------------------------------------------------------------------
__global__ __launch_bounds__(256) void k_norm(
    const unsigned int* __restrict__ eix, float2* __restrict__ alpha2,
    const float4* __restrict__ ajrd4, const float* __restrict__ tblg, int Ee) {
  __shared__ float tbl[30];
  int t = threadIdx.x;
  if (t < 30) tbl[t] = tblg[t];
  __syncthreads();

#define NORM_BODY(U, A, F, OUT)                                                \
  {                                                                            \
    int a0 = ((U) >> 16) & 7, a1 = ((U) >> 19) & 7, a2 = ((U) >> 22) & 7;      \
    float lg0 = (A).x + (F).x + tbl[a0 * 2] + tbl[10 + a1 * 2] +               \
                tbl[20 + a2 * 2];                                              \
    float lg1 = (A).y + (F).y + tbl[a0 * 2 + 1] + tbl[10 + a1 * 2 + 1] +       \
                tbl[20 + a2 * 2 + 1];                                          \
    lg0 = lg0 >= 0.f ? lg0 : NEG_SLOPE * lg0;                                  \
    lg1 = lg1 >= 0.f ? lg1 : NEG_SLOPE * lg1;                                  \
    OUT = make_float2(__expf(lg0) * (F).z, __expf(lg1) * (F).w);               \
  }

  int g = blockIdx.x * 256 + t;
  int e = g * 4;
  if (e + 4 <= Ee) {
    uint4 u = *reinterpret_cast<const uint4*>(&eix[e]);
    float4 f0 = ajrd4[u.x & 0xFFFFu];
    float4 f1 = ajrd4[u.y & 0xFFFFu];
    float4 f2 = ajrd4[u.z & 0xFFFFu];
    float4 f3 = ajrd4[u.w & 0xFFFFu];
    float2 a0v = alpha2[e], a1v = alpha2[e + 1];
    float2 a2v = alpha2[e + 2], a3v = alpha2[e + 3];
    float2 o0, o1, o2, o3;
    NORM_BODY(u.x, a0v, f0, o0)
    NORM_BODY(u.y, a1v, f1, o1)
    NORM_BODY(u.z, a2v, f2, o2)
    NORM_BODY(u.w, a3v, f3, o3)
    alpha2[e] = o0; alpha2[e + 1] = o1;
    alpha2[e + 2] = o2; alpha2[e + 3] = o3;
  } else {
    for (; e < Ee; ++e) {
      unsigned u = eix[e];
      float4 f = ajrd4[u & 0xFFFFu];
      float2 a = alpha2[e];
      float2 o;
      NORM_BODY(u, a, f, o)
      alpha2[e] = o;
    }
  }
#undef NORM_BODY
}

// ---------------------------------------------------------------------------
// K_gather: round-7 body (verified 58.1-58.3us). alpha2 holds FINAL alpha.
// One block of 4 waves per 4 nodes, scalarized uniform loads, myshift shave.
// ---------------------------------------------------------------------------
__global__ __launch_bounds__(256) void k_gather(
    const unsigned int* __restrict__ eix, const float2* __restrict__ alpha2,
    const int* __restrict__ off, const unsigned int* __restrict__ hb,
    const float* __restrict__ bemb, const float* __restrict__ bias,
    float* __restrict__ out, int Nn) {
  __shared__ float bembs[15 * 128];  // [f*5+c][128]
  __shared__ float wsm[4][32];
  int t = threadIdx.x;
  for (int i = t; i < 15 * 128; i += 256) bembs[i] = bemb[i];
  __syncthreads();
  int wave = t >> 6, lane = t & 63;
  int n = blockIdx.x * 4 + wave;
  if (n >= Nn) return;
  int p0 = __builtin_amdgcn_readfirstlane(off[n]);
  int p1 = __builtin_amdgcn_readfirstlane(off[n + 1]);
  int myf = lane / 5;                 // 0..2 for lanes 0..14
  int myc = lane % 5;
  bool active = lane < 15;
  int myshift = 16 + 3 * myf;         // {16,19,22}: a0/a1/a2 bit positions
  int mycEff = active ? myc : 8;      // sel in 0..7 -> 8 never matches
  float w0 = 0.f, w1 = 0.f;
  float acc0 = 0.f, acc1 = 0.f;

#define EDGE_BODY(U, HV, AL)                                                   \
  {                                                                            \
    acc0 = fmaf((AL).x, __uint_as_float((HV) << 16), acc0);                    \
    acc1 = fmaf((AL).y, __uint_as_float((HV) & 0xffff0000u), acc1);            \
    int sel = (int)(((U) >> myshift) & 7u);                                    \
    float m = (sel == mycEff) ? 1.0f : 0.0f;                                   \
    w0 = fmaf(m, (AL).x, w0);                                                  \
    w1 = fmaf(m, (AL).y, w1);                                                  \
  }

  int p = p0;
  for (; p + 8 <= p1; p += 8) {
    unsigned u[8], hv[8];
    float2 al[8];
#pragma unroll
    for (int k = 0; k < 8; ++k) u[k] = eix[p + k];       // uniform -> s_load
#pragma unroll
    for (int k = 0; k < 8; ++k) al[k] = alpha2[p + k];   // uniform -> s_load
#pragma unroll
    for (int k = 0; k < 8; ++k) {
      const unsigned* __restrict__ hrow = hb + ((size_t)(u[k] & 0xFFFFu) << 6);
      hv[k] = hrow[lane];                                // s[base] + v_laneoff
    }
#pragma unroll
    for (int k = 0; k < 8; ++k) EDGE_BODY(u[k], hv[k], al[k])
  }
  for (; p < p1; ++p) {
    unsigned ue = eix[p];
    float2 ale = alpha2[p];
    const unsigned* __restrict__ hrow = hb + ((size_t)(ue & 0xFFFFu) << 6);
    unsigned hve = hrow[lane];
    EDGE_BODY(ue, hve, ale)
  }
#undef EDGE_BODY

  if (active) {
    wsm[wave][lane * 2] = w0;      // same-wave LDS ops are in-order
    wsm[wave][lane * 2 + 1] = w1;
  }
#pragma unroll
  for (int k = 0; k < 15; ++k) {
    acc0 += wsm[wave][k * 2] * bembs[k * 128 + lane];
    acc1 += wsm[wave][k * 2 + 1] * bembs[k * 128 + 64 + lane];
  }
  out[(size_t)n * 64 + lane] = 0.5f * (acc0 + acc1) + bias[lane];
}

extern "C" void kernel_launch(void* const* d_in, const int* in_sizes, int n_in,
                              void* d_out, int out_size, void* d_ws, size_t ws_size,
                              hipStream_t stream) {
  const float* x    = (const float*)d_in[0];
  const int*   ei   = (const int*)d_in[1];
  const int*   eatt = (const int*)d_in[2];
  const float* W    = (const float*)d_in[3];
  const float* bW   = (const float*)d_in[4];
  const float* att  = (const float*)d_in[5];
  const float* bias = (const float*)d_in[6];
  const float* bemb = (const float*)d_in[7];
  int Nn = in_sizes[0] / 64;
  int Ee = in_sizes[1] / 2;
  int NCB = (Nn + NPB2 - 1) / NPB2;            // 391 coarse buckets (128 nodes)
  int NBLK = (Ee + CHUNK - 1) / CHUNK;         // 782 bin blocks

  char* ws = (char*)d_ws;
  ws = (char*)(((uintptr_t)ws + 15) & ~(uintptr_t)15);
  float* ajrd = (float*)ws;               ws += (size_t)Nn * 4 * 4;  // 16B-aligned
  float* ai = (float*)ws;                 ws += (size_t)Nn * 2 * 4;
  float* tblg = (float*)ws;               ws += 32 * 4;
  unsigned int* hb = (unsigned int*)ws;   ws += (size_t)Nn * 64 * 4;
  unsigned int* rec = (unsigned int*)ws;  ws += (size_t)NBLK * CHUNK * 4;
  unsigned int* rec_src = (unsigned int*)ws; ws += (size_t)NBLK * CHUNK * 4;
  unsigned int* eix2 = (unsigned int*)ws; ws += (size_t)Ee * 4;
  float2* alpha2 = (float2*)ws;           ws += (size_t)Ee * 8;
  int* off = (int*)ws;                    ws += (size_t)(Nn + 1) * 4;
  int* cnt_tbl = (int*)ws;                ws += (size_t)NBLK * NCB * 4;
  int* base_tbl = (int*)ws;               ws += (size_t)NBLK * NCB * 4;
  int* cnt_tbl2 = (int*)ws;               ws += (size_t)NBLK * NCB * 4;
  int* base_tbl2 = (int*)ws;              ws += (size_t)NBLK * NCB * 4;
  int* segdst = (int*)ws;                 ws += (size_t)NCB * NBLK * 4;
  int* segdst2 = (int*)ws;                ws += (size_t)NCB * NBLK * 4;
  int* coarse_base = (int*)ws;            ws += (size_t)(NCB + 1) * 4;
  int* btot = (int*)ws;                   ws += (size_t)NCB * 4;
  int* btot2 = (int*)ws;                  ws += (size_t)NCB * 4;

  k1_gemm<<<1024, 256, 0, stream>>>(x, W, bW, att, hb, ai, ajrd, Nn);
  k_bin<<<NBLK, 256, 0, stream>>>(ei, eatt, rec, cnt_tbl, base_tbl, rec_src,
                                  cnt_tbl2, base_tbl2, Ee, NCB);
  k_segoff_ab<<<2 * NCB, 256, 0, stream>>>(cnt_tbl, segdst, btot, cnt_tbl2,
                                           segdst2, btot2, NCB, NBLK);
  k_segoff_b<<<1, 512, 0, stream>>>(btot, coarse_base, att, bemb, tblg, NCB, Ee);
  k_mid<<<2 * NCB, 512, 0, stream>>>(rec, cnt_tbl, base_tbl, segdst,
                                     coarse_base, rec_src, cnt_tbl2, base_tbl2,
                                     segdst2, btot2, (const float2*)ai, ajrd,
                                     att, bemb, eix2, alpha2, off,
                                     Nn, NCB, NBLK, Ee);
  k_norm<<<(Ee / 4 + 255) / 256, 256, 0, stream>>>(eix2, alpha2,
                                                   (const float4*)ajrd, tblg, Ee);
  k_gather<<<(Nn + 3) / 4, 256, 0, stream>>>(eix2, alpha2, off, hb, bemb, bias,
                                             (float*)d_out, Nn);
}

// Round 15
// 264.634 us; speedup vs baseline: 1.0938x; 1.0096x over previous
//
#include <hip/hip_runtime.h>
#include <hip/hip_bf16.h>
#include <math.h>

#define NEG_SLOPE 0.2f
#define CHUNK 2048      // edges per k_bin block
#define NPB2 128        // nodes per coarse bucket
#define SCAP 5120       // LDS record capacity (bucket mean ~4092, sd ~64)

__device__ __forceinline__ unsigned f2bf(float f) {
  unsigned u = __float_as_uint(f);
  return (u + 0x7fffu + ((u >> 16) & 1u)) >> 16;  // RNE
}

// ---------------------------------------------------------------------------
// K1: h = x @ W + b_W. Register-stationary: one wave per row, W columns in
// 128 VGPRs, x row via scalar loads, zero LDS. aj written into the combined
// ajrd float4 table (aj0,aj1,rden0,rden1) — rden filled by k_mid.
// ---------------------------------------------------------------------------
__global__ __launch_bounds__(256) void k1_gemm(
    const float* __restrict__ x, const float* __restrict__ W,
    const float* __restrict__ bW, const float* __restrict__ att,
    unsigned int* __restrict__ hb, float* __restrict__ ai,
    float* __restrict__ ajrd, int Nn) {
  int t = threadIdx.x;
  int lane = t & 63;  // d
  int wid = blockIdx.x * (blockDim.x >> 6) + (t >> 6);
  int nwaves = gridDim.x * (blockDim.x >> 6);

  float Wr0[64], Wr1[64];
#pragma unroll
  for (int k = 0; k < 64; ++k) {
    Wr0[k] = W[k * 128 + lane];
    Wr1[k] = W[k * 128 + 64 + lane];
  }
  float bs0 = bW[lane], bs1 = bW[64 + lane];
  float ati0 = att[lane];
  float atj0 = att[64 + lane];
  float ati1 = att[128 + lane];
  float atj1 = att[192 + lane];

  for (int row = wid; row < Nn; row += nwaves) {
    int r = __builtin_amdgcn_readfirstlane(row);
    const float* __restrict__ xr = x + (size_t)r * 64;
    float a0a = 0.f, a0b = 0.f, a1a = 0.f, a1b = 0.f;
#pragma unroll
    for (int k = 0; k < 64; k += 2) {
      float xk0 = xr[k], xk1 = xr[k + 1];
      a0a = fmaf(xk0, Wr0[k], a0a);
      a1a = fmaf(xk0, Wr1[k], a1a);
      a0b = fmaf(xk1, Wr0[k + 1], a0b);
      a1b = fmaf(xk1, Wr1[k + 1], a1b);
    }
    float h0 = a0a + a0b + bs0;
    float h1 = a1a + a1b + bs1;
    hb[(size_t)r * 64 + lane] = f2bf(h0) | (f2bf(h1) << 16);

    float ti0 = ati0 * h0, tj0 = atj0 * h0;
    float ti1 = ati1 * h1, tj1 = atj1 * h1;
    ti0 += __shfl_xor(ti0, 32, 64);
    tj0 += __shfl_xor(tj0, 32, 64);
    ti1 += __shfl_xor(ti1, 32, 64);
    tj1 += __shfl_xor(tj1, 32, 64);
    float mi = (lane < 32) ? ti0 : ti1;
    float mj = (lane < 32) ? tj0 : tj1;
#pragma unroll
    for (int off = 16; off > 0; off >>= 1) {
      mi += __shfl_xor(mi, off, 64);
      mj += __shfl_xor(mj, off, 64);
    }
    if ((lane & 31) == 0) {
      ai[r * 2 + (lane >> 5)] = mi;
      ajrd[(size_t)r * 4 + (lane >> 5)] = mj;
    }
  }
}

// ---------------------------------------------------------------------------
// K_bin: DUAL multi-split. ROUND 15: 512 THREADS/BLOCK (the round-13 lever
// applied here): halves every serial per-thread chain (staging nk 8->4,
// scatter 16->8 atomics, flush 8->4) and doubles waves/CU (~12 -> ~24) at
// unchanged 33KB LDS. Scans widened to 512 threads (1 value/thread).
// ---------------------------------------------------------------------------
__global__ __launch_bounds__(512) void k_bin(
    const int* __restrict__ ei, const int* __restrict__ eattr,
    unsigned int* __restrict__ rec, int* __restrict__ cnt_tbl,
    int* __restrict__ base_tbl, unsigned int* __restrict__ rec_src,
    int* __restrict__ cnt_tbl2, int* __restrict__ base_tbl2, int Ee, int NCB) {
  __shared__ unsigned sbuf[CHUNK];   // 8 KB
  __shared__ unsigned sbuf2[CHUNK];  // 8 KB
  __shared__ int hist[512], cur[512], hist2[512], cur2[512];
  __shared__ int ssc[512];
  int t = threadIdx.x;
  for (int i = t; i < NCB; i += 512) { hist[i] = 0; hist2[i] = 0; }
  __syncthreads();
  int start = blockIdx.x * CHUNK;
  int end = min(start + CHUNK, Ee);
  int cnt = end - start;
  int cbv[CHUNK / 512], cb2v[CHUNK / 512];
  unsigned pkv[CHUNK / 512], pk2v[CHUNK / 512];
  int nk = 0;
  for (int e = start + t; e < end; e += 512, ++nk) {
    int dst = __builtin_nontemporal_load(&ei[Ee + e]);
    int src = __builtin_nontemporal_load(&ei[e]);
    int a0 = __builtin_nontemporal_load(&eattr[e * 3]);
    int a1 = __builtin_nontemporal_load(&eattr[e * 3 + 1]);
    int a2 = __builtin_nontemporal_load(&eattr[e * 3 + 2]);
    unsigned c012 = (unsigned)(a0 + 5 * a1 + 25 * a2);
    cbv[nk] = dst >> 7;
    pkv[nk] = (unsigned)src | (c012 << 16) | ((unsigned)(dst & 127) << 23);
    cb2v[nk] = src >> 7;
    pk2v[nk] = (unsigned)dst | ((unsigned)(src & 127) << 17) | (c012 << 24);
    atomicAdd(&hist[dst >> 7], 1);
    atomicAdd(&hist2[src >> 7], 1);
  }
  __syncthreads();
  // parallel exclusive scans (512-wide Hillis-Steele, 1 value/thread)
  {
    int v = (t < NCB) ? hist[t] : 0;
    ssc[t] = v;
    __syncthreads();
#pragma unroll
    for (int o = 1; o < 512; o <<= 1) {
      int xv = (t >= o) ? ssc[t - o] : 0;
      __syncthreads();
      ssc[t] += xv;
      __syncthreads();
    }
    if (t < NCB) cur[t] = ssc[t] - v;
    __syncthreads();
    v = (t < NCB) ? hist2[t] : 0;
    ssc[t] = v;
    __syncthreads();
#pragma unroll
    for (int o = 1; o < 512; o <<= 1) {
      int xv = (t >= o) ? ssc[t - o] : 0;
      __syncthreads();
      ssc[t] += xv;
      __syncthreads();
    }
    if (t < NCB) cur2[t] = ssc[t] - v;
  }
  __syncthreads();
  for (int i = t; i < NCB; i += 512) {
    cnt_tbl[blockIdx.x * NCB + i] = hist[i];
    base_tbl[blockIdx.x * NCB + i] = cur[i];
    cnt_tbl2[blockIdx.x * NCB + i] = hist2[i];
    base_tbl2[blockIdx.x * NCB + i] = cur2[i];
  }
  __syncthreads();
  for (int k = 0; k < nk; ++k) {
    int pos = atomicAdd(&cur[cbv[k]], 1);
    sbuf[pos] = pkv[k];
    int pos2 = atomicAdd(&cur2[cb2v[k]], 1);
    sbuf2[pos2] = pk2v[k];
  }
  __syncthreads();
  for (int i = t; i < cnt; i += 512) {
    __builtin_nontemporal_store(sbuf[i], &rec[start + i]);
    __builtin_nontemporal_store(sbuf2[i], &rec_src[start + i]);
  }
}

// ---------------------------------------------------------------------------
// K_segoff_ab: both per-bucket segment-offset scans in ONE launch.
// ---------------------------------------------------------------------------
__global__ __launch_bounds__(256) void k_segoff_ab(
    const int* __restrict__ cnt_tbl, int* __restrict__ segdst,
    int* __restrict__ btot, const int* __restrict__ cnt_tbl2,
    int* __restrict__ segdst2, int* __restrict__ btot2, int NCB, int NBLK) {
  __shared__ int s[256];
  int t = threadIdx.x;
  int bid = blockIdx.x;
  const int* __restrict__ ct = (bid < NCB) ? cnt_tbl : cnt_tbl2;
  int* __restrict__ sd = (bid < NCB) ? segdst : segdst2;
  int* __restrict__ bt = (bid < NCB) ? btot : btot2;
  int cb = (bid < NCB) ? bid : bid - NCB;
  int per = (NBLK + 255) / 256;
  int loc[8];
  int sum = 0;
  for (int j = 0; j < per; ++j) {
    int blk = t * per + j;
    int v = (blk < NBLK) ? ct[blk * NCB + cb] : 0;
    loc[j] = sum;
    sum += v;
  }
  s[t] = sum;
  __syncthreads();
#pragma unroll
  for (int o = 1; o < 256; o <<= 1) {
    int xv = (t >= o) ? s[t - o] : 0;
    __syncthreads();
    s[t] += xv;
    __syncthreads();
  }
  int excl = s[t] - sum;
  for (int j = 0; j < per; ++j) {
    int blk = t * per + j;
    if (blk < NBLK) sd[cb * NBLK + blk] = excl + loc[j];
  }
  if (t == 255) bt[cb] = s[255];
}

// ---------------------------------------------------------------------------
// K_segoff_b: tiny single-block exclusive scan over dst bucket totals.
// Also precomputes tblg[30] (att·bemb dot products) for k_norm.
// ---------------------------------------------------------------------------
__global__ __launch_bounds__(512) void k_segoff_b(
    const int* __restrict__ btot, int* __restrict__ coarse_base,
    const float* __restrict__ att, const float* __restrict__ bemb,
    float* __restrict__ tblg, int NCB, int Ee) {
  __shared__ int s[512];
  int t = threadIdx.x;
  if (t < 30) {
    int f = t / 10, rem = t % 10, c = rem >> 1, hh = rem & 1;
    float sacc = 0.f;
    for (int d = 0; d < 64; ++d)
      sacc += att[hh * 128 + 64 + d] * bemb[(f * 5 + c) * 128 + hh * 64 + d];
    tblg[t] = sacc;
  }
  int v = (t < NCB) ? btot[t] : 0;
  s[t] = v;
  __syncthreads();
#pragma unroll
  for (int o = 1; o < 512; o <<= 1) {
    int xv = (t >= o) ? s[t - o] : 0;
    __syncthreads();
    s[t] += xv;
    __syncthreads();
  }
  if (t < NCB) coarse_base[t] = s[t] - v;
  if (t == 0) coarse_base[NCB] = Ee;
}

// ---------------------------------------------------------------------------
// K_mid: FUSED k_sacc + k_sort, 512 threads, VGPR capped via
// __launch_bounds__(512, 8) (round-14). SORT emits eix2 + AI partials
// (k_norm finishes); SACC writes rden into ajrd[.zw].
// ---------------------------------------------------------------------------
__global__ __launch_bounds__(512, 8) void k_mid(
    const unsigned int* __restrict__ rec, const int* __restrict__ cnt_tbl,
    const int* __restrict__ base_tbl, const int* __restrict__ segdst,
    const int* __restrict__ coarse_base,
    const unsigned int* __restrict__ rec_src, const int* __restrict__ cnt_tbl2,
    const int* __restrict__ base_tbl2, const int* __restrict__ segdst2,
    const int* __restrict__ btot2,
    const float2* __restrict__ ai2, float* __restrict__ ajrd,
    const float* __restrict__ att, const float* __restrict__ bemb,
    unsigned int* __restrict__ eix2, float2* __restrict__ alpha2,
    int* __restrict__ off, int Nn, int NCB, int NBLK, int Ee) {
  __shared__ unsigned ubuf[SCAP];   // 20 KB
  __shared__ unsigned ubuf2[SCAP];  // 20 KB (sort half only)
  __shared__ int hist[NPB2], basex[NPB2], curx[NPB2], scn[NPB2];
  __shared__ float tbl[30];
  __shared__ float2 nodev[NPB2];    // ajs (sacc) / ais (sort)
  __shared__ float sdl[NPB2 * 2];   // sacc accumulators
  int t = threadIdx.x;
  if (t < 30) {
    int f = t / 10, rem = t % 10, c = rem >> 1, hh = rem & 1;
    float sacc = 0.f;
    for (int d = 0; d < 64; ++d)
      sacc += att[hh * 128 + 64 + d] * bemb[(f * 5 + c) * 128 + hh * 64 + d];
    tbl[t] = sacc;
  }

  if (blockIdx.x < NCB) {
    // ------------------------------ SACC half ------------------------------
    int cb = blockIdx.x;
    int node0 = cb << 7;
    if (t < NPB2 && node0 + t < Nn)
      nodev[t] = *(const float2*)(ajrd + (size_t)(node0 + t) * 4);
    if (t < NPB2 * 2) sdl[t] = 0.f;
    int total = btot2[cb];
    __syncthreads();
    bool fits = (total <= SCAP);

#define SACC_BODY(U, AIV)                                                      \
    {                                                                          \
      int sl = ((U) >> 17) & 127;                                              \
      int c012 = ((U) >> 24) & 127;                                            \
      int a0 = c012 % 5, a1 = (c012 / 5) % 5, a2 = c012 / 25;                  \
      float2 ajv = nodev[sl];                                                  \
      float lg0 = AIV.x + ajv.x + tbl[a0 * 2] + tbl[10 + a1 * 2] +             \
                  tbl[20 + a2 * 2];                                            \
      float lg1 = AIV.y + ajv.y + tbl[a0 * 2 + 1] + tbl[10 + a1 * 2 + 1] +     \
                  tbl[20 + a2 * 2 + 1];                                        \
      lg0 = lg0 >= 0.f ? lg0 : NEG_SLOPE * lg0;                                \
      lg1 = lg1 >= 0.f ? lg1 : NEG_SLOPE * lg1;                                \
      atomicAdd(&sdl[sl * 2], __expf(lg0));                                    \
      atomicAdd(&sdl[sl * 2 + 1], __expf(lg1));                                \
    }

    if (fits) {
      for (int blk = t; blk < NBLK; blk += 512) {
        int len = cnt_tbl2[blk * NCB + cb];
        if (!len) continue;
        int sp = blk * CHUNK + base_tbl2[blk * NCB + cb];
        int dp = segdst2[cb * NBLK + blk];
        for (int j = 0; j < len; ++j) ubuf[dp + j] = rec_src[sp + j];
      }
      __syncthreads();
      int i = t;
      for (; i + 7 * 512 < total; i += 8 * 512) {
        unsigned u[8];
        float2 aiv[8];
#pragma unroll
        for (int k = 0; k < 8; ++k) u[k] = ubuf[i + k * 512];
#pragma unroll
        for (int k = 0; k < 8; ++k) aiv[k] = ai2[u[k] & 0x1FFFF];
#pragma unroll
        for (int k = 0; k < 8; ++k) SACC_BODY(u[k], aiv[k])
      }
      for (; i < total; i += 512) {
        unsigned u = ubuf[i];
        float2 aiv = ai2[u & 0x1FFFF];
        SACC_BODY(u, aiv)
      }
    } else {
      for (int blk = t; blk < NBLK; blk += 512) {
        int len = cnt_tbl2[blk * NCB + cb];
        int sp = blk * CHUNK + base_tbl2[blk * NCB + cb];
        for (int j = 0; j < len; ++j) {
          unsigned u = rec_src[sp + j];
          float2 aiv = ai2[u & 0x1FFFF];
          SACC_BODY(u, aiv)
        }
      }
    }
#undef SACC_BODY
    __syncthreads();
    if (t < NPB2 * 2) {
      int node = node0 + (t >> 1);
      if (node < Nn)
        ajrd[(size_t)node * 4 + 2 + (t & 1)] = 1.0f / (sdl[t] + 1e-16f);
    }

  } else {
    // ------------------------------ SORT half ------------------------------
    int cb = blockIdx.x - NCB;
    int node0 = cb << 7;
    if (t < NPB2) {
      hist[t] = 0;
      if (node0 + t < Nn) nodev[t] = ai2[node0 + t];
    }
    int gbase = coarse_base[cb];
    int total = coarse_base[cb + 1] - gbase;
    __syncthreads();
    bool fits = (total <= SCAP);

    if (fits) {
      for (int blk = t; blk < NBLK; blk += 512) {
        int len = cnt_tbl[blk * NCB + cb];
        if (!len) continue;
        int sp = blk * CHUNK + base_tbl[blk * NCB + cb];
        int dp = segdst[cb * NBLK + blk];
        for (int j = 0; j < len; ++j) ubuf[dp + j] = rec[sp + j];
      }
      __syncthreads();
      for (int i = t; i < total; i += 512)
        atomicAdd(&hist[(ubuf[i] >> 23) & 127], 1);
      __syncthreads();
      // parallel exclusive scan over 128 bins (Hillis-Steele)
      if (t < NPB2) scn[t] = hist[t];
      __syncthreads();
#pragma unroll
      for (int o = 1; o < NPB2; o <<= 1) {
        int v = (t < NPB2 && t >= o) ? scn[t - o] : 0;
        __syncthreads();
        if (t < NPB2) scn[t] += v;
        __syncthreads();
      }
      if (t < NPB2) {
        basex[t] = scn[t] - hist[t];
        curx[t] = scn[t] - hist[t];
        if (node0 + t < Nn) off[node0 + t] = gbase + scn[t] - hist[t];
      }
      if (cb == 0 && t == 0) off[Nn] = Ee;
      __syncthreads();
      for (int i = t; i < total; i += 512) {
        unsigned u = ubuf[i];
        int pos = atomicAdd(&curx[(u >> 23) & 127], 1);
        ubuf2[pos] = u;
      }
      __syncthreads();
      // output: eix2 + AI-partials only (no gathers, no exp)
      for (int i = t; i < total; i += 512) {
        unsigned u = ubuf2[i];
        int src = u & 0xFFFF;
        int c012 = (u >> 16) & 127;
        int dl = (u >> 23) & 127;
        int a0 = c012 % 5, a1 = (c012 / 5) % 5, a2 = c012 / 25;
        eix2[gbase + i] = (unsigned)src | ((unsigned)a0 << 16) |
                          ((unsigned)a1 << 19) | ((unsigned)a2 << 22);
        alpha2[gbase + i] = nodev[dl];
      }
    } else {
      // fallback (statistically unreachable): global-read path
      for (int blk = t; blk < NBLK; blk += 512) {
        int len = cnt_tbl[blk * NCB + cb];
        int sp = blk * CHUNK + base_tbl[blk * NCB + cb];
        for (int j = 0; j < len; ++j)
          atomicAdd(&hist[(rec[sp + j] >> 23) & 127], 1);
      }
      __syncthreads();
      if (t == 0) {
        int s = 0;
        for (int i = 0; i < NPB2; ++i) { basex[i] = s; s += hist[i]; }
      }
      __syncthreads();
      if (t < NPB2) {
        curx[t] = basex[t];
        if (node0 + t < Nn) off[node0 + t] = gbase + basex[t];
      }
      if (cb == 0 && t == 0) off[Nn] = Ee;
      __syncthreads();
      for (int blk = t; blk < NBLK; blk += 512) {
        int len = cnt_tbl[blk * NCB + cb];
        int sp = blk * CHUNK + base_tbl[blk * NCB + cb];
        for (int j = 0; j < len; ++j) {
          unsigned u = rec[sp + j];
          int src = u & 0xFFFF;
          int c012 = (u >> 16) & 127;
          int dl = (u >> 23) & 127;
          int a0 = c012 % 5, a1 = (c012 / 5) % 5, a2 = c012 / 25;
          int pos = gbase + atomicAdd(&curx[dl], 1);
          eix2[pos] = (unsigned)src | ((unsigned)a0 << 16) |
                      ((unsigned)a1 << 19) | ((unsigned)a2 << 22);
          alpha2[pos] = nodev[dl];
        }
      }
    }
  }
}

// ---------------------------------------------------------------------------
// K_norm: finishes the logit at FULL occupancy. Per edge: one float4 gather
// ajrd[src] = (aj0,aj1,rden0,rden1), lg = ai_part + aj + tbl[attrs], leaky,
// alpha = exp(lg) * rden. Same add order as the fused version.
// ---------------------------------------------------------------------------
__global__ __launch_bounds__(256) void k_norm(
    const unsigned int* __restrict__ eix, float2* __restrict__ alpha2,
    const float4* __restrict__ ajrd4, const float* __restrict__ tblg, int Ee) {
  __shared__ float tbl[30];
  int t = threadIdx.x;
  if (t < 30) tbl[t] = tblg[t];
  __syncthreads();

#define NORM_BODY(U, A, F, OUT)                                                \
  {                                                                            \
    int a0 = ((U) >> 16) & 7, a1 = ((U) >> 19) & 7, a2 = ((U) >> 22) & 7;      \
    float lg0 = (A).x + (F).x + tbl[a0 * 2] + tbl[10 + a1 * 2] +               \
                tbl[20 + a2 * 2];                                              \
    float lg1 = (A).y + (F).y + tbl[a0 * 2 + 1] + tbl[10 + a1 * 2 + 1] +       \
                tbl[20 + a2 * 2 + 1];                                          \
    lg0 = lg0 >= 0.f ? lg0 : NEG_SLOPE * lg0;                                  \
    lg1 = lg1 >= 0.f ? lg1 : NEG_SLOPE * lg1;                                  \
    OUT = make_float2(__expf(lg0) * (F).z, __expf(lg1) * (F).w);               \
  }

  int g = blockIdx.x * 256 + t;
  int e = g * 4;
  if (e + 4 <= Ee) {
    uint4 u = *reinterpret_cast<const uint4*>(&eix[e]);
    float4 f0 = ajrd4[u.x & 0xFFFFu];
    float4 f1 = ajrd4[u.y & 0xFFFFu];
    float4 f2 = ajrd4[u.z & 0xFFFFu];
    float4 f3 = ajrd4[u.w & 0xFFFFu];
    float2 a0v = alpha2[e], a1v = alpha2[e + 1];
    float2 a2v = alpha2[e + 2], a3v = alpha2[e + 3];
    float2 o0, o1, o2, o3;
    NORM_BODY(u.x, a0v, f0, o0)
    NORM_BODY(u.y, a1v, f1, o1)
    NORM_BODY(u.z, a2v, f2, o2)
    NORM_BODY(u.w, a3v, f3, o3)
    alpha2[e] = o0; alpha2[e + 1] = o1;
    alpha2[e + 2] = o2; alpha2[e + 3] = o3;
  } else {
    for (; e < Ee; ++e) {
      unsigned u = eix[e];
      float4 f = ajrd4[u & 0xFFFFu];
      float2 a = alpha2[e];
      float2 o;
      NORM_BODY(u, a, f, o)
      alpha2[e] = o;
    }
  }
#undef NORM_BODY
}

// ---------------------------------------------------------------------------
// K_gather: round-7 body (verified 58.1-58.3us). alpha2 holds FINAL alpha.
// One block of 4 waves per 4 nodes, scalarized uniform loads, myshift shave.
// ---------------------------------------------------------------------------
__global__ __launch_bounds__(256) void k_gather(
    const unsigned int* __restrict__ eix, const float2* __restrict__ alpha2,
    const int* __restrict__ off, const unsigned int* __restrict__ hb,
    const float* __restrict__ bemb, const float* __restrict__ bias,
    float* __restrict__ out, int Nn) {
  __shared__ float bembs[15 * 128];  // [f*5+c][128]
  __shared__ float wsm[4][32];
  int t = threadIdx.x;
  for (int i = t; i < 15 * 128; i += 256) bembs[i] = bemb[i];
  __syncthreads();
  int wave = t >> 6, lane = t & 63;
  int n = blockIdx.x * 4 + wave;
  if (n >= Nn) return;
  int p0 = __builtin_amdgcn_readfirstlane(off[n]);
  int p1 = __builtin_amdgcn_readfirstlane(off[n + 1]);
  int myf = lane / 5;                 // 0..2 for lanes 0..14
  int myc = lane % 5;
  bool active = lane < 15;
  int myshift = 16 + 3 * myf;         // {16,19,22}: a0/a1/a2 bit positions
  int mycEff = active ? myc : 8;      // sel in 0..7 -> 8 never matches
  float w0 = 0.f, w1 = 0.f;
  float acc0 = 0.f, acc1 = 0.f;

#define EDGE_BODY(U, HV, AL)                                                   \
  {                                                                            \
    acc0 = fmaf((AL).x, __uint_as_float((HV) << 16), acc0);                    \
    acc1 = fmaf((AL).y, __uint_as_float((HV) & 0xffff0000u), acc1);            \
    int sel = (int)(((U) >> myshift) & 7u);                                    \
    float m = (sel == mycEff) ? 1.0f : 0.0f;                                   \
    w0 = fmaf(m, (AL).x, w0);                                                  \
    w1 = fmaf(m, (AL).y, w1);                                                  \
  }

  int p = p0;
  for (; p + 8 <= p1; p += 8) {
    unsigned u[8], hv[8];
    float2 al[8];
#pragma unroll
    for (int k = 0; k < 8; ++k) u[k] = eix[p + k];       // uniform -> s_load
#pragma unroll
    for (int k = 0; k < 8; ++k) al[k] = alpha2[p + k];   // uniform -> s_load
#pragma unroll
    for (int k = 0; k < 8; ++k) {
      const unsigned* __restrict__ hrow = hb + ((size_t)(u[k] & 0xFFFFu) << 6);
      hv[k] = hrow[lane];                                // s[base] + v_laneoff
    }
#pragma unroll
    for (int k = 0; k < 8; ++k) EDGE_BODY(u[k], hv[k], al[k])
  }
  for (; p < p1; ++p) {
    unsigned ue = eix[p];
    float2 ale = alpha2[p];
    const unsigned* __restrict__ hrow = hb + ((size_t)(ue & 0xFFFFu) << 6);
    unsigned hve = hrow[lane];
    EDGE_BODY(ue, hve, ale)
  }
#undef EDGE_BODY

  if (active) {
    wsm[wave][lane * 2] = w0;      // same-wave LDS ops are in-order
    wsm[wave][lane * 2 + 1] = w1;
  }
#pragma unroll
  for (int k = 0; k < 15; ++k) {
    acc0 += wsm[wave][k * 2] * bembs[k * 128 + lane];
    acc1 += wsm[wave][k * 2 + 1] * bembs[k * 128 + 64 + lane];
  }
  out[(size_t)n * 64 + lane] = 0.5f * (acc0 + acc1) + bias[lane];
}

extern "C" void kernel_launch(void* const* d_in, const int* in_sizes, int n_in,
                              void* d_out, int out_size, void* d_ws, size_t ws_size,
                              hipStream_t stream) {
  const float* x    = (const float*)d_in[0];
  const int*   ei   = (const int*)d_in[1];
  const int*   eatt = (const int*)d_in[2];
  const float* W    = (const float*)d_in[3];
  const float* bW   = (const float*)d_in[4];
  const float* att  = (const float*)d_in[5];
  const float* bias = (const float*)d_in[6];
  const float* bemb = (const float*)d_in[7];
  int Nn = in_sizes[0] / 64;
  int Ee = in_sizes[1] / 2;
  int NCB = (Nn + NPB2 - 1) / NPB2;            // 391 coarse buckets (128 nodes)
  int NBLK = (Ee + CHUNK - 1) / CHUNK;         // 782 bin blocks

  char* ws = (char*)d_ws;
  ws = (char*)(((uintptr_t)ws + 15) & ~(uintptr_t)15);
  float* ajrd = (float*)ws;               ws += (size_t)Nn * 4 * 4;  // 16B-aligned
  float* ai = (float*)ws;                 ws += (size_t)Nn * 2 * 4;
  float* tblg = (float*)ws;               ws += 32 * 4;
  unsigned int* hb = (unsigned int*)ws;   ws += (size_t)Nn * 64 * 4;
  unsigned int* rec = (unsigned int*)ws;  ws += (size_t)NBLK * CHUNK * 4;
  unsigned int* rec_src = (unsigned int*)ws; ws += (size_t)NBLK * CHUNK * 4;
  unsigned int* eix2 = (unsigned int*)ws; ws += (size_t)Ee * 4;
  float2* alpha2 = (float2*)ws;           ws += (size_t)Ee * 8;
  int* off = (int*)ws;                    ws += (size_t)(Nn + 1) * 4;
  int* cnt_tbl = (int*)ws;                ws += (size_t)NBLK * NCB * 4;
  int* base_tbl = (int*)ws;               ws += (size_t)NBLK * NCB * 4;
  int* cnt_tbl2 = (int*)ws;               ws += (size_t)NBLK * NCB * 4;
  int* base_tbl2 = (int*)ws;              ws += (size_t)NBLK * NCB * 4;
  int* segdst = (int*)ws;                 ws += (size_t)NCB * NBLK * 4;
  int* segdst2 = (int*)ws;                ws += (size_t)NCB * NBLK * 4;
  int* coarse_base = (int*)ws;            ws += (size_t)(NCB + 1) * 4;
  int* btot = (int*)ws;                   ws += (size_t)NCB * 4;
  int* btot2 = (int*)ws;                  ws += (size_t)NCB * 4;

  k1_gemm<<<1024, 256, 0, stream>>>(x, W, bW, att, hb, ai, ajrd, Nn);
  k_bin<<<NBLK, 512, 0, stream>>>(ei, eatt, rec, cnt_tbl, base_tbl, rec_src,
                                  cnt_tbl2, base_tbl2, Ee, NCB);
  k_segoff_ab<<<2 * NCB, 256, 0, stream>>>(cnt_tbl, segdst, btot, cnt_tbl2,
                                           segdst2, btot2, NCB, NBLK);
  k_segoff_b<<<1, 512, 0, stream>>>(btot, coarse_base, att, bemb, tblg, NCB, Ee);
  k_mid<<<2 * NCB, 512, 0, stream>>>(rec, cnt_tbl, base_tbl, segdst,
                                     coarse_base, rec_src, cnt_tbl2, base_tbl2,
                                     segdst2, btot2, (const float2*)ai, ajrd,
                                     att, bemb, eix2, alpha2, off,
                                     Nn, NCB, NBLK, Ee);
  k_norm<<<(Ee / 4 + 255) / 256, 256, 0, stream>>>(eix2, alpha2,
                                                   (const float4*)ajrd, tblg, Ee);
  k_gather<<<(Nn + 3) / 4, 256, 0, stream>>>(eix2, alpha2, off, hb, bemb, bias,
                                             (float*)d_out, Nn);
}

// Round 16
// 257.322 us; speedup vs baseline: 1.1249x; 1.0284x over previous
//
#include <hip/hip_runtime.h>
#include <hip/hip_bf16.h>
#include <math.h>

#define NEG_SLOPE 0.2f
#define CHUNK 4096      // edges per k_bin block (round 16: halves NBLK/tables)
#define NPB2 128        // nodes per coarse bucket
#define SCAP 5120       // LDS record capacity (bucket mean ~4092, sd ~64)

__device__ __forceinline__ unsigned f2bf(float f) {
  unsigned u = __float_as_uint(f);
  return (u + 0x7fffu + ((u >> 16) & 1u)) >> 16;  // RNE
}

// ---------------------------------------------------------------------------
// K1: h = x @ W + b_W. Register-stationary: one wave per row, W columns in
// 128 VGPRs, x row via scalar loads, zero LDS. aj written into the combined
// ajrd float4 table (aj0,aj1,rden0,rden1) — rden filled by k_mid.
// ---------------------------------------------------------------------------
__global__ __launch_bounds__(256) void k1_gemm(
    const float* __restrict__ x, const float* __restrict__ W,
    const float* __restrict__ bW, const float* __restrict__ att,
    unsigned int* __restrict__ hb, float* __restrict__ ai,
    float* __restrict__ ajrd, int Nn) {
  int t = threadIdx.x;
  int lane = t & 63;  // d
  int wid = blockIdx.x * (blockDim.x >> 6) + (t >> 6);
  int nwaves = gridDim.x * (blockDim.x >> 6);

  float Wr0[64], Wr1[64];
#pragma unroll
  for (int k = 0; k < 64; ++k) {
    Wr0[k] = W[k * 128 + lane];
    Wr1[k] = W[k * 128 + 64 + lane];
  }
  float bs0 = bW[lane], bs1 = bW[64 + lane];
  float ati0 = att[lane];
  float atj0 = att[64 + lane];
  float ati1 = att[128 + lane];
  float atj1 = att[192 + lane];

  for (int row = wid; row < Nn; row += nwaves) {
    int r = __builtin_amdgcn_readfirstlane(row);
    const float* __restrict__ xr = x + (size_t)r * 64;
    float a0a = 0.f, a0b = 0.f, a1a = 0.f, a1b = 0.f;
#pragma unroll
    for (int k = 0; k < 64; k += 2) {
      float xk0 = xr[k], xk1 = xr[k + 1];
      a0a = fmaf(xk0, Wr0[k], a0a);
      a1a = fmaf(xk0, Wr1[k], a1a);
      a0b = fmaf(xk1, Wr0[k + 1], a0b);
      a1b = fmaf(xk1, Wr1[k + 1], a1b);
    }
    float h0 = a0a + a0b + bs0;
    float h1 = a1a + a1b + bs1;
    hb[(size_t)r * 64 + lane] = f2bf(h0) | (f2bf(h1) << 16);

    float ti0 = ati0 * h0, tj0 = atj0 * h0;
    float ti1 = ati1 * h1, tj1 = atj1 * h1;
    ti0 += __shfl_xor(ti0, 32, 64);
    tj0 += __shfl_xor(tj0, 32, 64);
    ti1 += __shfl_xor(ti1, 32, 64);
    tj1 += __shfl_xor(tj1, 32, 64);
    float mi = (lane < 32) ? ti0 : ti1;
    float mj = (lane < 32) ? tj0 : tj1;
#pragma unroll
    for (int off = 16; off > 0; off >>= 1) {
      mi += __shfl_xor(mi, off, 64);
      mj += __shfl_xor(mj, off, 64);
    }
    if ((lane & 31) == 0) {
      ai[r * 2 + (lane >> 5)] = mi;
      ajrd[(size_t)r * 4 + (lane >> 5)] = mj;
    }
  }
}

// ---------------------------------------------------------------------------
// K_bin: DUAL multi-split, 512 threads (round-15 win). ROUND 16: CHUNK=4096 —
// per-thread chains unchanged (8-deep), LDS 42KB (3 blocks/CU), but NBLK
// halves -> half the table metadata downstream.
// ---------------------------------------------------------------------------
__global__ __launch_bounds__(512) void k_bin(
    const int* __restrict__ ei, const int* __restrict__ eattr,
    unsigned int* __restrict__ rec, int* __restrict__ cnt_tbl,
    int* __restrict__ base_tbl, unsigned int* __restrict__ rec_src,
    int* __restrict__ cnt_tbl2, int* __restrict__ base_tbl2, int Ee, int NCB) {
  __shared__ unsigned sbuf[CHUNK];   // 16 KB
  __shared__ unsigned sbuf2[CHUNK];  // 16 KB
  __shared__ int hist[512], cur[512], hist2[512], cur2[512];
  __shared__ int ssc[512];
  int t = threadIdx.x;
  for (int i = t; i < NCB; i += 512) { hist[i] = 0; hist2[i] = 0; }
  __syncthreads();
  int start = blockIdx.x * CHUNK;
  int end = min(start + CHUNK, Ee);
  int cnt = end - start;
  int cbv[CHUNK / 512], cb2v[CHUNK / 512];
  unsigned pkv[CHUNK / 512], pk2v[CHUNK / 512];
  int nk = 0;
  for (int e = start + t; e < end; e += 512, ++nk) {
    int dst = __builtin_nontemporal_load(&ei[Ee + e]);
    int src = __builtin_nontemporal_load(&ei[e]);
    int a0 = __builtin_nontemporal_load(&eattr[e * 3]);
    int a1 = __builtin_nontemporal_load(&eattr[e * 3 + 1]);
    int a2 = __builtin_nontemporal_load(&eattr[e * 3 + 2]);
    unsigned c012 = (unsigned)(a0 + 5 * a1 + 25 * a2);
    cbv[nk] = dst >> 7;
    pkv[nk] = (unsigned)src | (c012 << 16) | ((unsigned)(dst & 127) << 23);
    cb2v[nk] = src >> 7;
    pk2v[nk] = (unsigned)dst | ((unsigned)(src & 127) << 17) | (c012 << 24);
    atomicAdd(&hist[dst >> 7], 1);
    atomicAdd(&hist2[src >> 7], 1);
  }
  __syncthreads();
  // parallel exclusive scans (512-wide Hillis-Steele, 1 value/thread)
  {
    int v = (t < NCB) ? hist[t] : 0;
    ssc[t] = v;
    __syncthreads();
#pragma unroll
    for (int o = 1; o < 512; o <<= 1) {
      int xv = (t >= o) ? ssc[t - o] : 0;
      __syncthreads();
      ssc[t] += xv;
      __syncthreads();
    }
    if (t < NCB) cur[t] = ssc[t] - v;
    __syncthreads();
    v = (t < NCB) ? hist2[t] : 0;
    ssc[t] = v;
    __syncthreads();
#pragma unroll
    for (int o = 1; o < 512; o <<= 1) {
      int xv = (t >= o) ? ssc[t - o] : 0;
      __syncthreads();
      ssc[t] += xv;
      __syncthreads();
    }
    if (t < NCB) cur2[t] = ssc[t] - v;
  }
  __syncthreads();
  for (int i = t; i < NCB; i += 512) {
    cnt_tbl[blockIdx.x * NCB + i] = hist[i];
    base_tbl[blockIdx.x * NCB + i] = cur[i];
    cnt_tbl2[blockIdx.x * NCB + i] = hist2[i];
    base_tbl2[blockIdx.x * NCB + i] = cur2[i];
  }
  __syncthreads();
  for (int k = 0; k < nk; ++k) {
    int pos = atomicAdd(&cur[cbv[k]], 1);
    sbuf[pos] = pkv[k];
    int pos2 = atomicAdd(&cur2[cb2v[k]], 1);
    sbuf2[pos2] = pk2v[k];
  }
  __syncthreads();
  for (int i = t; i < cnt; i += 512) {
    __builtin_nontemporal_store(sbuf[i], &rec[start + i]);
    __builtin_nontemporal_store(sbuf2[i], &rec_src[start + i]);
  }
}

// ---------------------------------------------------------------------------
// K_segoff_ab: both per-bucket segment-offset scans in ONE launch.
// ---------------------------------------------------------------------------
__global__ __launch_bounds__(256) void k_segoff_ab(
    const int* __restrict__ cnt_tbl, int* __restrict__ segdst,
    int* __restrict__ btot, const int* __restrict__ cnt_tbl2,
    int* __restrict__ segdst2, int* __restrict__ btot2, int NCB, int NBLK) {
  __shared__ int s[256];
  int t = threadIdx.x;
  int bid = blockIdx.x;
  const int* __restrict__ ct = (bid < NCB) ? cnt_tbl : cnt_tbl2;
  int* __restrict__ sd = (bid < NCB) ? segdst : segdst2;
  int* __restrict__ bt = (bid < NCB) ? btot : btot2;
  int cb = (bid < NCB) ? bid : bid - NCB;
  int per = (NBLK + 255) / 256;
  int loc[8];
  int sum = 0;
  for (int j = 0; j < per; ++j) {
    int blk = t * per + j;
    int v = (blk < NBLK) ? ct[blk * NCB + cb] : 0;
    loc[j] = sum;
    sum += v;
  }
  s[t] = sum;
  __syncthreads();
#pragma unroll
  for (int o = 1; o < 256; o <<= 1) {
    int xv = (t >= o) ? s[t - o] : 0;
    __syncthreads();
    s[t] += xv;
    __syncthreads();
  }
  int excl = s[t] - sum;
  for (int j = 0; j < per; ++j) {
    int blk = t * per + j;
    if (blk < NBLK) sd[cb * NBLK + blk] = excl + loc[j];
  }
  if (t == 255) bt[cb] = s[255];
}

// ---------------------------------------------------------------------------
// K_segoff_b: tiny single-block exclusive scan over dst bucket totals.
// Also precomputes tblg[30] (att·bemb dot products) for k_norm.
// ---------------------------------------------------------------------------
__global__ __launch_bounds__(512) void k_segoff_b(
    const int* __restrict__ btot, int* __restrict__ coarse_base,
    const float* __restrict__ att, const float* __restrict__ bemb,
    float* __restrict__ tblg, int NCB, int Ee) {
  __shared__ int s[512];
  int t = threadIdx.x;
  if (t < 30) {
    int f = t / 10, rem = t % 10, c = rem >> 1, hh = rem & 1;
    float sacc = 0.f;
    for (int d = 0; d < 64; ++d)
      sacc += att[hh * 128 + 64 + d] * bemb[(f * 5 + c) * 128 + hh * 64 + d];
    tblg[t] = sacc;
  }
  int v = (t < NCB) ? btot[t] : 0;
  s[t] = v;
  __syncthreads();
#pragma unroll
  for (int o = 1; o < 512; o <<= 1) {
    int xv = (t >= o) ? s[t - o] : 0;
    __syncthreads();
    s[t] += xv;
    __syncthreads();
  }
  if (t < NCB) coarse_base[t] = s[t] - v;
  if (t == 0) coarse_base[NCB] = Ee;
}

// ---------------------------------------------------------------------------
// K_mid: FUSED k_sacc + k_sort, 512 threads, VGPR capped via
// __launch_bounds__(512, 8) (round-14). With CHUNK=4096, NBLK=391 < 512:
// each thread stages at most ONE ~10.5-record segment (half the metadata
// loads, doubled run length). SORT emits eix2 + AI partials; SACC -> rden.
// ---------------------------------------------------------------------------
__global__ __launch_bounds__(512, 8) void k_mid(
    const unsigned int* __restrict__ rec, const int* __restrict__ cnt_tbl,
    const int* __restrict__ base_tbl, const int* __restrict__ segdst,
    const int* __restrict__ coarse_base,
    const unsigned int* __restrict__ rec_src, const int* __restrict__ cnt_tbl2,
    const int* __restrict__ base_tbl2, const int* __restrict__ segdst2,
    const int* __restrict__ btot2,
    const float2* __restrict__ ai2, float* __restrict__ ajrd,
    const float* __restrict__ att, const float* __restrict__ bemb,
    unsigned int* __restrict__ eix2, float2* __restrict__ alpha2,
    int* __restrict__ off, int Nn, int NCB, int NBLK, int Ee) {
  __shared__ unsigned ubuf[SCAP];   // 20 KB
  __shared__ unsigned ubuf2[SCAP];  // 20 KB (sort half only)
  __shared__ int hist[NPB2], basex[NPB2], curx[NPB2], scn[NPB2];
  __shared__ float tbl[30];
  __shared__ float2 nodev[NPB2];    // ajs (sacc) / ais (sort)
  __shared__ float sdl[NPB2 * 2];   // sacc accumulators
  int t = threadIdx.x;
  if (t < 30) {
    int f = t / 10, rem = t % 10, c = rem >> 1, hh = rem & 1;
    float sacc = 0.f;
    for (int d = 0; d < 64; ++d)
      sacc += att[hh * 128 + 64 + d] * bemb[(f * 5 + c) * 128 + hh * 64 + d];
    tbl[t] = sacc;
  }

  if (blockIdx.x < NCB) {
    // ------------------------------ SACC half ------------------------------
    int cb = blockIdx.x;
    int node0 = cb << 7;
    if (t < NPB2 && node0 + t < Nn)
      nodev[t] = *(const float2*)(ajrd + (size_t)(node0 + t) * 4);
    if (t < NPB2 * 2) sdl[t] = 0.f;
    int total = btot2[cb];
    __syncthreads();
    bool fits = (total <= SCAP);

#define SACC_BODY(U, AIV)                                                      \
    {                                                                          \
      int sl = ((U) >> 17) & 127;                                              \
      int c012 = ((U) >> 24) & 127;                                            \
      int a0 = c012 % 5, a1 = (c012 / 5) % 5, a2 = c012 / 25;                  \
      float2 ajv = nodev[sl];                                                  \
      float lg0 = AIV.x + ajv.x + tbl[a0 * 2] + tbl[10 + a1 * 2] +             \
                  tbl[20 + a2 * 2];                                            \
      float lg1 = AIV.y + ajv.y + tbl[a0 * 2 + 1] + tbl[10 + a1 * 2 + 1] +     \
                  tbl[20 + a2 * 2 + 1];                                        \
      lg0 = lg0 >= 0.f ? lg0 : NEG_SLOPE * lg0;                                \
      lg1 = lg1 >= 0.f ? lg1 : NEG_SLOPE * lg1;                                \
      atomicAdd(&sdl[sl * 2], __expf(lg0));                                    \
      atomicAdd(&sdl[sl * 2 + 1], __expf(lg1));                                \
    }

    if (fits) {
      for (int blk = t; blk < NBLK; blk += 512) {
        int len = cnt_tbl2[blk * NCB + cb];
        if (!len) continue;
        int sp = blk * CHUNK + base_tbl2[blk * NCB + cb];
        int dp = segdst2[cb * NBLK + blk];
        for (int j = 0; j < len; ++j) ubuf[dp + j] = rec_src[sp + j];
      }
      __syncthreads();
      int i = t;
      for (; i + 7 * 512 < total; i += 8 * 512) {
        unsigned u[8];
        float2 aiv[8];
#pragma unroll
        for (int k = 0; k < 8; ++k) u[k] = ubuf[i + k * 512];
#pragma unroll
        for (int k = 0; k < 8; ++k) aiv[k] = ai2[u[k] & 0x1FFFF];
#pragma unroll
        for (int k = 0; k < 8; ++k) SACC_BODY(u[k], aiv[k])
      }
      for (; i < total; i += 512) {
        unsigned u = ubuf[i];
        float2 aiv = ai2[u & 0x1FFFF];
        SACC_BODY(u, aiv)
      }
    } else {
      for (int blk = t; blk < NBLK; blk += 512) {
        int len = cnt_tbl2[blk * NCB + cb];
        int sp = blk * CHUNK + base_tbl2[blk * NCB + cb];
        for (int j = 0; j < len; ++j) {
          unsigned u = rec_src[sp + j];
          float2 aiv = ai2[u & 0x1FFFF];
          SACC_BODY(u, aiv)
        }
      }
    }
#undef SACC_BODY
    __syncthreads();
    if (t < NPB2 * 2) {
      int node = node0 + (t >> 1);
      if (node < Nn)
        ajrd[(size_t)node * 4 + 2 + (t & 1)] = 1.0f / (sdl[t] + 1e-16f);
    }

  } else {
    // ------------------------------ SORT half ------------------------------
    int cb = blockIdx.x - NCB;
    int node0 = cb << 7;
    if (t < NPB2) {
      hist[t] = 0;
      if (node0 + t < Nn) nodev[t] = ai2[node0 + t];
    }
    int gbase = coarse_base[cb];
    int total = coarse_base[cb + 1] - gbase;
    __syncthreads();
    bool fits = (total <= SCAP);

    if (fits) {
      for (int blk = t; blk < NBLK; blk += 512) {
        int len = cnt_tbl[blk * NCB + cb];
        if (!len) continue;
        int sp = blk * CHUNK + base_tbl[blk * NCB + cb];
        int dp = segdst[cb * NBLK + blk];
        for (int j = 0; j < len; ++j) ubuf[dp + j] = rec[sp + j];
      }
      __syncthreads();
      for (int i = t; i < total; i += 512)
        atomicAdd(&hist[(ubuf[i] >> 23) & 127], 1);
      __syncthreads();
      // parallel exclusive scan over 128 bins (Hillis-Steele)
      if (t < NPB2) scn[t] = hist[t];
      __syncthreads();
#pragma unroll
      for (int o = 1; o < NPB2; o <<= 1) {
        int v = (t < NPB2 && t >= o) ? scn[t - o] : 0;
        __syncthreads();
        if (t < NPB2) scn[t] += v;
        __syncthreads();
      }
      if (t < NPB2) {
        basex[t] = scn[t] - hist[t];
        curx[t] = scn[t] - hist[t];
        if (node0 + t < Nn) off[node0 + t] = gbase + scn[t] - hist[t];
      }
      if (cb == 0 && t == 0) off[Nn] = Ee;
      __syncthreads();
      for (int i = t; i < total; i += 512) {
        unsigned u = ubuf[i];
        int pos = atomicAdd(&curx[(u >> 23) & 127], 1);
        ubuf2[pos] = u;
      }
      __syncthreads();
      // output: eix2 + AI-partials only (no gathers, no exp)
      for (int i = t; i < total; i += 512) {
        unsigned u = ubuf2[i];
        int src = u & 0xFFFF;
        int c012 = (u >> 16) & 127;
        int dl = (u >> 23) & 127;
        int a0 = c012 % 5, a1 = (c012 / 5) % 5, a2 = c012 / 25;
        eix2[gbase + i] = (unsigned)src | ((unsigned)a0 << 16) |
                          ((unsigned)a1 << 19) | ((unsigned)a2 << 22);
        alpha2[gbase + i] = nodev[dl];
      }
    } else {
      // fallback (statistically unreachable): global-read path
      for (int blk = t; blk < NBLK; blk += 512) {
        int len = cnt_tbl[blk * NCB + cb];
        int sp = blk * CHUNK + base_tbl[blk * NCB + cb];
        for (int j = 0; j < len; ++j)
          atomicAdd(&hist[(rec[sp + j] >> 23) & 127], 1);
      }
      __syncthreads();
      if (t == 0) {
        int s = 0;
        for (int i = 0; i < NPB2; ++i) { basex[i] = s; s += hist[i]; }
      }
      __syncthreads();
      if (t < NPB2) {
        curx[t] = basex[t];
        if (node0 + t < Nn) off[node0 + t] = gbase + basex[t];
      }
      if (cb == 0 && t == 0) off[Nn] = Ee;
      __syncthreads();
      for (int blk = t; blk < NBLK; blk += 512) {
        int len = cnt_tbl[blk * NCB + cb];
        int sp = blk * CHUNK + base_tbl[blk * NCB + cb];
        for (int j = 0; j < len; ++j) {
          unsigned u = rec[sp + j];
          int src = u & 0xFFFF;
          int c012 = (u >> 16) & 127;
          int dl = (u >> 23) & 127;
          int a0 = c012 % 5, a1 = (c012 / 5) % 5, a2 = c012 / 25;
          int pos = gbase + atomicAdd(&curx[dl], 1);
          eix2[pos] = (unsigned)src | ((unsigned)a0 << 16) |
                      ((unsigned)a1 << 19) | ((unsigned)a2 << 22);
          alpha2[pos] = nodev[dl];
        }
      }
    }
  }
}

// ---------------------------------------------------------------------------
// K_norm: finishes the logit at FULL occupancy. Per edge: one float4 gather
// ajrd[src] = (aj0,aj1,rden0,rden1), lg = ai_part + aj + tbl[attrs], leaky,
// alpha = exp(lg) * rden. Same add order as the fused version.
// ---------------------------------------------------------------------------
__global__ __launch_bounds__(256) void k_norm(
    const unsigned int* __restrict__ eix, float2* __restrict__ alpha2,
    const float4* __restrict__ ajrd4, const float* __restrict__ tblg, int Ee) {
  __shared__ float tbl[30];
  int t = threadIdx.x;
  if (t < 30) tbl[t] = tblg[t];
  __syncthreads();

#define NORM_BODY(U, A, F, OUT)                                                \
  {                                                                            \
    int a0 = ((U) >> 16) & 7, a1 = ((U) >> 19) & 7, a2 = ((U) >> 22) & 7;      \
    float lg0 = (A).x + (F).x + tbl[a0 * 2] + tbl[10 + a1 * 2] +               \
                tbl[20 + a2 * 2];                                              \
    float lg1 = (A).y + (F).y + tbl[a0 * 2 + 1] + tbl[10 + a1 * 2 + 1] +       \
                tbl[20 + a2 * 2 + 1];                                          \
    lg0 = lg0 >= 0.f ? lg0 : NEG_SLOPE * lg0;                                  \
    lg1 = lg1 >= 0.f ? lg1 : NEG_SLOPE * lg1;                                  \
    OUT = make_float2(__expf(lg0) * (F).z, __expf(lg1) * (F).w);               \
  }

  int g = blockIdx.x * 256 + t;
  int e = g * 4;
  if (e + 4 <= Ee) {
    uint4 u = *reinterpret_cast<const uint4*>(&eix[e]);
    float4 f0 = ajrd4[u.x & 0xFFFFu];
    float4 f1 = ajrd4[u.y & 0xFFFFu];
    float4 f2 = ajrd4[u.z & 0xFFFFu];
    float4 f3 = ajrd4[u.w & 0xFFFFu];
    float2 a0v = alpha2[e], a1v = alpha2[e + 1];
    float2 a2v = alpha2[e + 2], a3v = alpha2[e + 3];
    float2 o0, o1, o2, o3;
    NORM_BODY(u.x, a0v, f0, o0)
    NORM_BODY(u.y, a1v, f1, o1)
    NORM_BODY(u.z, a2v, f2, o2)
    NORM_BODY(u.w, a3v, f3, o3)
    alpha2[e] = o0; alpha2[e + 1] = o1;
    alpha2[e + 2] = o2; alpha2[e + 3] = o3;
  } else {
    for (; e < Ee; ++e) {
      unsigned u = eix[e];
      float4 f = ajrd4[u & 0xFFFFu];
      float2 a = alpha2[e];
      float2 o;
      NORM_BODY(u, a, f, o)
      alpha2[e] = o;
    }
  }
#undef NORM_BODY
}

// ---------------------------------------------------------------------------
// K_gather: round-7 body (verified 58.1-58.3us). alpha2 holds FINAL alpha.
// One block of 4 waves per 4 nodes, scalarized uniform loads, myshift shave.
// ---------------------------------------------------------------------------
__global__ __launch_bounds__(256) void k_gather(
    const unsigned int* __restrict__ eix, const float2* __restrict__ alpha2,
    const int* __restrict__ off, const unsigned int* __restrict__ hb,
    const float* __restrict__ bemb, const float* __restrict__ bias,
    float* __restrict__ out, int Nn) {
  __shared__ float bembs[15 * 128];  // [f*5+c][128]
  __shared__ float wsm[4][32];
  int t = threadIdx.x;
  for (int i = t; i < 15 * 128; i += 256) bembs[i] = bemb[i];
  __syncthreads();
  int wave = t >> 6, lane = t & 63;
  int n = blockIdx.x * 4 + wave;
  if (n >= Nn) return;
  int p0 = __builtin_amdgcn_readfirstlane(off[n]);
  int p1 = __builtin_amdgcn_readfirstlane(off[n + 1]);
  int myf = lane / 5;                 // 0..2 for lanes 0..14
  int myc = lane % 5;
  bool active = lane < 15;
  int myshift = 16 + 3 * myf;         // {16,19,22}: a0/a1/a2 bit positions
  int mycEff = active ? myc : 8;      // sel in 0..7 -> 8 never matches
  float w0 = 0.f, w1 = 0.f;
  float acc0 = 0.f, acc1 = 0.f;

#define EDGE_BODY(U, HV, AL)                                                   \
  {                                                                            \
    acc0 = fmaf((AL).x, __uint_as_float((HV) << 16), acc0);                    \
    acc1 = fmaf((AL).y, __uint_as_float((HV) & 0xffff0000u), acc1);            \
    int sel = (int)(((U) >> myshift) & 7u);                                    \
    float m = (sel == mycEff) ? 1.0f : 0.0f;                                   \
    w0 = fmaf(m, (AL).x, w0);                                                  \
    w1 = fmaf(m, (AL).y, w1);                                                  \
  }

  int p = p0;
  for (; p + 8 <= p1; p += 8) {
    unsigned u[8], hv[8];
    float2 al[8];
#pragma unroll
    for (int k = 0; k < 8; ++k) u[k] = eix[p + k];       // uniform -> s_load
#pragma unroll
    for (int k = 0; k < 8; ++k) al[k] = alpha2[p + k];   // uniform -> s_load
#pragma unroll
    for (int k = 0; k < 8; ++k) {
      const unsigned* __restrict__ hrow = hb + ((size_t)(u[k] & 0xFFFFu) << 6);
      hv[k] = hrow[lane];                                // s[base] + v_laneoff
    }
#pragma unroll
    for (int k = 0; k < 8; ++k) EDGE_BODY(u[k], hv[k], al[k])
  }
  for (; p < p1; ++p) {
    unsigned ue = eix[p];
    float2 ale = alpha2[p];
    const unsigned* __restrict__ hrow = hb + ((size_t)(ue & 0xFFFFu) << 6);
    unsigned hve = hrow[lane];
    EDGE_BODY(ue, hve, ale)
  }
#undef EDGE_BODY

  if (active) {
    wsm[wave][lane * 2] = w0;      // same-wave LDS ops are in-order
    wsm[wave][lane * 2 + 1] = w1;
  }
#pragma unroll
  for (int k = 0; k < 15; ++k) {
    acc0 += wsm[wave][k * 2] * bembs[k * 128 + lane];
    acc1 += wsm[wave][k * 2 + 1] * bembs[k * 128 + 64 + lane];
  }
  out[(size_t)n * 64 + lane] = 0.5f * (acc0 + acc1) + bias[lane];
}

extern "C" void kernel_launch(void* const* d_in, const int* in_sizes, int n_in,
                              void* d_out, int out_size, void* d_ws, size_t ws_size,
                              hipStream_t stream) {
  const float* x    = (const float*)d_in[0];
  const int*   ei   = (const int*)d_in[1];
  const int*   eatt = (const int*)d_in[2];
  const float* W    = (const float*)d_in[3];
  const float* bW   = (const float*)d_in[4];
  const float* att  = (const float*)d_in[5];
  const float* bias = (const float*)d_in[6];
  const float* bemb = (const float*)d_in[7];
  int Nn = in_sizes[0] / 64;
  int Ee = in_sizes[1] / 2;
  int NCB = (Nn + NPB2 - 1) / NPB2;            // 391 coarse buckets (128 nodes)
  int NBLK = (Ee + CHUNK - 1) / CHUNK;         // 391 bin blocks (CHUNK=4096)

  char* ws = (char*)d_ws;
  ws = (char*)(((uintptr_t)ws + 15) & ~(uintptr_t)15);
  float* ajrd = (float*)ws;               ws += (size_t)Nn * 4 * 4;  // 16B-aligned
  float* ai = (float*)ws;                 ws += (size_t)Nn * 2 * 4;
  float* tblg = (float*)ws;               ws += 32 * 4;
  unsigned int* hb = (unsigned int*)ws;   ws += (size_t)Nn * 64 * 4;
  unsigned int* rec = (unsigned int*)ws;  ws += (size_t)NBLK * CHUNK * 4;
  unsigned int* rec_src = (unsigned int*)ws; ws += (size_t)NBLK * CHUNK * 4;
  unsigned int* eix2 = (unsigned int*)ws; ws += (size_t)Ee * 4;
  float2* alpha2 = (float2*)ws;           ws += (size_t)Ee * 8;
  int* off = (int*)ws;                    ws += (size_t)(Nn + 1) * 4;
  int* cnt_tbl = (int*)ws;                ws += (size_t)NBLK * NCB * 4;
  int* base_tbl = (int*)ws;               ws += (size_t)NBLK * NCB * 4;
  int* cnt_tbl2 = (int*)ws;               ws += (size_t)NBLK * NCB * 4;
  int* base_tbl2 = (int*)ws;              ws += (size_t)NBLK * NCB * 4;
  int* segdst = (int*)ws;                 ws += (size_t)NCB * NBLK * 4;
  int* segdst2 = (int*)ws;                ws += (size_t)NCB * NBLK * 4;
  int* coarse_base = (int*)ws;            ws += (size_t)(NCB + 1) * 4;
  int* btot = (int*)ws;                   ws += (size_t)NCB * 4;
  int* btot2 = (int*)ws;                  ws += (size_t)NCB * 4;

  k1_gemm<<<1024, 256, 0, stream>>>(x, W, bW, att, hb, ai, ajrd, Nn);
  k_bin<<<NBLK, 512, 0, stream>>>(ei, eatt, rec, cnt_tbl, base_tbl, rec_src,
                                  cnt_tbl2, base_tbl2, Ee, NCB);
  k_segoff_ab<<<2 * NCB, 256, 0, stream>>>(cnt_tbl, segdst, btot, cnt_tbl2,
                                           segdst2, btot2, NCB, NBLK);
  k_segoff_b<<<1, 512, 0, stream>>>(btot, coarse_base, att, bemb, tblg, NCB, Ee);
  k_mid<<<2 * NCB, 512, 0, stream>>>(rec, cnt_tbl, base_tbl, segdst,
                                     coarse_base, rec_src, cnt_tbl2, base_tbl2,
                                     segdst2, btot2, (const float2*)ai, ajrd,
                                     att, bemb, eix2, alpha2, off,
                                     Nn, NCB, NBLK, Ee);
  k_norm<<<(Ee / 4 + 255) / 256, 256, 0, stream>>>(eix2, alpha2,
                                                   (const float4*)ajrd, tblg, Ee);
  k_gather<<<(Nn + 3) / 4, 256, 0, stream>>>(eix2, alpha2, off, hb, bemb, bias,
                                             (float*)d_out, Nn);
}

// Round 17
// 257.211 us; speedup vs baseline: 1.1253x; 1.0004x over previous
//
#include <hip/hip_runtime.h>
#include <hip/hip_bf16.h>
#include <math.h>

#define NEG_SLOPE 0.2f
#define CHUNK 4096      // edges per k_bin block
#define NPB2 128        // nodes per coarse bucket
#define SCAP 5120       // LDS record capacity (bucket mean ~4092, sd ~64)

__device__ __forceinline__ unsigned f2bf(float f) {
  unsigned u = __float_as_uint(f);
  return (u + 0x7fffu + ((u >> 16) & 1u)) >> 16;  // RNE
}

// ---------------------------------------------------------------------------
// K1: h = x @ W + b_W. Register-stationary: one wave per row, W columns in
// 128 VGPRs, x row via scalar loads, zero LDS. aj written into the combined
// ajrd float4 table (aj0,aj1,rden0,rden1) — rden filled by k_mid.
// ---------------------------------------------------------------------------
__global__ __launch_bounds__(256) void k1_gemm(
    const float* __restrict__ x, const float* __restrict__ W,
    const float* __restrict__ bW, const float* __restrict__ att,
    unsigned int* __restrict__ hb, float* __restrict__ ai,
    float* __restrict__ ajrd, int Nn) {
  int t = threadIdx.x;
  int lane = t & 63;  // d
  int wid = blockIdx.x * (blockDim.x >> 6) + (t >> 6);
  int nwaves = gridDim.x * (blockDim.x >> 6);

  float Wr0[64], Wr1[64];
#pragma unroll
  for (int k = 0; k < 64; ++k) {
    Wr0[k] = W[k * 128 + lane];
    Wr1[k] = W[k * 128 + 64 + lane];
  }
  float bs0 = bW[lane], bs1 = bW[64 + lane];
  float ati0 = att[lane];
  float atj0 = att[64 + lane];
  float ati1 = att[128 + lane];
  float atj1 = att[192 + lane];

  for (int row = wid; row < Nn; row += nwaves) {
    int r = __builtin_amdgcn_readfirstlane(row);
    const float* __restrict__ xr = x + (size_t)r * 64;
    float a0a = 0.f, a0b = 0.f, a1a = 0.f, a1b = 0.f;
#pragma unroll
    for (int k = 0; k < 64; k += 2) {
      float xk0 = xr[k], xk1 = xr[k + 1];
      a0a = fmaf(xk0, Wr0[k], a0a);
      a1a = fmaf(xk0, Wr1[k], a1a);
      a0b = fmaf(xk1, Wr0[k + 1], a0b);
      a1b = fmaf(xk1, Wr1[k + 1], a1b);
    }
    float h0 = a0a + a0b + bs0;
    float h1 = a1a + a1b + bs1;
    hb[(size_t)r * 64 + lane] = f2bf(h0) | (f2bf(h1) << 16);

    float ti0 = ati0 * h0, tj0 = atj0 * h0;
    float ti1 = ati1 * h1, tj1 = atj1 * h1;
    ti0 += __shfl_xor(ti0, 32, 64);
    tj0 += __shfl_xor(tj0, 32, 64);
    ti1 += __shfl_xor(ti1, 32, 64);
    tj1 += __shfl_xor(tj1, 32, 64);
    float mi = (lane < 32) ? ti0 : ti1;
    float mj = (lane < 32) ? tj0 : tj1;
#pragma unroll
    for (int off = 16; off > 0; off >>= 1) {
      mi += __shfl_xor(mi, off, 64);
      mj += __shfl_xor(mj, off, 64);
    }
    if ((lane & 31) == 0) {
      ai[r * 2 + (lane >> 5)] = mi;
      ajrd[(size_t)r * 4 + (lane >> 5)] = mj;
    }
  }
}

// ---------------------------------------------------------------------------
// K_bin: DUAL multi-split, 512 threads, CHUNK=4096 (round-15/16 wins).
// ---------------------------------------------------------------------------
__global__ __launch_bounds__(512) void k_bin(
    const int* __restrict__ ei, const int* __restrict__ eattr,
    unsigned int* __restrict__ rec, int* __restrict__ cnt_tbl,
    int* __restrict__ base_tbl, unsigned int* __restrict__ rec_src,
    int* __restrict__ cnt_tbl2, int* __restrict__ base_tbl2, int Ee, int NCB) {
  __shared__ unsigned sbuf[CHUNK];   // 16 KB
  __shared__ unsigned sbuf2[CHUNK];  // 16 KB
  __shared__ int hist[512], cur[512], hist2[512], cur2[512];
  __shared__ int ssc[512];
  int t = threadIdx.x;
  for (int i = t; i < NCB; i += 512) { hist[i] = 0; hist2[i] = 0; }
  __syncthreads();
  int start = blockIdx.x * CHUNK;
  int end = min(start + CHUNK, Ee);
  int cnt = end - start;
  int cbv[CHUNK / 512], cb2v[CHUNK / 512];
  unsigned pkv[CHUNK / 512], pk2v[CHUNK / 512];
  int nk = 0;
  for (int e = start + t; e < end; e += 512, ++nk) {
    int dst = __builtin_nontemporal_load(&ei[Ee + e]);
    int src = __builtin_nontemporal_load(&ei[e]);
    int a0 = __builtin_nontemporal_load(&eattr[e * 3]);
    int a1 = __builtin_nontemporal_load(&eattr[e * 3 + 1]);
    int a2 = __builtin_nontemporal_load(&eattr[e * 3 + 2]);
    unsigned c012 = (unsigned)(a0 + 5 * a1 + 25 * a2);
    cbv[nk] = dst >> 7;
    pkv[nk] = (unsigned)src | (c012 << 16) | ((unsigned)(dst & 127) << 23);
    cb2v[nk] = src >> 7;
    pk2v[nk] = (unsigned)dst | ((unsigned)(src & 127) << 17) | (c012 << 24);
    atomicAdd(&hist[dst >> 7], 1);
    atomicAdd(&hist2[src >> 7], 1);
  }
  __syncthreads();
  // parallel exclusive scans (512-wide Hillis-Steele, 1 value/thread)
  {
    int v = (t < NCB) ? hist[t] : 0;
    ssc[t] = v;
    __syncthreads();
#pragma unroll
    for (int o = 1; o < 512; o <<= 1) {
      int xv = (t >= o) ? ssc[t - o] : 0;
      __syncthreads();
      ssc[t] += xv;
      __syncthreads();
    }
    if (t < NCB) cur[t] = ssc[t] - v;
    __syncthreads();
    v = (t < NCB) ? hist2[t] : 0;
    ssc[t] = v;
    __syncthreads();
#pragma unroll
    for (int o = 1; o < 512; o <<= 1) {
      int xv = (t >= o) ? ssc[t - o] : 0;
      __syncthreads();
      ssc[t] += xv;
      __syncthreads();
    }
    if (t < NCB) cur2[t] = ssc[t] - v;
  }
  __syncthreads();
  for (int i = t; i < NCB; i += 512) {
    cnt_tbl[blockIdx.x * NCB + i] = hist[i];
    base_tbl[blockIdx.x * NCB + i] = cur[i];
    cnt_tbl2[blockIdx.x * NCB + i] = hist2[i];
    base_tbl2[blockIdx.x * NCB + i] = cur2[i];
  }
  __syncthreads();
  for (int k = 0; k < nk; ++k) {
    int pos = atomicAdd(&cur[cbv[k]], 1);
    sbuf[pos] = pkv[k];
    int pos2 = atomicAdd(&cur2[cb2v[k]], 1);
    sbuf2[pos2] = pk2v[k];
  }
  __syncthreads();
  for (int i = t; i < cnt; i += 512) {
    __builtin_nontemporal_store(sbuf[i], &rec[start + i]);
    __builtin_nontemporal_store(sbuf2[i], &rec_src[start + i]);
  }
}

// ---------------------------------------------------------------------------
// K_segoff_ab: both per-bucket segment-offset scans in ONE launch.
// ---------------------------------------------------------------------------
__global__ __launch_bounds__(256) void k_segoff_ab(
    const int* __restrict__ cnt_tbl, int* __restrict__ segdst,
    int* __restrict__ btot, const int* __restrict__ cnt_tbl2,
    int* __restrict__ segdst2, int* __restrict__ btot2, int NCB, int NBLK) {
  __shared__ int s[256];
  int t = threadIdx.x;
  int bid = blockIdx.x;
  const int* __restrict__ ct = (bid < NCB) ? cnt_tbl : cnt_tbl2;
  int* __restrict__ sd = (bid < NCB) ? segdst : segdst2;
  int* __restrict__ bt = (bid < NCB) ? btot : btot2;
  int cb = (bid < NCB) ? bid : bid - NCB;
  int per = (NBLK + 255) / 256;
  int loc[8];
  int sum = 0;
  for (int j = 0; j < per; ++j) {
    int blk = t * per + j;
    int v = (blk < NBLK) ? ct[blk * NCB + cb] : 0;
    loc[j] = sum;
    sum += v;
  }
  s[t] = sum;
  __syncthreads();
#pragma unroll
  for (int o = 1; o < 256; o <<= 1) {
    int xv = (t >= o) ? s[t - o] : 0;
    __syncthreads();
    s[t] += xv;
    __syncthreads();
  }
  int excl = s[t] - sum;
  for (int j = 0; j < per; ++j) {
    int blk = t * per + j;
    if (blk < NBLK) sd[cb * NBLK + blk] = excl + loc[j];
  }
  if (t == 255) bt[cb] = s[255];
}

// ---------------------------------------------------------------------------
// K_segoff_b: tiny single-block exclusive scan over dst bucket totals.
// Also precomputes tblg[30] (att·bemb dot products) for k_norm.
// ---------------------------------------------------------------------------
__global__ __launch_bounds__(512) void k_segoff_b(
    const int* __restrict__ btot, int* __restrict__ coarse_base,
    const float* __restrict__ att, const float* __restrict__ bemb,
    float* __restrict__ tblg, int NCB, int Ee) {
  __shared__ int s[512];
  int t = threadIdx.x;
  if (t < 30) {
    int f = t / 10, rem = t % 10, c = rem >> 1, hh = rem & 1;
    float sacc = 0.f;
    for (int d = 0; d < 64; ++d)
      sacc += att[hh * 128 + 64 + d] * bemb[(f * 5 + c) * 128 + hh * 64 + d];
    tblg[t] = sacc;
  }
  int v = (t < NCB) ? btot[t] : 0;
  s[t] = v;
  __syncthreads();
#pragma unroll
  for (int o = 1; o < 512; o <<= 1) {
    int xv = (t >= o) ? s[t - o] : 0;
    __syncthreads();
    s[t] += xv;
    __syncthreads();
  }
  if (t < NCB) coarse_base[t] = s[t] - v;
  if (t == 0) coarse_base[NCB] = Ee;
}

// ---------------------------------------------------------------------------
// K_mid: FUSED k_sacc + k_sort, 512 threads, VGPR capped via
// __launch_bounds__(512, 8). SORT emits eix2 + AI partials; SACC -> rden.
// ---------------------------------------------------------------------------
__global__ __launch_bounds__(512, 8) void k_mid(
    const unsigned int* __restrict__ rec, const int* __restrict__ cnt_tbl,
    const int* __restrict__ base_tbl, const int* __restrict__ segdst,
    const int* __restrict__ coarse_base,
    const unsigned int* __restrict__ rec_src, const int* __restrict__ cnt_tbl2,
    const int* __restrict__ base_tbl2, const int* __restrict__ segdst2,
    const int* __restrict__ btot2,
    const float2* __restrict__ ai2, float* __restrict__ ajrd,
    const float* __restrict__ att, const float* __restrict__ bemb,
    unsigned int* __restrict__ eix2, float2* __restrict__ alpha2,
    int* __restrict__ off, int Nn, int NCB, int NBLK, int Ee) {
  __shared__ unsigned ubuf[SCAP];   // 20 KB
  __shared__ unsigned ubuf2[SCAP];  // 20 KB (sort half only)
  __shared__ int hist[NPB2], basex[NPB2], curx[NPB2], scn[NPB2];
  __shared__ float tbl[30];
  __shared__ float2 nodev[NPB2];    // ajs (sacc) / ais (sort)
  __shared__ float sdl[NPB2 * 2];   // sacc accumulators
  int t = threadIdx.x;
  if (t < 30) {
    int f = t / 10, rem = t % 10, c = rem >> 1, hh = rem & 1;
    float sacc = 0.f;
    for (int d = 0; d < 64; ++d)
      sacc += att[hh * 128 + 64 + d] * bemb[(f * 5 + c) * 128 + hh * 64 + d];
    tbl[t] = sacc;
  }

  if (blockIdx.x < NCB) {
    // ------------------------------ SACC half ------------------------------
    int cb = blockIdx.x;
    int node0 = cb << 7;
    if (t < NPB2 && node0 + t < Nn)
      nodev[t] = *(const float2*)(ajrd + (size_t)(node0 + t) * 4);
    if (t < NPB2 * 2) sdl[t] = 0.f;
    int total = btot2[cb];
    __syncthreads();
    bool fits = (total <= SCAP);

#define SACC_BODY(U, AIV)                                                      \
    {                                                                          \
      int sl = ((U) >> 17) & 127;                                              \
      int c012 = ((U) >> 24) & 127;                                            \
      int a0 = c012 % 5, a1 = (c012 / 5) % 5, a2 = c012 / 25;                  \
      float2 ajv = nodev[sl];                                                  \
      float lg0 = AIV.x + ajv.x + tbl[a0 * 2] + tbl[10 + a1 * 2] +             \
                  tbl[20 + a2 * 2];                                            \
      float lg1 = AIV.y + ajv.y + tbl[a0 * 2 + 1] + tbl[10 + a1 * 2 + 1] +     \
                  tbl[20 + a2 * 2 + 1];                                        \
      lg0 = lg0 >= 0.f ? lg0 : NEG_SLOPE * lg0;                                \
      lg1 = lg1 >= 0.f ? lg1 : NEG_SLOPE * lg1;                                \
      atomicAdd(&sdl[sl * 2], __expf(lg0));                                    \
      atomicAdd(&sdl[sl * 2 + 1], __expf(lg1));                                \
    }

    if (fits) {
      for (int blk = t; blk < NBLK; blk += 512) {
        int len = cnt_tbl2[blk * NCB + cb];
        if (!len) continue;
        int sp = blk * CHUNK + base_tbl2[blk * NCB + cb];
        int dp = segdst2[cb * NBLK + blk];
        for (int j = 0; j < len; ++j) ubuf[dp + j] = rec_src[sp + j];
      }
      __syncthreads();
      int i = t;
      for (; i + 7 * 512 < total; i += 8 * 512) {
        unsigned u[8];
        float2 aiv[8];
#pragma unroll
        for (int k = 0; k < 8; ++k) u[k] = ubuf[i + k * 512];
#pragma unroll
        for (int k = 0; k < 8; ++k) aiv[k] = ai2[u[k] & 0x1FFFF];
#pragma unroll
        for (int k = 0; k < 8; ++k) SACC_BODY(u[k], aiv[k])
      }
      for (; i < total; i += 512) {
        unsigned u = ubuf[i];
        float2 aiv = ai2[u & 0x1FFFF];
        SACC_BODY(u, aiv)
      }
    } else {
      for (int blk = t; blk < NBLK; blk += 512) {
        int len = cnt_tbl2[blk * NCB + cb];
        int sp = blk * CHUNK + base_tbl2[blk * NCB + cb];
        for (int j = 0; j < len; ++j) {
          unsigned u = rec_src[sp + j];
          float2 aiv = ai2[u & 0x1FFFF];
          SACC_BODY(u, aiv)
        }
      }
    }
#undef SACC_BODY
    __syncthreads();
    if (t < NPB2 * 2) {
      int node = node0 + (t >> 1);
      if (node < Nn)
        ajrd[(size_t)node * 4 + 2 + (t & 1)] = 1.0f / (sdl[t] + 1e-16f);
    }

  } else {
    // ------------------------------ SORT half ------------------------------
    int cb = blockIdx.x - NCB;
    int node0 = cb << 7;
    if (t < NPB2) {
      hist[t] = 0;
      if (node0 + t < Nn) nodev[t] = ai2[node0 + t];
    }
    int gbase = coarse_base[cb];
    int total = coarse_base[cb + 1] - gbase;
    __syncthreads();
    bool fits = (total <= SCAP);

    if (fits) {
      for (int blk = t; blk < NBLK; blk += 512) {
        int len = cnt_tbl[blk * NCB + cb];
        if (!len) continue;
        int sp = blk * CHUNK + base_tbl[blk * NCB + cb];
        int dp = segdst[cb * NBLK + blk];
        for (int j = 0; j < len; ++j) ubuf[dp + j] = rec[sp + j];
      }
      __syncthreads();
      for (int i = t; i < total; i += 512)
        atomicAdd(&hist[(ubuf[i] >> 23) & 127], 1);
      __syncthreads();
      // parallel exclusive scan over 128 bins (Hillis-Steele)
      if (t < NPB2) scn[t] = hist[t];
      __syncthreads();
#pragma unroll
      for (int o = 1; o < NPB2; o <<= 1) {
        int v = (t < NPB2 && t >= o) ? scn[t - o] : 0;
        __syncthreads();
        if (t < NPB2) scn[t] += v;
        __syncthreads();
      }
      if (t < NPB2) {
        basex[t] = scn[t] - hist[t];
        curx[t] = scn[t] - hist[t];
        if (node0 + t < Nn) off[node0 + t] = gbase + scn[t] - hist[t];
      }
      if (cb == 0 && t == 0) off[Nn] = Ee;
      __syncthreads();
      for (int i = t; i < total; i += 512) {
        unsigned u = ubuf[i];
        int pos = atomicAdd(&curx[(u >> 23) & 127], 1);
        ubuf2[pos] = u;
      }
      __syncthreads();
      // output: eix2 + AI-partials only (no gathers, no exp)
      for (int i = t; i < total; i += 512) {
        unsigned u = ubuf2[i];
        int src = u & 0xFFFF;
        int c012 = (u >> 16) & 127;
        int dl = (u >> 23) & 127;
        int a0 = c012 % 5, a1 = (c012 / 5) % 5, a2 = c012 / 25;
        eix2[gbase + i] = (unsigned)src | ((unsigned)a0 << 16) |
                          ((unsigned)a1 << 19) | ((unsigned)a2 << 22);
        alpha2[gbase + i] = nodev[dl];
      }
    } else {
      // fallback (statistically unreachable): global-read path
      for (int blk = t; blk < NBLK; blk += 512) {
        int len = cnt_tbl[blk * NCB + cb];
        int sp = blk * CHUNK + base_tbl[blk * NCB + cb];
        for (int j = 0; j < len; ++j)
          atomicAdd(&hist[(rec[sp + j] >> 23) & 127], 1);
      }
      __syncthreads();
      if (t == 0) {
        int s = 0;
        for (int i = 0; i < NPB2; ++i) { basex[i] = s; s += hist[i]; }
      }
      __syncthreads();
      if (t < NPB2) {
        curx[t] = basex[t];
        if (node0 + t < Nn) off[node0 + t] = gbase + basex[t];
      }
      if (cb == 0 && t == 0) off[Nn] = Ee;
      __syncthreads();
      for (int blk = t; blk < NBLK; blk += 512) {
        int len = cnt_tbl[blk * NCB + cb];
        int sp = blk * CHUNK + base_tbl[blk * NCB + cb];
        for (int j = 0; j < len; ++j) {
          unsigned u = rec[sp + j];
          int src = u & 0xFFFF;
          int c012 = (u >> 16) & 127;
          int dl = (u >> 23) & 127;
          int a0 = c012 % 5, a1 = (c012 / 5) % 5, a2 = c012 / 25;
          int pos = gbase + atomicAdd(&curx[dl], 1);
          eix2[pos] = (unsigned)src | ((unsigned)a0 << 16) |
                      ((unsigned)a1 << 19) | ((unsigned)a2 << 22);
          alpha2[pos] = nodev[dl];
        }
      }
    }
  }
}

// ---------------------------------------------------------------------------
// K_norm: finishes the logit at FULL occupancy. Per edge: one float4 gather
// ajrd[src] = (aj0,aj1,rden0,rden1), lg = ai_part + aj + tbl[attrs], leaky,
// alpha = exp(lg) * rden. Same add order as the fused version.
// ---------------------------------------------------------------------------
__global__ __launch_bounds__(256) void k_norm(
    const unsigned int* __restrict__ eix, float2* __restrict__ alpha2,
    const float4* __restrict__ ajrd4, const float* __restrict__ tblg, int Ee) {
  __shared__ float tbl[30];
  int t = threadIdx.x;
  if (t < 30) tbl[t] = tblg[t];
  __syncthreads();

#define NORM_BODY(U, A, F, OUT)                                                \
  {                                                                            \
    int a0 = ((U) >> 16) & 7, a1 = ((U) >> 19) & 7, a2 = ((U) >> 22) & 7;      \
    float lg0 = (A).x + (F).x + tbl[a0 * 2] + tbl[10 + a1 * 2] +               \
                tbl[20 + a2 * 2];                                              \
    float lg1 = (A).y + (F).y + tbl[a0 * 2 + 1] + tbl[10 + a1 * 2 + 1] +       \
                tbl[20 + a2 * 2 + 1];                                          \
    lg0 = lg0 >= 0.f ? lg0 : NEG_SLOPE * lg0;                                  \
    lg1 = lg1 >= 0.f ? lg1 : NEG_SLOPE * lg1;                                  \
    OUT = make_float2(__expf(lg0) * (F).z, __expf(lg1) * (F).w);               \
  }

  int g = blockIdx.x * 256 + t;
  int e = g * 4;
  if (e + 4 <= Ee) {
    uint4 u = *reinterpret_cast<const uint4*>(&eix[e]);
    float4 f0 = ajrd4[u.x & 0xFFFFu];
    float4 f1 = ajrd4[u.y & 0xFFFFu];
    float4 f2 = ajrd4[u.z & 0xFFFFu];
    float4 f3 = ajrd4[u.w & 0xFFFFu];
    float2 a0v = alpha2[e], a1v = alpha2[e + 1];
    float2 a2v = alpha2[e + 2], a3v = alpha2[e + 3];
    float2 o0, o1, o2, o3;
    NORM_BODY(u.x, a0v, f0, o0)
    NORM_BODY(u.y, a1v, f1, o1)
    NORM_BODY(u.z, a2v, f2, o2)
    NORM_BODY(u.w, a3v, f3, o3)
    alpha2[e] = o0; alpha2[e + 1] = o1;
    alpha2[e + 2] = o2; alpha2[e + 3] = o3;
  } else {
    for (; e < Ee; ++e) {
      unsigned u = eix[e];
      float4 f = ajrd4[u & 0xFFFFu];
      float2 a = alpha2[e];
      float2 o;
      NORM_BODY(u, a, f, o)
      alpha2[e] = o;
    }
  }
#undef NORM_BODY
}

// ---------------------------------------------------------------------------
// K_gather: round-7 skeleton. ROUND 17: 16-deep gather batch (mean degree 32
// = 2 full batches/node) — doubles in-flight hb gathers per wave to cover
// random-row latency; u/al stay in SGPRs, hv[16] costs ~8 extra VGPRs.
// ---------------------------------------------------------------------------
__global__ __launch_bounds__(256) void k_gather(
    const unsigned int* __restrict__ eix, const float2* __restrict__ alpha2,
    const int* __restrict__ off, const unsigned int* __restrict__ hb,
    const float* __restrict__ bemb, const float* __restrict__ bias,
    float* __restrict__ out, int Nn) {
  __shared__ float bembs[15 * 128];  // [f*5+c][128]
  __shared__ float wsm[4][32];
  int t = threadIdx.x;
  for (int i = t; i < 15 * 128; i += 256) bembs[i] = bemb[i];
  __syncthreads();
  int wave = t >> 6, lane = t & 63;
  int n = blockIdx.x * 4 + wave;
  if (n >= Nn) return;
  int p0 = __builtin_amdgcn_readfirstlane(off[n]);
  int p1 = __builtin_amdgcn_readfirstlane(off[n + 1]);
  int myf = lane / 5;                 // 0..2 for lanes 0..14
  int myc = lane % 5;
  bool active = lane < 15;
  int myshift = 16 + 3 * myf;         // {16,19,22}: a0/a1/a2 bit positions
  int mycEff = active ? myc : 8;      // sel in 0..7 -> 8 never matches
  float w0 = 0.f, w1 = 0.f;
  float acc0 = 0.f, acc1 = 0.f;

#define EDGE_BODY(U, HV, AL)                                                   \
  {                                                                            \
    acc0 = fmaf((AL).x, __uint_as_float((HV) << 16), acc0);                    \
    acc1 = fmaf((AL).y, __uint_as_float((HV) & 0xffff0000u), acc1);            \
    int sel = (int)(((U) >> myshift) & 7u);                                    \
    float m = (sel == mycEff) ? 1.0f : 0.0f;                                   \
    w0 = fmaf(m, (AL).x, w0);                                                  \
    w1 = fmaf(m, (AL).y, w1);                                                  \
  }

  int p = p0;
  for (; p + 16 <= p1; p += 16) {
    unsigned u[16], hv[16];
    float2 al[16];
#pragma unroll
    for (int k = 0; k < 16; ++k) u[k] = eix[p + k];      // uniform -> s_load
#pragma unroll
    for (int k = 0; k < 16; ++k) al[k] = alpha2[p + k];  // uniform -> s_load
#pragma unroll
    for (int k = 0; k < 16; ++k) {
      const unsigned* __restrict__ hrow = hb + ((size_t)(u[k] & 0xFFFFu) << 6);
      hv[k] = hrow[lane];                                // s[base] + v_laneoff
    }
#pragma unroll
    for (int k = 0; k < 16; ++k) EDGE_BODY(u[k], hv[k], al[k])
  }
  for (; p + 8 <= p1; p += 8) {
    unsigned u[8], hv[8];
    float2 al[8];
#pragma unroll
    for (int k = 0; k < 8; ++k) u[k] = eix[p + k];
#pragma unroll
    for (int k = 0; k < 8; ++k) al[k] = alpha2[p + k];
#pragma unroll
    for (int k = 0; k < 8; ++k) {
      const unsigned* __restrict__ hrow = hb + ((size_t)(u[k] & 0xFFFFu) << 6);
      hv[k] = hrow[lane];
    }
#pragma unroll
    for (int k = 0; k < 8; ++k) EDGE_BODY(u[k], hv[k], al[k])
  }
  for (; p < p1; ++p) {
    unsigned ue = eix[p];
    float2 ale = alpha2[p];
    const unsigned* __restrict__ hrow = hb + ((size_t)(ue & 0xFFFFu) << 6);
    unsigned hve = hrow[lane];
    EDGE_BODY(ue, hve, ale)
  }
#undef EDGE_BODY

  if (active) {
    wsm[wave][lane * 2] = w0;      // same-wave LDS ops are in-order
    wsm[wave][lane * 2 + 1] = w1;
  }
#pragma unroll
  for (int k = 0; k < 15; ++k) {
    acc0 += wsm[wave][k * 2] * bembs[k * 128 + lane];
    acc1 += wsm[wave][k * 2 + 1] * bembs[k * 128 + 64 + lane];
  }
  out[(size_t)n * 64 + lane] = 0.5f * (acc0 + acc1) + bias[lane];
}

extern "C" void kernel_launch(void* const* d_in, const int* in_sizes, int n_in,
                              void* d_out, int out_size, void* d_ws, size_t ws_size,
                              hipStream_t stream) {
  const float* x    = (const float*)d_in[0];
  const int*   ei   = (const int*)d_in[1];
  const int*   eatt = (const int*)d_in[2];
  const float* W    = (const float*)d_in[3];
  const float* bW   = (const float*)d_in[4];
  const float* att  = (const float*)d_in[5];
  const float* bias = (const float*)d_in[6];
  const float* bemb = (const float*)d_in[7];
  int Nn = in_sizes[0] / 64;
  int Ee = in_sizes[1] / 2;
  int NCB = (Nn + NPB2 - 1) / NPB2;            // 391 coarse buckets (128 nodes)
  int NBLK = (Ee + CHUNK - 1) / CHUNK;         // 391 bin blocks (CHUNK=4096)

  char* ws = (char*)d_ws;
  ws = (char*)(((uintptr_t)ws + 15) & ~(uintptr_t)15);
  float* ajrd = (float*)ws;               ws += (size_t)Nn * 4 * 4;  // 16B-aligned
  float* ai = (float*)ws;                 ws += (size_t)Nn * 2 * 4;
  float* tblg = (float*)ws;               ws += 32 * 4;
  unsigned int* hb = (unsigned int*)ws;   ws += (size_t)Nn * 64 * 4;
  unsigned int* rec = (unsigned int*)ws;  ws += (size_t)NBLK * CHUNK * 4;
  unsigned int* rec_src = (unsigned int*)ws; ws += (size_t)NBLK * CHUNK * 4;
  unsigned int* eix2 = (unsigned int*)ws; ws += (size_t)Ee * 4;
  float2* alpha2 = (float2*)ws;           ws += (size_t)Ee * 8;
  int* off = (int*)ws;                    ws += (size_t)(Nn + 1) * 4;
  int* cnt_tbl = (int*)ws;                ws += (size_t)NBLK * NCB * 4;
  int* base_tbl = (int*)ws;               ws += (size_t)NBLK * NCB * 4;
  int* cnt_tbl2 = (int*)ws;               ws += (size_t)NBLK * NCB * 4;
  int* base_tbl2 = (int*)ws;              ws += (size_t)NBLK * NCB * 4;
  int* segdst = (int*)ws;                 ws += (size_t)NCB * NBLK * 4;
  int* segdst2 = (int*)ws;                ws += (size_t)NCB * NBLK * 4;
  int* coarse_base = (int*)ws;            ws += (size_t)(NCB + 1) * 4;
  int* btot = (int*)ws;                   ws += (size_t)NCB * 4;
  int* btot2 = (int*)ws;                  ws += (size_t)NCB * 4;

  k1_gemm<<<1024, 256, 0, stream>>>(x, W, bW, att, hb, ai, ajrd, Nn);
  k_bin<<<NBLK, 512, 0, stream>>>(ei, eatt, rec, cnt_tbl, base_tbl, rec_src,
                                  cnt_tbl2, base_tbl2, Ee, NCB);
  k_segoff_ab<<<2 * NCB, 256, 0, stream>>>(cnt_tbl, segdst, btot, cnt_tbl2,
                                           segdst2, btot2, NCB, NBLK);
  k_segoff_b<<<1, 512, 0, stream>>>(btot, coarse_base, att, bemb, tblg, NCB, Ee);
  k_mid<<<2 * NCB, 512, 0, stream>>>(rec, cnt_tbl, base_tbl, segdst,
                                     coarse_base, rec_src, cnt_tbl2, base_tbl2,
                                     segdst2, btot2, (const float2*)ai, ajrd,
                                     att, bemb, eix2, alpha2, off,
                                     Nn, NCB, NBLK, Ee);
  k_norm<<<(Ee / 4 + 255) / 256, 256, 0, stream>>>(eix2, alpha2,
                                                   (const float4*)ajrd, tblg, Ee);
  k_gather<<<(Nn + 3) / 4, 256, 0, stream>>>(eix2, alpha2, off, hb, bemb, bias,
                                             (float*)d_out, Nn);
}